// Round 14
// baseline (757.781 us; speedup 1.0000x reference)
//
#include <hip/hip_runtime.h>
#include <math.h>

#define BB 4096
#define TT 48
#define DD 32
#define HH 256
#define LL 128
#define HID 256
#define EE 8
#define NHZ 48
#define NS 8              // RK4 macro steps (dense-output Hermite between knots)
#define NTEMB (2*NS+1)    // 17 precomputed time-embeddings
#define GROWS 32          // GRU rows per block (2 M-tiles) -> grid 128

typedef __attribute__((ext_vector_type(8))) short bf16x8;   // 8 bf16 = 4 VGPRs
typedef __attribute__((ext_vector_type(4))) float f32x4;

#define MFMA_BF16(a,b,c) __builtin_amdgcn_mfma_f32_16x16x32_bf16((a),(b),(c),0,0,0)

__device__ __forceinline__ float sigm_f(float x) {
    return 1.0f / (1.0f + __expf(-x));
}
__device__ __forceinline__ float tanh_f(float x) {
    x = fminf(fmaxf(x, -15.0f), 15.0f);
    float e = __expf(2.0f * x);
    return (e - 1.0f) / (e + 1.0f);
}
__device__ __forceinline__ float4 axpy4(float s, float4 a, float4 z) {
    return make_float4(fmaf(s, a.x, z.x), fmaf(s, a.y, z.y),
                       fmaf(s, a.z, z.z), fmaf(s, a.w, z.w));
}
__device__ __forceinline__ unsigned short f2bf(float x) {   // RNE fp32->bf16
    union { float f; unsigned u; } a; a.f = x;
    unsigned r = a.u + 0x7FFFu + ((a.u >> 16) & 1u);
    return (unsigned short)(r >> 16);
}

// ---------------- prep kernels ----------------

__global__ void temb_k(const float* __restrict__ tproj_w, const float* __restrict__ tproj_b,
                       float* __restrict__ tembs) {
    int i = blockIdx.x * 64 + threadIdx.x;
    if (i >= NTEMB) return;
    float t = (float)i / (float)(2 * NS);
    const float PI = 3.14159265358979323846f;
    float emb[8];
    #pragma unroll
    for (int m = 0; m < 4; ++m) {
        float pos = t * (float)(m + 1) * PI;
        emb[m]     = sinf(pos);
        emb[4 + m] = cosf(pos);
    }
    #pragma unroll
    for (int o = 0; o < 8; ++o) {
        float a = tproj_b[o];
        #pragma unroll
        for (int k = 0; k < 8; ++k) a = fmaf(tproj_w[o * 8 + k], emb[k], a);
        tembs[i * 8 + o] = a;
    }
}

// tembW1[ti][n] = b1[n] + sum_k W1[n][128+k] * temb(ti)[k]
__global__ void tembW1_k(const float* __restrict__ w1, const float* __restrict__ b1,
                         const float* __restrict__ tembs, float* __restrict__ out) {
    int i = blockIdx.x * 256 + threadIdx.x;
    if (i >= NTEMB * 256) return;
    int ti = i >> 8, n = i & 255;
    float a = b1[n];
    #pragma unroll
    for (int k = 0; k < 8; ++k) a = fmaf(w1[n * 136 + 128 + k], tembs[ti * 8 + k], a);
    out[i] = a;
}

// B-fragment packers (bf16). Fragment = 512 bf16: element (lane*8+j) holds
// B[k][n] with k = ks*32 + (lane>>4)*8 + j, n = nt*16 + (lane&15).

__global__ void packBrz_k(const float* __restrict__ w_ih, const float* __restrict__ w_hh,
                          unsigned short* __restrict__ dst) {
    int i = blockIdx.x * 256 + threadIdx.x;      // 32 nt * 10 ks * 512
    if (i >= 32 * 10 * 512) return;
    int frag = i >> 9, e = i & 511;
    int lane = e >> 3, j = e & 7;
    int nt = frag / 10, ks = frag % 10;
    int k = ks * 32 + ((lane >> 4) << 3) + j;
    int n = nt * 16 + (lane & 15);
    float v = (k < 64) ? w_ih[n * 64 + k] : w_hh[n * 256 + (k - 64)];
    dst[i] = f2bf(v);
}

__global__ void packB_k(const float* __restrict__ src, unsigned short* __restrict__ dst,
                        int K, int NT, int NKS) {
    int i = blockIdx.x * 256 + threadIdx.x;
    if (i >= NT * NKS * 512) return;
    int frag = i >> 9, e = i & 511;
    int lane = e >> 3, j = e & 7;
    int nt = frag / NKS, ks = frag % NKS;
    int k = ks * 32 + ((lane >> 4) << 3) + j;
    int n = nt * 16 + (lane & 15);
    dst[i] = f2bf(src[n * K + k]);
}

// ---------------- GRU encoder via MFMA (+ fused z0 projection) ----------------
// Round-13 structure, NEW: 32 rows/block (2 M-tiles share every B-fragment
// load -> half the L2 weight traffic per unit work), grid 128.

__global__ __launch_bounds__(512, 1) void gru_mfma_k(
    const float* __restrict__ Xp, const float* __restrict__ Mp,
    const unsigned short* __restrict__ Brz,   // [32 nt][10 ks][512]  (L2-streamed)
    const unsigned short* __restrict__ Bnu,   // [16 nt][ 2 ks][512]  (L2-streamed)
    const unsigned short* __restrict__ Bnh,   // [16 nt][ 8 ks][512]  (-> LDS)
    const unsigned short* __restrict__ Bz0,   // [16 nt][ 8 ks][512]
    const float* __restrict__ b_ih, const float* __restrict__ b_hh,
    const float* __restrict__ z0_b,
    float* __restrict__ out_mean, float* __restrict__ out_lv) {

    __shared__ unsigned short h_bf[GROWS * 256];     // 16KB, swizzled
    __shared__ unsigned short u_bf[GROWS * 64];      // 4KB, swizzled
    __shared__ unsigned short bnh_lds[16 * 8 * 512]; // 131KB n-gate hh fragments
    __shared__ float obs[GROWS];

    int tid = threadIdx.x, blk = blockIdx.x;
    int lane = tid & 63, w = tid >> 6;
    int l4 = lane >> 4, l15 = lane & 15;

    for (int e = tid; e < GROWS * 256; e += 512) h_bf[e] = 0;
    for (int e = tid; e < 8192; e += 512)
        ((f32x4*)bnh_lds)[e] = ((const f32x4*)Bnh)[e];

    float brz0[2], brz1[2], bin_[2], bhn_[2];
    int hcol[2];
    #pragma unroll
    for (int gg = 0; gg < 2; ++gg) {
        int n = (2 * w + gg) * 16 + l15;
        hcol[gg] = n;
        brz0[gg] = b_ih[n]       + b_hh[n];
        brz1[gg] = b_ih[256 + n] + b_hh[256 + n];
        bin_[gg] = b_ih[512 + n];
        bhn_[gg] = b_hh[512 + n];
    }
    float h_st[2][2][4];   // [gg][mt][q]
    #pragma unroll
    for (int gg = 0; gg < 2; ++gg)
        #pragma unroll
        for (int mt = 0; mt < 2; ++mt)
            #pragma unroll
            for (int q = 0; q < 4; ++q) h_st[gg][mt][q] = 0.0f;

    __syncthreads();

    for (int t = TT - 1; t >= 0; --t) {
        // stage u (32 rows x 64 cols, all 512 threads), obs
        {
            int r = tid >> 4, c4 = tid & 15;
            const float* base = (c4 < 8 ? Xp : Mp) + (size_t)(blk * GROWS + r) * (TT * DD) + t * DD;
            f32x4 v = __builtin_nontemporal_load(((const f32x4*)base) + (c4 & 7));
            ushort4 p;
            p.x = f2bf(v.x); p.y = f2bf(v.y); p.z = f2bf(v.z); p.w = f2bf(v.w);
            int k0 = (c4 < 8) ? c4 * 4 : 32 + (c4 - 8) * 4;
            int off = r * 128 + ((k0 * 2) ^ ((r & 7) << 4));
            *(ushort4*)((char*)u_bf + off) = p;
        }
        if (tid < GROWS) {
            const f32x4* mrow = (const f32x4*)(Mp + (size_t)(blk * GROWS + tid) * (TT * DD) + t * DD);
            float s = 0.0f;
            #pragma unroll
            for (int i = 0; i < 8; ++i) {
                f32x4 v = __builtin_nontemporal_load(mrow + i);
                s += v.x + v.y + v.z + v.w;
            }
            obs[tid] = (s > 0.0f) ? 1.0f : 0.0f;
        }
        // read prev-h A-frags for both M-tiles (before barrier: h writes occur after it)
        bf16x8 ah[2][8];
        #pragma unroll
        for (int mt = 0; mt < 2; ++mt) {
            int arow = mt * 16 + l15, asw = (arow & 7) << 4;
            #pragma unroll
            for (int ks = 0; ks < 8; ++ks)
                ah[mt][ks] = *(const bf16x8*)((const char*)h_bf + (arow * 512 + ((ks * 64 + l4 * 16) ^ asw)));
        }
        __syncthreads();

        bf16x8 au[2][2];
        #pragma unroll
        for (int mt = 0; mt < 2; ++mt) {
            int arow = mt * 16 + l15, asw = (arow & 7) << 4;
            #pragma unroll
            for (int ks = 0; ks < 2; ++ks)
                au[mt][ks] = *(const bf16x8*)((const char*)u_bf + (arow * 128 + ((ks * 64 + l4 * 16) ^ asw)));
        }

        #pragma unroll
        for (int gg = 0; gg < 2; ++gg) {
            int g = 2 * w + gg;
            f32x4 accr[2] = {{0,0,0,0},{0,0,0,0}};
            f32x4 accz[2] = {{0,0,0,0},{0,0,0,0}};
            f32x4 acci[2] = {{0,0,0,0},{0,0,0,0}};
            f32x4 acch[2] = {{0,0,0,0},{0,0,0,0}};
            #pragma unroll
            for (int ks = 0; ks < 10; ++ks) {
                bf16x8 br = *(const bf16x8*)(Brz + ((g * 10 + ks) * 512 + lane * 8));
                bf16x8 bz = *(const bf16x8*)(Brz + (((16 + g) * 10 + ks) * 512 + lane * 8));
                #pragma unroll
                for (int mt = 0; mt < 2; ++mt) {
                    bf16x8 a = (ks < 2) ? au[mt][ks] : ah[mt][ks - 2];
                    accr[mt] = MFMA_BF16(a, br, accr[mt]);
                    accz[mt] = MFMA_BF16(a, bz, accz[mt]);
                }
            }
            #pragma unroll
            for (int ks = 0; ks < 2; ++ks) {
                bf16x8 b = *(const bf16x8*)(Bnu + ((g * 2 + ks) * 512 + lane * 8));
                #pragma unroll
                for (int mt = 0; mt < 2; ++mt)
                    acci[mt] = MFMA_BF16(au[mt][ks], b, acci[mt]);
            }
            #pragma unroll
            for (int ks = 0; ks < 8; ++ks) {
                bf16x8 b = *(const bf16x8*)(bnh_lds + ((g * 8 + ks) * 512 + lane * 8));
                #pragma unroll
                for (int mt = 0; mt < 2; ++mt)
                    acch[mt] = MFMA_BF16(ah[mt][ks], b, acch[mt]);
            }
            #pragma unroll
            for (int mt = 0; mt < 2; ++mt) {
                #pragma unroll
                for (int q = 0; q < 4; ++q) {
                    int m = mt * 16 + l4 * 4 + q;
                    float rg = sigm_f(accr[mt][q] + brz0[gg]);
                    float zg = sigm_f(accz[mt][q] + brz1[gg]);
                    float nn = tanh_f(acci[mt][q] + bin_[gg] + rg * (acch[mt][q] + bhn_[gg]));
                    float hnew = (1.0f - zg) * nn + zg * h_st[gg][mt][q];
                    float o = obs[m];
                    float hs = o * hnew + (1.0f - o) * h_st[gg][mt][q];
                    h_st[gg][mt][q] = hs;
                    int off = m * 512 + ((hcol[gg] * 2) ^ ((m & 7) << 4));
                    *(unsigned short*)((char*)h_bf + off) = f2bf(hs);
                }
            }
        }
        __syncthreads();
    }

    // fused z0 projection: 2 M-tiles x 2 n-tiles per wave
    #pragma unroll
    for (int mt = 0; mt < 2; ++mt) {
        int arow = mt * 16 + l15, asw = (arow & 7) << 4;
        bf16x8 ahf[8];
        #pragma unroll
        for (int ks = 0; ks < 8; ++ks)
            ahf[ks] = *(const bf16x8*)((const char*)h_bf + (arow * 512 + ((ks * 64 + l4 * 16) ^ asw)));
        #pragma unroll
        for (int gg = 0; gg < 2; ++gg) {
            int nt = 2 * w + gg;
            f32x4 acc = {0,0,0,0};
            #pragma unroll
            for (int ks = 0; ks < 8; ++ks) {
                bf16x8 b = *(const bf16x8*)(Bz0 + ((nt * 8 + ks) * 512 + lane * 8));
                acc = MFMA_BF16(ahf[ks], b, acc);
            }
            int n = nt * 16 + l15;
            float bb = z0_b[n];
            #pragma unroll
            for (int q = 0; q < 4; ++q) {
                int row = blk * GROWS + mt * 16 + l4 * 4 + q;
                float v = acc[q] + bb;
                if (n < 128) out_mean[row * LL + n] = v;
                else         out_lv  [row * LL + (n - 128)] = v;
            }
        }
    }
}

// ---------------- ODE dynamics eval via MFMA (round-11 verbatim, validated) ----------------

__device__ __forceinline__ void ode_f_mfma(
    const unsigned short* __restrict__ az, unsigned short* __restrict__ h1b,
    unsigned short* __restrict__ h2b, float* __restrict__ fo,
    const unsigned short* __restrict__ B1, const unsigned short* __restrict__ B2,
    const unsigned short* __restrict__ B3,
    const float* __restrict__ tW1,   // tembW1 + ti*256 (includes b1)
    float b2n0, float b2n1, float b3n, int lane, int w) {

    int l4 = lane >> 4, l15 = lane & 15;
    int arow = l15, asw = (arow & 7) << 4;

    // phase A: h1 = tanh(W1z·z + tembW1(t))   K=128 -> 4 ks
    bf16x8 a4[4];
    #pragma unroll
    for (int ks = 0; ks < 4; ++ks)
        a4[ks] = *(const bf16x8*)((const char*)az + (arow * 256 + ((ks * 64 + l4 * 16) ^ asw)));
    #pragma unroll
    for (int gg = 0; gg < 2; ++gg) {
        int nt = 2 * w + gg, n = nt * 16 + l15;
        f32x4 acc = {0,0,0,0};
        #pragma unroll
        for (int ks = 0; ks < 4; ++ks) {
            bf16x8 b = *(const bf16x8*)(B1 + ((nt * 4 + ks) * 512 + lane * 8));
            acc = MFMA_BF16(a4[ks], b, acc);
        }
        float tb = tW1[n];
        #pragma unroll
        for (int q = 0; q < 4; ++q) {
            int m = l4 * 4 + q;
            float v = tanh_f(acc[q] + tb);
            *(unsigned short*)((char*)h1b + (m * 512 + ((n * 2) ^ ((m & 7) << 4)))) = f2bf(v);
        }
    }
    __syncthreads();

    // phase B: h2 = tanh(W2·h1 + b2)   K=256 -> 8 ks
    bf16x8 a8[8];
    #pragma unroll
    for (int ks = 0; ks < 8; ++ks)
        a8[ks] = *(const bf16x8*)((const char*)h1b + (arow * 512 + ((ks * 64 + l4 * 16) ^ asw)));
    #pragma unroll
    for (int gg = 0; gg < 2; ++gg) {
        int nt = 2 * w + gg, n = nt * 16 + l15;
        f32x4 acc = {0,0,0,0};
        #pragma unroll
        for (int ks = 0; ks < 8; ++ks) {
            bf16x8 b = *(const bf16x8*)(B2 + ((nt * 8 + ks) * 512 + lane * 8));
            acc = MFMA_BF16(a8[ks], b, acc);
        }
        float bb = (gg == 0) ? b2n0 : b2n1;
        #pragma unroll
        for (int q = 0; q < 4; ++q) {
            int m = l4 * 4 + q;
            float v = tanh_f(acc[q] + bb);
            *(unsigned short*)((char*)h2b + (m * 512 + ((n * 2) ^ ((m & 7) << 4)))) = f2bf(v);
        }
    }
    __syncthreads();

    // phase C: fo = W3·h2 + b3   N=128, wave w -> tile w
    #pragma unroll
    for (int ks = 0; ks < 8; ++ks)
        a8[ks] = *(const bf16x8*)((const char*)h2b + (arow * 512 + ((ks * 64 + l4 * 16) ^ asw)));
    {
        f32x4 acc = {0,0,0,0};
        #pragma unroll
        for (int ks = 0; ks < 8; ++ks) {
            bf16x8 b = *(const bf16x8*)(B3 + ((w * 8 + ks) * 512 + lane * 8));
            acc = MFMA_BF16(a8[ks], b, acc);
        }
        int n = w * 16 + l15;
        #pragma unroll
        for (int q = 0; q < 4; ++q)
            fo[(l4 * 4 + q) * 128 + n] = acc[q] + b3n;
    }
    __syncthreads();
}

// ---------------- ODE (8-step RK4 + Hermite dense output) + head ----------------

__global__ __launch_bounds__(512, 2) void ode_head_mfma_k(
    const float* __restrict__ zinit,
    const unsigned short* __restrict__ B1, const unsigned short* __restrict__ B2,
    const unsigned short* __restrict__ B3,
    const float* __restrict__ tembW1, const float* __restrict__ b2, const float* __restrict__ b3,
    const float* __restrict__ shw1g, const float* __restrict__ shb1,
    const float* __restrict__ shw2, const float* __restrict__ shb2,
    float* __restrict__ out_haz, float* __restrict__ out_surv, float* __restrict__ out_pg) {

    __shared__ __align__(16) float bufA [2048];              // 8KB z knot s
    __shared__ __align__(16) float bufB [2048];              // 8KB z knot s+1
    __shared__ __align__(16) float bufFP[2048];              // 8KB f knot s
    __shared__ __align__(16) float bufFN[2048];              // 8KB f scratch
    __shared__ __align__(16) float ztl  [2048];              // 8KB stage/z-theta
    __shared__ __align__(16) unsigned short az [16 * 128];   // 4KB bf16 A of state
    __shared__ __align__(16) unsigned short h1b[16 * 256];   // 8KB
    __shared__ __align__(16) unsigned short h2b[16 * 256];   // 8KB
    __shared__ __align__(16) float w1h[32 * 128];            // 16KB head W1 packed

    int tid = threadIdx.x, blk = blockIdx.x;
    int lane = tid & 63, w = tid >> 6;
    int l15 = lane & 15;
    int s5 = tid & 31, rh = tid >> 5;

    float b2n0 = b2[(2 * w) * 16 + l15];
    float b2n1 = b2[(2 * w + 1) * 16 + l15];
    float b3n  = b3[w * 16 + l15];
    float w2s = shw2[s5], b1s = shb1[s5], b2s = shb2[0];
    float cum_r = 0.0f;
    const float4* w1hq = (const float4*)w1h;

    float* zA = bufA; float* zB = bufB;
    float* fP = bufFP; float* fN = bufFN;

    int crow = tid >> 5, ccol = (tid & 31) * 4;
    int azoff = crow * 256 + ((ccol * 2) ^ ((crow & 7) << 4));

    {
        float4 zv = ((const float4*)(zinit + (size_t)blk * 2048))[tid];
        ((float4*)zA)[tid] = zv;
        ushort4 pb; pb.x = f2bf(zv.x); pb.y = f2bf(zv.y); pb.z = f2bf(zv.z); pb.w = f2bf(zv.w);
        *(ushort4*)((char*)az + azoff) = pb;
    }
    for (int e = tid; e < 32 * 128; e += 512) {
        int u = e >> 7, k = e & 127;
        w1h[((k >> 2) * 32 + u) * 4 + (k & 3)] = shw1g[e];
    }
    __syncthreads();

    // f0 = f(z0, t=0)
    ode_f_mfma(az, h1b, h2b, fP, B1, B2, B3, tembW1, b2n0, b2n1, b3n, lane, w);

    const float Hh = 1.0f / (float)NS;

    for (int st = 0; st < NS; ++st) {
        float4 ka, zr0;
        {   // k1 = fP (FSAL)
            float4 f = ((const float4*)fP)[tid];
            zr0 = ((const float4*)zA)[tid];
            ka = f;
            float4 zv = axpy4(0.5f * Hh, f, zr0);
            ((float4*)ztl)[tid] = zv;
            ushort4 pb; pb.x=f2bf(zv.x); pb.y=f2bf(zv.y); pb.z=f2bf(zv.z); pb.w=f2bf(zv.w);
            *(ushort4*)((char*)az + azoff) = pb;
        }
        __syncthreads();
        ode_f_mfma(az, h1b, h2b, fN, B1, B2, B3, tembW1 + (2*st+1)*256, b2n0, b2n1, b3n, lane, w); // k2
        {
            float4 f = ((const float4*)fN)[tid];
            ka = axpy4(2.0f, f, ka);
            float4 zv = axpy4(0.5f * Hh, f, zr0);
            ((float4*)ztl)[tid] = zv;
            ushort4 pb; pb.x=f2bf(zv.x); pb.y=f2bf(zv.y); pb.z=f2bf(zv.z); pb.w=f2bf(zv.w);
            *(ushort4*)((char*)az + azoff) = pb;
        }
        __syncthreads();
        ode_f_mfma(az, h1b, h2b, fN, B1, B2, B3, tembW1 + (2*st+1)*256, b2n0, b2n1, b3n, lane, w); // k3
        {
            float4 f = ((const float4*)fN)[tid];
            ka = axpy4(2.0f, f, ka);
            float4 zv = axpy4(Hh, f, zr0);
            ((float4*)ztl)[tid] = zv;
            ushort4 pb; pb.x=f2bf(zv.x); pb.y=f2bf(zv.y); pb.z=f2bf(zv.z); pb.w=f2bf(zv.w);
            *(ushort4*)((char*)az + azoff) = pb;
        }
        __syncthreads();
        ode_f_mfma(az, h1b, h2b, fN, B1, B2, B3, tembW1 + (2*st+2)*256, b2n0, b2n1, b3n, lane, w); // k4
        {
            float4 f = ((const float4*)fN)[tid];
            float s6 = Hh / 6.0f;
            float4 kk = make_float4(ka.x + f.x, ka.y + f.y, ka.z + f.z, ka.w + f.w);
            float4 zv = axpy4(s6, kk, zr0);
            ((float4*)zB)[tid] = zv;
            ushort4 pb; pb.x=f2bf(zv.x); pb.y=f2bf(zv.y); pb.z=f2bf(zv.z); pb.w=f2bf(zv.w);
            *(ushort4*)((char*)az + azoff) = pb;
        }
        __syncthreads();
        // f_{s+1} (next step's k1, Hermite right-slope)
        ode_f_mfma(az, h1b, h2b, fN, B1, B2, B3, tembW1 + (2*st+2)*256, b2n0, b2n1, b3n, lane, w);

        // ---- emit head at output points inside [st/NS, (st+1)/NS] via Hermite ----
        int jlo = (47 * st + NS - 1) / NS;
        int jhi = (st == NS - 1) ? 47 : (47 * (st + 1) + NS - 1) / NS - 1;
        for (int jp = jlo; jp <= jhi; ++jp) {
            float th  = ((float)NS * (float)jp - 47.0f * (float)st) * (1.0f / 47.0f);
            float th2 = th * th, th3 = th2 * th;
            float c0 = 2.0f * th3 - 3.0f * th2 + 1.0f;
            float c1 = 3.0f * th2 - 2.0f * th3;
            float c2 = Hh * (th3 - 2.0f * th2 + th);
            float c3 = Hh * (th3 - th2);
            {
                float4 za = ((const float4*)zA)[tid];
                float4 zb = ((const float4*)zB)[tid];
                float4 fa = ((const float4*)fP)[tid];
                float4 fb = ((const float4*)fN)[tid];
                float4 zv;
                zv.x = c0*za.x + c1*zb.x + c2*fa.x + c3*fb.x;
                zv.y = c0*za.y + c1*zb.y + c2*fa.y + c3*fb.y;
                zv.z = c0*za.z + c1*zb.z + c2*fa.z + c3*fb.z;
                zv.w = c0*za.w + c1*zb.w + c2*fa.w + c3*fb.w;
                ((float4*)ztl)[tid] = zv;
            }
            __syncthreads();
            {
                float aa = b1s;
                const float4* zrow = (const float4*)(ztl + rh * LL);
                for (int k4 = 0; k4 < 32; ++k4) {
                    float4 wv = w1hq[k4 * 32 + s5];
                    float4 v = zrow[k4];
                    aa = fmaf(wv.x, v.x, aa); aa = fmaf(wv.y, v.y, aa);
                    aa = fmaf(wv.z, v.z, aa); aa = fmaf(wv.w, v.w, aa);
                }
                float p = fmaxf(aa, 0.0f) * w2s;
                p += __shfl_xor(p, 1);  p += __shfl_xor(p, 2);
                p += __shfl_xor(p, 4);  p += __shfl_xor(p, 8);
                p += __shfl_xor(p, 16);
                float hz = sigm_f(p + b2s);
                float sv = __expf(cum_r);
                cum_r += __logf(1.0f - hz + 1e-7f);
                if (s5 == 0) {
                    int row = blk * 16 + rh;
                    out_haz [row * NHZ + jp] = hz;
                    out_surv[row * NHZ + jp] = sv;
                    if (jp == NHZ - 1) out_pg[row] = 1.0f - sv;
                }
            }
            __syncthreads();
        }

        // roll buffers
        float* t0 = zA; zA = zB; zB = t0;
        t0 = fP; fP = fN; fN = t0;
    }
}

// ---------------- launch ----------------

extern "C" void kernel_launch(void* const* d_in, const int* in_sizes, int n_in,
                              void* d_out, int out_size, void* d_ws, size_t ws_size,
                              hipStream_t stream) {
    const float* X        = (const float*)d_in[0];
    const float* Mask     = (const float*)d_in[1];
    const float* gru_w_ih = (const float*)d_in[2];
    const float* gru_w_hh = (const float*)d_in[3];
    const float* gru_b_ih = (const float*)d_in[4];
    const float* gru_b_hh = (const float*)d_in[5];
    const float* z0_w     = (const float*)d_in[6];
    const float* z0_b     = (const float*)d_in[7];
    const float* tproj_w  = (const float*)d_in[8];
    const float* tproj_b  = (const float*)d_in[9];
    const float* ode_w1   = (const float*)d_in[10];
    const float* ode_b1   = (const float*)d_in[11];
    const float* ode_w2   = (const float*)d_in[12];
    const float* ode_b2   = (const float*)d_in[13];
    const float* ode_w3   = (const float*)d_in[14];
    const float* ode_b3   = (const float*)d_in[15];
    const float* sh_w1    = (const float*)d_in[16];
    const float* sh_b1    = (const float*)d_in[17];
    const float* sh_w2    = (const float*)d_in[18];
    const float* sh_b2    = (const float*)d_in[19];

    float* ws     = (float*)d_ws;
    float* tembs  = ws;                        // 136 floats
    float* tembW1 = ws + 256;                  // 17*256 = 4352 -> end 4608
    unsigned short* Brz = (unsigned short*)(ws + 4608);  // 163840
    unsigned short* Bnu = Brz + 163840;                  // 16384
    unsigned short* Bnh = Bnu + 16384;                   // 65536
    unsigned short* Bz0 = Bnh + 65536;                   // 65536
    unsigned short* B1  = Bz0 + 65536;                   // 16*4*512 = 32768
    unsigned short* B2  = B1  + 32768;                   // 16*8*512 = 65536
    unsigned short* B3  = B2  + 65536;                   //  8*8*512 = 32768

    float* out      = (float*)d_out;
    float* out_haz  = out;                              // 4096*48
    float* out_surv = out + 196608;                     // 4096*48
    float* out_mean = out + 393216;                     // 4096*128
    float* out_lv   = out + 917504;                     // 4096*128
    float* out_pg   = out + 1441792;                    // 4096

    temb_k<<<1, 64, 0, stream>>>(tproj_w, tproj_b, tembs);
    tembW1_k<<<(NTEMB * 256 + 255) / 256, 256, 0, stream>>>(ode_w1, ode_b1, tembs, tembW1);

    packBrz_k<<<(32*10*512) / 256, 256, 0, stream>>>(gru_w_ih, gru_w_hh, Brz);
    packB_k<<<(16*2*512) / 256, 256, 0, stream>>>(gru_w_ih + 512 * 64,  Bnu, 64,  16, 2);
    packB_k<<<(16*8*512) / 256, 256, 0, stream>>>(gru_w_hh + 512 * 256, Bnh, 256, 16, 8);
    packB_k<<<(16*8*512) / 256, 256, 0, stream>>>(z0_w,                 Bz0, 256, 16, 8);
    packB_k<<<(16*4*512) / 256, 256, 0, stream>>>(ode_w1, B1, 136, 16, 4);   // k<128 only
    packB_k<<<(16*8*512) / 256, 256, 0, stream>>>(ode_w2, B2, 256, 16, 8);
    packB_k<<<( 8*8*512) / 256, 256, 0, stream>>>(ode_w3, B3, 256,  8, 8);

    gru_mfma_k<<<BB / GROWS, 512, 0, stream>>>(X, Mask, Brz, Bnu, Bnh, Bz0,
                                               gru_b_ih, gru_b_hh, z0_b, out_mean, out_lv);

    ode_head_mfma_k<<<BB / 16, 512, 0, stream>>>(out_mean, B1, B2, B3,
                                                 tembW1, ode_b2, ode_b3,
                                                 sh_w1, sh_b1, sh_w2, sh_b2,
                                                 out_haz, out_surv, out_pg);
}

// Round 15
// 666.637 us; speedup vs baseline: 1.1367x; 1.1367x over previous
//
#include <hip/hip_runtime.h>
#include <math.h>

#define BB 4096
#define TT 48
#define DD 32
#define HH 256
#define LL 128
#define HID 256
#define EE 8
#define NHZ 48
#define NS 6              // RK4 macro steps (dense-output Hermite between knots)
#define NTEMB (2*NS+1)    // 13 precomputed time-embeddings

typedef __attribute__((ext_vector_type(8))) short bf16x8;   // 8 bf16 = 4 VGPRs
typedef __attribute__((ext_vector_type(4))) float f32x4;

#define MFMA_BF16(a,b,c) __builtin_amdgcn_mfma_f32_16x16x32_bf16((a),(b),(c),0,0,0)

__device__ __forceinline__ float sigm_f(float x) {
    return 1.0f / (1.0f + __expf(-x));
}
__device__ __forceinline__ float tanh_f(float x) {
    x = fminf(fmaxf(x, -15.0f), 15.0f);
    float e = __expf(2.0f * x);
    return (e - 1.0f) / (e + 1.0f);
}
__device__ __forceinline__ float4 axpy4(float s, float4 a, float4 z) {
    return make_float4(fmaf(s, a.x, z.x), fmaf(s, a.y, z.y),
                       fmaf(s, a.z, z.z), fmaf(s, a.w, z.w));
}
__device__ __forceinline__ unsigned short f2bf(float x) {   // RNE fp32->bf16
    union { float f; unsigned u; } a; a.f = x;
    unsigned r = a.u + 0x7FFFu + ((a.u >> 16) & 1u);
    return (unsigned short)(r >> 16);
}

// ---------------- prep kernels ----------------

__global__ void temb_k(const float* __restrict__ tproj_w, const float* __restrict__ tproj_b,
                       float* __restrict__ tembs) {
    int i = blockIdx.x * 64 + threadIdx.x;
    if (i >= NTEMB) return;
    float t = (float)i / (float)(2 * NS);
    const float PI = 3.14159265358979323846f;
    float emb[8];
    #pragma unroll
    for (int m = 0; m < 4; ++m) {
        float pos = t * (float)(m + 1) * PI;
        emb[m]     = sinf(pos);
        emb[4 + m] = cosf(pos);
    }
    #pragma unroll
    for (int o = 0; o < 8; ++o) {
        float a = tproj_b[o];
        #pragma unroll
        for (int k = 0; k < 8; ++k) a = fmaf(tproj_w[o * 8 + k], emb[k], a);
        tembs[i * 8 + o] = a;
    }
}

// tembW1[ti][n] = b1[n] + sum_k W1[n][128+k] * temb(ti)[k]
__global__ void tembW1_k(const float* __restrict__ w1, const float* __restrict__ b1,
                         const float* __restrict__ tembs, float* __restrict__ out) {
    int i = blockIdx.x * 256 + threadIdx.x;
    if (i >= NTEMB * 256) return;
    int ti = i >> 8, n = i & 255;
    float a = b1[n];
    #pragma unroll
    for (int k = 0; k < 8; ++k) a = fmaf(w1[n * 136 + 128 + k], tembs[ti * 8 + k], a);
    out[i] = a;
}

// B-fragment packers (bf16). Fragment = 512 bf16: element (lane*8+j) holds
// B[k][n] with k = ks*32 + (lane>>4)*8 + j, n = nt*16 + (lane&15).

__global__ void packBrz_k(const float* __restrict__ w_ih, const float* __restrict__ w_hh,
                          unsigned short* __restrict__ dst) {
    int i = blockIdx.x * 256 + threadIdx.x;      // 32 nt * 10 ks * 512
    if (i >= 32 * 10 * 512) return;
    int frag = i >> 9, e = i & 511;
    int lane = e >> 3, j = e & 7;
    int nt = frag / 10, ks = frag % 10;
    int k = ks * 32 + ((lane >> 4) << 3) + j;
    int n = nt * 16 + (lane & 15);
    float v = (k < 64) ? w_ih[n * 64 + k] : w_hh[n * 256 + (k - 64)];
    dst[i] = f2bf(v);
}

__global__ void packB_k(const float* __restrict__ src, unsigned short* __restrict__ dst,
                        int K, int NT, int NKS) {
    int i = blockIdx.x * 256 + threadIdx.x;
    if (i >= NT * NKS * 512) return;
    int frag = i >> 9, e = i & 511;
    int lane = e >> 3, j = e & 7;
    int nt = frag / NKS, ks = frag % NKS;
    int k = ks * 32 + ((lane >> 4) << 3) + j;
    int n = nt * 16 + (lane & 15);
    dst[i] = f2bf(src[n * K + k]);
}

// ---------------- GRU encoder via MFMA (+ fused z0 projection) ----------------
// Round-13 dataflow (16 rows/block, grid 256, Bnh in LDS, NT X/Mask loads).
// NEW: 1024 threads / 16 waves -- each wave owns ONE gate n-group (g = w),
// halving per-wave work and doubling waves/SIMD for latency hiding.

__global__ __launch_bounds__(1024, 1) void gru_mfma_k(
    const float* __restrict__ Xp, const float* __restrict__ Mp,
    const unsigned short* __restrict__ Brz,   // [32 nt][10 ks][512]  (L2-streamed)
    const unsigned short* __restrict__ Bnu,   // [16 nt][ 2 ks][512]  (L2-streamed)
    const unsigned short* __restrict__ Bnh,   // [16 nt][ 8 ks][512]  (-> LDS)
    const unsigned short* __restrict__ Bz0,   // [16 nt][ 8 ks][512]
    const float* __restrict__ b_ih, const float* __restrict__ b_hh,
    const float* __restrict__ z0_b,
    float* __restrict__ out_mean, float* __restrict__ out_lv) {

    __shared__ unsigned short h_bf[16 * 256];        // 8KB, swizzled
    __shared__ unsigned short u_bf[16 * 64];         // 2KB, swizzled
    __shared__ unsigned short bnh_lds[16 * 8 * 512]; // 131KB n-gate hh fragments
    __shared__ float obs[16];

    int tid = threadIdx.x, blk = blockIdx.x;
    int lane = tid & 63, w = tid >> 6;    // w = 0..15: gate n-group
    int l4 = lane >> 4, l15 = lane & 15;

    for (int e = tid; e < 16 * 256; e += 1024) h_bf[e] = 0;
    for (int e = tid; e < 8192; e += 1024)
        ((f32x4*)bnh_lds)[e] = ((const f32x4*)Bnh)[e];

    int ncol = w * 16 + l15;
    float brz0 = b_ih[ncol]       + b_hh[ncol];
    float brz1 = b_ih[256 + ncol] + b_hh[256 + ncol];
    float bin_ = b_ih[512 + ncol];
    float bhn_ = b_hh[512 + ncol];
    float h_st[4] = {0, 0, 0, 0};

    __syncthreads();

    int arow = l15, asw = (arow & 7) << 4;

    for (int t = TT - 1; t >= 0; --t) {
        if (tid < 256) {
            int r = tid >> 4, c4 = tid & 15;
            const float* base = (c4 < 8 ? Xp : Mp) + (size_t)(blk * 16 + r) * (TT * DD) + t * DD;
            f32x4 v = __builtin_nontemporal_load(((const f32x4*)base) + (c4 & 7));
            ushort4 p;
            p.x = f2bf(v.x); p.y = f2bf(v.y); p.z = f2bf(v.z); p.w = f2bf(v.w);
            int k0 = (c4 < 8) ? c4 * 4 : 32 + (c4 - 8) * 4;
            int off = r * 128 + ((k0 * 2) ^ ((r & 7) << 4));
            *(ushort4*)((char*)u_bf + off) = p;
        }
        if (tid < 16) {
            const f32x4* mrow = (const f32x4*)(Mp + (size_t)(blk * 16 + tid) * (TT * DD) + t * DD);
            float s = 0.0f;
            #pragma unroll
            for (int i = 0; i < 8; ++i) {
                f32x4 v = __builtin_nontemporal_load(mrow + i);
                s += v.x + v.y + v.z + v.w;
            }
            obs[tid] = (s > 0.0f) ? 1.0f : 0.0f;
        }
        // read prev-h A-frags (h writes happen after the 2nd barrier)
        bf16x8 ah[8];
        #pragma unroll
        for (int ks = 0; ks < 8; ++ks)
            ah[ks] = *(const bf16x8*)((const char*)h_bf + (arow * 512 + ((ks * 64 + l4 * 16) ^ asw)));
        __syncthreads();

        bf16x8 au[2];
        #pragma unroll
        for (int ks = 0; ks < 2; ++ks)
            au[ks] = *(const bf16x8*)((const char*)u_bf + (arow * 128 + ((ks * 64 + l4 * 16) ^ asw)));

        f32x4 accr = {0,0,0,0}, accz = {0,0,0,0}, acci = {0,0,0,0}, acch = {0,0,0,0};
        #pragma unroll
        for (int ks = 0; ks < 10; ++ks) {
            bf16x8 a = (ks < 2) ? au[ks] : ah[ks - 2];
            bf16x8 br = *(const bf16x8*)(Brz + ((w * 10 + ks) * 512 + lane * 8));
            bf16x8 bz = *(const bf16x8*)(Brz + (((16 + w) * 10 + ks) * 512 + lane * 8));
            accr = MFMA_BF16(a, br, accr);
            accz = MFMA_BF16(a, bz, accz);
        }
        #pragma unroll
        for (int ks = 0; ks < 2; ++ks) {
            bf16x8 b = *(const bf16x8*)(Bnu + ((w * 2 + ks) * 512 + lane * 8));
            acci = MFMA_BF16(au[ks], b, acci);
        }
        #pragma unroll
        for (int ks = 0; ks < 8; ++ks) {
            bf16x8 b = *(const bf16x8*)(bnh_lds + ((w * 8 + ks) * 512 + lane * 8));
            acch = MFMA_BF16(ah[ks], b, acch);
        }
        #pragma unroll
        for (int q = 0; q < 4; ++q) {
            int m = l4 * 4 + q;
            float rg = sigm_f(accr[q] + brz0);
            float zg = sigm_f(accz[q] + brz1);
            float nn = tanh_f(acci[q] + bin_ + rg * (acch[q] + bhn_));
            float hnew = (1.0f - zg) * nn + zg * h_st[q];
            float o = obs[m];
            float hs = o * hnew + (1.0f - o) * h_st[q];
            h_st[q] = hs;
            int off = m * 512 + ((ncol * 2) ^ ((m & 7) << 4));
            *(unsigned short*)((char*)h_bf + off) = f2bf(hs);
        }
        __syncthreads();
    }

    // fused z0 projection: wave w -> n-tile w
    bf16x8 ahf[8];
    #pragma unroll
    for (int ks = 0; ks < 8; ++ks)
        ahf[ks] = *(const bf16x8*)((const char*)h_bf + (arow * 512 + ((ks * 64 + l4 * 16) ^ asw)));
    {
        f32x4 acc = {0,0,0,0};
        #pragma unroll
        for (int ks = 0; ks < 8; ++ks) {
            bf16x8 b = *(const bf16x8*)(Bz0 + ((w * 8 + ks) * 512 + lane * 8));
            acc = MFMA_BF16(ahf[ks], b, acc);
        }
        float bb = z0_b[ncol];
        #pragma unroll
        for (int q = 0; q < 4; ++q) {
            int m = l4 * 4 + q;
            int row = blk * 16 + m;
            float v = acc[q] + bb;
            if (ncol < 128) out_mean[row * LL + ncol] = v;
            else            out_lv  [row * LL + (ncol - 128)] = v;
        }
    }
}

// ---------------- ODE dynamics eval via MFMA (round-11 verbatim, validated) ----------------

__device__ __forceinline__ void ode_f_mfma(
    const unsigned short* __restrict__ az, unsigned short* __restrict__ h1b,
    unsigned short* __restrict__ h2b, float* __restrict__ fo,
    const unsigned short* __restrict__ B1, const unsigned short* __restrict__ B2,
    const unsigned short* __restrict__ B3,
    const float* __restrict__ tW1,   // tembW1 + ti*256 (includes b1)
    float b2n0, float b2n1, float b3n, int lane, int w) {

    int l4 = lane >> 4, l15 = lane & 15;
    int arow = l15, asw = (arow & 7) << 4;

    // phase A: h1 = tanh(W1z·z + tembW1(t))   K=128 -> 4 ks
    bf16x8 a4[4];
    #pragma unroll
    for (int ks = 0; ks < 4; ++ks)
        a4[ks] = *(const bf16x8*)((const char*)az + (arow * 256 + ((ks * 64 + l4 * 16) ^ asw)));
    #pragma unroll
    for (int gg = 0; gg < 2; ++gg) {
        int nt = 2 * w + gg, n = nt * 16 + l15;
        f32x4 acc = {0,0,0,0};
        #pragma unroll
        for (int ks = 0; ks < 4; ++ks) {
            bf16x8 b = *(const bf16x8*)(B1 + ((nt * 4 + ks) * 512 + lane * 8));
            acc = MFMA_BF16(a4[ks], b, acc);
        }
        float tb = tW1[n];
        #pragma unroll
        for (int q = 0; q < 4; ++q) {
            int m = l4 * 4 + q;
            float v = tanh_f(acc[q] + tb);
            *(unsigned short*)((char*)h1b + (m * 512 + ((n * 2) ^ ((m & 7) << 4)))) = f2bf(v);
        }
    }
    __syncthreads();

    // phase B: h2 = tanh(W2·h1 + b2)   K=256 -> 8 ks
    bf16x8 a8[8];
    #pragma unroll
    for (int ks = 0; ks < 8; ++ks)
        a8[ks] = *(const bf16x8*)((const char*)h1b + (arow * 512 + ((ks * 64 + l4 * 16) ^ asw)));
    #pragma unroll
    for (int gg = 0; gg < 2; ++gg) {
        int nt = 2 * w + gg, n = nt * 16 + l15;
        f32x4 acc = {0,0,0,0};
        #pragma unroll
        for (int ks = 0; ks < 8; ++ks) {
            bf16x8 b = *(const bf16x8*)(B2 + ((nt * 8 + ks) * 512 + lane * 8));
            acc = MFMA_BF16(a8[ks], b, acc);
        }
        float bb = (gg == 0) ? b2n0 : b2n1;
        #pragma unroll
        for (int q = 0; q < 4; ++q) {
            int m = l4 * 4 + q;
            float v = tanh_f(acc[q] + bb);
            *(unsigned short*)((char*)h2b + (m * 512 + ((n * 2) ^ ((m & 7) << 4)))) = f2bf(v);
        }
    }
    __syncthreads();

    // phase C: fo = W3·h2 + b3   N=128, wave w -> tile w
    #pragma unroll
    for (int ks = 0; ks < 8; ++ks)
        a8[ks] = *(const bf16x8*)((const char*)h2b + (arow * 512 + ((ks * 64 + l4 * 16) ^ asw)));
    {
        f32x4 acc = {0,0,0,0};
        #pragma unroll
        for (int ks = 0; ks < 8; ++ks) {
            bf16x8 b = *(const bf16x8*)(B3 + ((w * 8 + ks) * 512 + lane * 8));
            acc = MFMA_BF16(a8[ks], b, acc);
        }
        int n = w * 16 + l15;
        #pragma unroll
        for (int q = 0; q < 4; ++q)
            fo[(l4 * 4 + q) * 128 + n] = acc[q] + b3n;
    }
    __syncthreads();
}

// ---------------- ODE (6-step RK4 + Hermite dense output) + head ----------------

__global__ __launch_bounds__(512, 2) void ode_head_mfma_k(
    const float* __restrict__ zinit,
    const unsigned short* __restrict__ B1, const unsigned short* __restrict__ B2,
    const unsigned short* __restrict__ B3,
    const float* __restrict__ tembW1, const float* __restrict__ b2, const float* __restrict__ b3,
    const float* __restrict__ shw1g, const float* __restrict__ shb1,
    const float* __restrict__ shw2, const float* __restrict__ shb2,
    float* __restrict__ out_haz, float* __restrict__ out_surv, float* __restrict__ out_pg) {

    __shared__ __align__(16) float bufA [2048];              // 8KB z knot s
    __shared__ __align__(16) float bufB [2048];              // 8KB z knot s+1
    __shared__ __align__(16) float bufFP[2048];              // 8KB f knot s
    __shared__ __align__(16) float bufFN[2048];              // 8KB f scratch
    __shared__ __align__(16) float ztl  [2048];              // 8KB stage/z-theta
    __shared__ __align__(16) unsigned short az [16 * 128];   // 4KB bf16 A of state
    __shared__ __align__(16) unsigned short h1b[16 * 256];   // 8KB
    __shared__ __align__(16) unsigned short h2b[16 * 256];   // 8KB
    __shared__ __align__(16) float w1h[32 * 128];            // 16KB head W1 packed

    int tid = threadIdx.x, blk = blockIdx.x;
    int lane = tid & 63, w = tid >> 6;
    int l15 = lane & 15;
    int s5 = tid & 31, rh = tid >> 5;

    float b2n0 = b2[(2 * w) * 16 + l15];
    float b2n1 = b2[(2 * w + 1) * 16 + l15];
    float b3n  = b3[w * 16 + l15];
    float w2s = shw2[s5], b1s = shb1[s5], b2s = shb2[0];
    float cum_r = 0.0f;
    const float4* w1hq = (const float4*)w1h;

    float* zA = bufA; float* zB = bufB;
    float* fP = bufFP; float* fN = bufFN;

    int crow = tid >> 5, ccol = (tid & 31) * 4;
    int azoff = crow * 256 + ((ccol * 2) ^ ((crow & 7) << 4));

    {
        float4 zv = ((const float4*)(zinit + (size_t)blk * 2048))[tid];
        ((float4*)zA)[tid] = zv;
        ushort4 pb; pb.x = f2bf(zv.x); pb.y = f2bf(zv.y); pb.z = f2bf(zv.z); pb.w = f2bf(zv.w);
        *(ushort4*)((char*)az + azoff) = pb;
    }
    for (int e = tid; e < 32 * 128; e += 512) {
        int u = e >> 7, k = e & 127;
        w1h[((k >> 2) * 32 + u) * 4 + (k & 3)] = shw1g[e];
    }
    __syncthreads();

    // f0 = f(z0, t=0)
    ode_f_mfma(az, h1b, h2b, fP, B1, B2, B3, tembW1, b2n0, b2n1, b3n, lane, w);

    const float Hh = 1.0f / (float)NS;

    for (int st = 0; st < NS; ++st) {
        float4 ka, zr0;
        {   // k1 = fP (FSAL)
            float4 f = ((const float4*)fP)[tid];
            zr0 = ((const float4*)zA)[tid];
            ka = f;
            float4 zv = axpy4(0.5f * Hh, f, zr0);
            ((float4*)ztl)[tid] = zv;
            ushort4 pb; pb.x=f2bf(zv.x); pb.y=f2bf(zv.y); pb.z=f2bf(zv.z); pb.w=f2bf(zv.w);
            *(ushort4*)((char*)az + azoff) = pb;
        }
        __syncthreads();
        ode_f_mfma(az, h1b, h2b, fN, B1, B2, B3, tembW1 + (2*st+1)*256, b2n0, b2n1, b3n, lane, w); // k2
        {
            float4 f = ((const float4*)fN)[tid];
            ka = axpy4(2.0f, f, ka);
            float4 zv = axpy4(0.5f * Hh, f, zr0);
            ((float4*)ztl)[tid] = zv;
            ushort4 pb; pb.x=f2bf(zv.x); pb.y=f2bf(zv.y); pb.z=f2bf(zv.z); pb.w=f2bf(zv.w);
            *(ushort4*)((char*)az + azoff) = pb;
        }
        __syncthreads();
        ode_f_mfma(az, h1b, h2b, fN, B1, B2, B3, tembW1 + (2*st+1)*256, b2n0, b2n1, b3n, lane, w); // k3
        {
            float4 f = ((const float4*)fN)[tid];
            ka = axpy4(2.0f, f, ka);
            float4 zv = axpy4(Hh, f, zr0);
            ((float4*)ztl)[tid] = zv;
            ushort4 pb; pb.x=f2bf(zv.x); pb.y=f2bf(zv.y); pb.z=f2bf(zv.z); pb.w=f2bf(zv.w);
            *(ushort4*)((char*)az + azoff) = pb;
        }
        __syncthreads();
        ode_f_mfma(az, h1b, h2b, fN, B1, B2, B3, tembW1 + (2*st+2)*256, b2n0, b2n1, b3n, lane, w); // k4
        {
            float4 f = ((const float4*)fN)[tid];
            float s6 = Hh / 6.0f;
            float4 kk = make_float4(ka.x + f.x, ka.y + f.y, ka.z + f.z, ka.w + f.w);
            float4 zv = axpy4(s6, kk, zr0);
            ((float4*)zB)[tid] = zv;
            ushort4 pb; pb.x=f2bf(zv.x); pb.y=f2bf(zv.y); pb.z=f2bf(zv.z); pb.w=f2bf(zv.w);
            *(ushort4*)((char*)az + azoff) = pb;
        }
        __syncthreads();
        // f_{s+1} (next step's k1, Hermite right-slope)
        ode_f_mfma(az, h1b, h2b, fN, B1, B2, B3, tembW1 + (2*st+2)*256, b2n0, b2n1, b3n, lane, w);

        // ---- emit head at output points inside [st/NS, (st+1)/NS] via Hermite ----
        int jlo = (47 * st + NS - 1) / NS;
        int jhi = (st == NS - 1) ? 47 : (47 * (st + 1) + NS - 1) / NS - 1;
        for (int jp = jlo; jp <= jhi; ++jp) {
            float th  = ((float)NS * (float)jp - 47.0f * (float)st) * (1.0f / 47.0f);
            float th2 = th * th, th3 = th2 * th;
            float c0 = 2.0f * th3 - 3.0f * th2 + 1.0f;
            float c1 = 3.0f * th2 - 2.0f * th3;
            float c2 = Hh * (th3 - 2.0f * th2 + th);
            float c3 = Hh * (th3 - th2);
            {
                float4 za = ((const float4*)zA)[tid];
                float4 zb = ((const float4*)zB)[tid];
                float4 fa = ((const float4*)fP)[tid];
                float4 fb = ((const float4*)fN)[tid];
                float4 zv;
                zv.x = c0*za.x + c1*zb.x + c2*fa.x + c3*fb.x;
                zv.y = c0*za.y + c1*zb.y + c2*fa.y + c3*fb.y;
                zv.z = c0*za.z + c1*zb.z + c2*fa.z + c3*fb.z;
                zv.w = c0*za.w + c1*zb.w + c2*fa.w + c3*fb.w;
                ((float4*)ztl)[tid] = zv;
            }
            __syncthreads();
            {
                float aa = b1s;
                const float4* zrow = (const float4*)(ztl + rh * LL);
                for (int k4 = 0; k4 < 32; ++k4) {
                    float4 wv = w1hq[k4 * 32 + s5];
                    float4 v = zrow[k4];
                    aa = fmaf(wv.x, v.x, aa); aa = fmaf(wv.y, v.y, aa);
                    aa = fmaf(wv.z, v.z, aa); aa = fmaf(wv.w, v.w, aa);
                }
                float p = fmaxf(aa, 0.0f) * w2s;
                p += __shfl_xor(p, 1);  p += __shfl_xor(p, 2);
                p += __shfl_xor(p, 4);  p += __shfl_xor(p, 8);
                p += __shfl_xor(p, 16);
                float hz = sigm_f(p + b2s);
                float sv = __expf(cum_r);
                cum_r += __logf(1.0f - hz + 1e-7f);
                if (s5 == 0) {
                    int row = blk * 16 + rh;
                    out_haz [row * NHZ + jp] = hz;
                    out_surv[row * NHZ + jp] = sv;
                    if (jp == NHZ - 1) out_pg[row] = 1.0f - sv;
                }
            }
            __syncthreads();
        }

        // roll buffers
        float* t0 = zA; zA = zB; zB = t0;
        t0 = fP; fP = fN; fN = t0;
    }
}

// ---------------- launch ----------------

extern "C" void kernel_launch(void* const* d_in, const int* in_sizes, int n_in,
                              void* d_out, int out_size, void* d_ws, size_t ws_size,
                              hipStream_t stream) {
    const float* X        = (const float*)d_in[0];
    const float* Mask     = (const float*)d_in[1];
    const float* gru_w_ih = (const float*)d_in[2];
    const float* gru_w_hh = (const float*)d_in[3];
    const float* gru_b_ih = (const float*)d_in[4];
    const float* gru_b_hh = (const float*)d_in[5];
    const float* z0_w     = (const float*)d_in[6];
    const float* z0_b     = (const float*)d_in[7];
    const float* tproj_w  = (const float*)d_in[8];
    const float* tproj_b  = (const float*)d_in[9];
    const float* ode_w1   = (const float*)d_in[10];
    const float* ode_b1   = (const float*)d_in[11];
    const float* ode_w2   = (const float*)d_in[12];
    const float* ode_b2   = (const float*)d_in[13];
    const float* ode_w3   = (const float*)d_in[14];
    const float* ode_b3   = (const float*)d_in[15];
    const float* sh_w1    = (const float*)d_in[16];
    const float* sh_b1    = (const float*)d_in[17];
    const float* sh_w2    = (const float*)d_in[18];
    const float* sh_b2    = (const float*)d_in[19];

    float* ws     = (float*)d_ws;
    float* tembs  = ws;                        // 104 floats
    float* tembW1 = ws + 256;                  // 13*256 = 3328 -> end 3584
    unsigned short* Brz = (unsigned short*)(ws + 4608);  // 163840
    unsigned short* Bnu = Brz + 163840;                  // 16384
    unsigned short* Bnh = Bnu + 16384;                   // 65536
    unsigned short* Bz0 = Bnh + 65536;                   // 65536
    unsigned short* B1  = Bz0 + 65536;                   // 16*4*512 = 32768
    unsigned short* B2  = B1  + 32768;                   // 16*8*512 = 65536
    unsigned short* B3  = B2  + 65536;                   //  8*8*512 = 32768

    float* out      = (float*)d_out;
    float* out_haz  = out;                              // 4096*48
    float* out_surv = out + 196608;                     // 4096*48
    float* out_mean = out + 393216;                     // 4096*128
    float* out_lv   = out + 917504;                     // 4096*128
    float* out_pg   = out + 1441792;                    // 4096

    temb_k<<<1, 64, 0, stream>>>(tproj_w, tproj_b, tembs);
    tembW1_k<<<(NTEMB * 256 + 255) / 256, 256, 0, stream>>>(ode_w1, ode_b1, tembs, tembW1);

    packBrz_k<<<(32*10*512) / 256, 256, 0, stream>>>(gru_w_ih, gru_w_hh, Brz);
    packB_k<<<(16*2*512) / 256, 256, 0, stream>>>(gru_w_ih + 512 * 64,  Bnu, 64,  16, 2);
    packB_k<<<(16*8*512) / 256, 256, 0, stream>>>(gru_w_hh + 512 * 256, Bnh, 256, 16, 8);
    packB_k<<<(16*8*512) / 256, 256, 0, stream>>>(z0_w,                 Bz0, 256, 16, 8);
    packB_k<<<(16*4*512) / 256, 256, 0, stream>>>(ode_w1, B1, 136, 16, 4);   // k<128 only
    packB_k<<<(16*8*512) / 256, 256, 0, stream>>>(ode_w2, B2, 256, 16, 8);
    packB_k<<<( 8*8*512) / 256, 256, 0, stream>>>(ode_w3, B3, 256,  8, 8);

    gru_mfma_k<<<BB / 16, 1024, 0, stream>>>(X, Mask, Brz, Bnu, Bnh, Bz0,
                                             gru_b_ih, gru_b_hh, z0_b, out_mean, out_lv);

    ode_head_mfma_k<<<BB / 16, 512, 0, stream>>>(out_mean, B1, B2, B3,
                                                 tembW1, ode_b2, ode_b3,
                                                 sh_w1, sh_b1, sh_w2, sh_b2,
                                                 out_haz, out_surv, out_pg);
}

// Round 16
// 418.296 us; speedup vs baseline: 1.8116x; 1.5937x over previous
//
#include <hip/hip_runtime.h>
#include <math.h>

#define BB 4096
#define TT 48
#define DD 32
#define HH 256
#define LL 128
#define HID 256
#define EE 8
#define NHZ 48
#define NS 6              // RK4 macro steps (dense-output Hermite between knots)
#define NTEMB (2*NS+1)    // 13 precomputed time-embeddings

typedef __attribute__((ext_vector_type(8))) short bf16x8;   // 8 bf16 = 4 VGPRs
typedef __attribute__((ext_vector_type(4))) float f32x4;

#define MFMA_BF16(a,b,c) __builtin_amdgcn_mfma_f32_16x16x32_bf16((a),(b),(c),0,0,0)

__device__ __forceinline__ float sigm_f(float x) {
    return 1.0f / (1.0f + __expf(-x));
}
__device__ __forceinline__ float tanh_f(float x) {
    x = fminf(fmaxf(x, -15.0f), 15.0f);
    float e = __expf(2.0f * x);
    return (e - 1.0f) / (e + 1.0f);
}
__device__ __forceinline__ float4 axpy4(float s, float4 a, float4 z) {
    return make_float4(fmaf(s, a.x, z.x), fmaf(s, a.y, z.y),
                       fmaf(s, a.z, z.z), fmaf(s, a.w, z.w));
}
__device__ __forceinline__ unsigned short f2bf(float x) {   // RNE fp32->bf16
    union { float f; unsigned u; } a; a.f = x;
    unsigned r = a.u + 0x7FFFu + ((a.u >> 16) & 1u);
    return (unsigned short)(r >> 16);
}

// ---------------- prep kernels ----------------

__global__ void temb_k(const float* __restrict__ tproj_w, const float* __restrict__ tproj_b,
                       float* __restrict__ tembs) {
    int i = blockIdx.x * 64 + threadIdx.x;
    if (i >= NTEMB) return;
    float t = (float)i / (float)(2 * NS);
    const float PI = 3.14159265358979323846f;
    float emb[8];
    #pragma unroll
    for (int m = 0; m < 4; ++m) {
        float pos = t * (float)(m + 1) * PI;
        emb[m]     = sinf(pos);
        emb[4 + m] = cosf(pos);
    }
    #pragma unroll
    for (int o = 0; o < 8; ++o) {
        float a = tproj_b[o];
        #pragma unroll
        for (int k = 0; k < 8; ++k) a = fmaf(tproj_w[o * 8 + k], emb[k], a);
        tembs[i * 8 + o] = a;
    }
}

// tembW1[ti][n] = b1[n] + sum_k W1[n][128+k] * temb(ti)[k]
__global__ void tembW1_k(const float* __restrict__ w1, const float* __restrict__ b1,
                         const float* __restrict__ tembs, float* __restrict__ out) {
    int i = blockIdx.x * 256 + threadIdx.x;
    if (i >= NTEMB * 256) return;
    int ti = i >> 8, n = i & 255;
    float a = b1[n];
    #pragma unroll
    for (int k = 0; k < 8; ++k) a = fmaf(w1[n * 136 + 128 + k], tembs[ti * 8 + k], a);
    out[i] = a;
}

// B-fragment packers (bf16). Fragment = 512 bf16: element (lane*8+j) holds
// B[k][n] with k = ks*32 + (lane>>4)*8 + j, n = nt*16 + (lane&15).

__global__ void packBrz_k(const float* __restrict__ w_ih, const float* __restrict__ w_hh,
                          unsigned short* __restrict__ dst) {
    int i = blockIdx.x * 256 + threadIdx.x;      // 32 nt * 10 ks * 512
    if (i >= 32 * 10 * 512) return;
    int frag = i >> 9, e = i & 511;
    int lane = e >> 3, j = e & 7;
    int nt = frag / 10, ks = frag % 10;
    int k = ks * 32 + ((lane >> 4) << 3) + j;
    int n = nt * 16 + (lane & 15);
    float v = (k < 64) ? w_ih[n * 64 + k] : w_hh[n * 256 + (k - 64)];
    dst[i] = f2bf(v);
}

__global__ void packB_k(const float* __restrict__ src, unsigned short* __restrict__ dst,
                        int K, int NT, int NKS) {
    int i = blockIdx.x * 256 + threadIdx.x;
    if (i >= NT * NKS * 512) return;
    int frag = i >> 9, e = i & 511;
    int lane = e >> 3, j = e & 7;
    int nt = frag / NKS, ks = frag % NKS;
    int k = ks * 32 + ((lane >> 4) << 3) + j;
    int n = nt * 16 + (lane & 15);
    dst[i] = f2bf(src[n * K + k]);
}

// ---------------- GRU encoder via MFMA (+ fused z0 projection) ----------------
// ROUND-13 EXACT (287us proven): 16 rows/block, 512 threads, grid 256,
// Bnh (131KB) in LDS, non-temporal X/Mask loads, launch_bounds(512,1).

__global__ __launch_bounds__(512, 1) void gru_mfma_k(
    const float* __restrict__ Xp, const float* __restrict__ Mp,
    const unsigned short* __restrict__ Brz,   // [32 nt][10 ks][512]  (L2-streamed)
    const unsigned short* __restrict__ Bnu,   // [16 nt][ 2 ks][512]  (L2-streamed)
    const unsigned short* __restrict__ Bnh,   // [16 nt][ 8 ks][512]  (-> LDS)
    const unsigned short* __restrict__ Bz0,   // [16 nt][ 8 ks][512]
    const float* __restrict__ b_ih, const float* __restrict__ b_hh,
    const float* __restrict__ z0_b,
    float* __restrict__ out_mean, float* __restrict__ out_lv) {

    __shared__ unsigned short h_bf[16 * 256];     // 8KB, swizzled
    __shared__ unsigned short u_bf[16 * 64];      // 2KB, swizzled
    __shared__ unsigned short bnh_lds[16 * 8 * 512]; // 131KB n-gate hh fragments
    __shared__ float obs[16];

    int tid = threadIdx.x, blk = blockIdx.x;
    int lane = tid & 63, w = tid >> 6;
    int l4 = lane >> 4, l15 = lane & 15;

    for (int e = tid; e < 16 * 256; e += 512) h_bf[e] = 0;
    for (int e = tid; e < 8192; e += 512)
        ((f32x4*)bnh_lds)[e] = ((const f32x4*)Bnh)[e];

    float brz0[2], brz1[2], bin_[2], bhn_[2];
    int hcol[2];
    #pragma unroll
    for (int gg = 0; gg < 2; ++gg) {
        int n = (2 * w + gg) * 16 + l15;
        hcol[gg] = n;
        brz0[gg] = b_ih[n]       + b_hh[n];
        brz1[gg] = b_ih[256 + n] + b_hh[256 + n];
        bin_[gg] = b_ih[512 + n];
        bhn_[gg] = b_hh[512 + n];
    }
    float h_st[2][4] = {{0,0,0,0},{0,0,0,0}};

    __syncthreads();

    int arow = l15, asw = (arow & 7) << 4;

    for (int t = TT - 1; t >= 0; --t) {
        if (tid < 256) {
            int r = tid >> 4, c4 = tid & 15;
            const float* base = (c4 < 8 ? Xp : Mp) + (size_t)(blk * 16 + r) * (TT * DD) + t * DD;
            f32x4 v = __builtin_nontemporal_load(((const f32x4*)base) + (c4 & 7));
            ushort4 p;
            p.x = f2bf(v.x); p.y = f2bf(v.y); p.z = f2bf(v.z); p.w = f2bf(v.w);
            int k0 = (c4 < 8) ? c4 * 4 : 32 + (c4 - 8) * 4;
            int off = r * 128 + ((k0 * 2) ^ ((r & 7) << 4));
            *(ushort4*)((char*)u_bf + off) = p;
        }
        if (tid < 16) {
            const f32x4* mrow = (const f32x4*)(Mp + (size_t)(blk * 16 + tid) * (TT * DD) + t * DD);
            float s = 0.0f;
            #pragma unroll
            for (int i = 0; i < 8; ++i) {
                f32x4 v = __builtin_nontemporal_load(mrow + i);
                s += v.x + v.y + v.z + v.w;
            }
            obs[tid] = (s > 0.0f) ? 1.0f : 0.0f;
        }
        bf16x8 ah[8];
        #pragma unroll
        for (int ks = 0; ks < 8; ++ks)
            ah[ks] = *(const bf16x8*)((const char*)h_bf + (arow * 512 + ((ks * 64 + l4 * 16) ^ asw)));
        __syncthreads();

        bf16x8 au[2];
        #pragma unroll
        for (int ks = 0; ks < 2; ++ks)
            au[ks] = *(const bf16x8*)((const char*)u_bf + (arow * 128 + ((ks * 64 + l4 * 16) ^ asw)));

        #pragma unroll
        for (int gg = 0; gg < 2; ++gg) {
            int g = 2 * w + gg;
            f32x4 accr = {0,0,0,0}, accz = {0,0,0,0}, acci = {0,0,0,0}, acch = {0,0,0,0};
            #pragma unroll
            for (int ks = 0; ks < 10; ++ks) {
                bf16x8 a = (ks < 2) ? au[ks] : ah[ks - 2];
                bf16x8 br = *(const bf16x8*)(Brz + ((g * 10 + ks) * 512 + lane * 8));
                bf16x8 bz = *(const bf16x8*)(Brz + (((16 + g) * 10 + ks) * 512 + lane * 8));
                accr = MFMA_BF16(a, br, accr);
                accz = MFMA_BF16(a, bz, accz);
            }
            #pragma unroll
            for (int ks = 0; ks < 2; ++ks) {
                bf16x8 b = *(const bf16x8*)(Bnu + ((g * 2 + ks) * 512 + lane * 8));
                acci = MFMA_BF16(au[ks], b, acci);
            }
            #pragma unroll
            for (int ks = 0; ks < 8; ++ks) {
                bf16x8 b = *(const bf16x8*)(bnh_lds + ((g * 8 + ks) * 512 + lane * 8));
                acch = MFMA_BF16(ah[ks], b, acch);
            }
            #pragma unroll
            for (int q = 0; q < 4; ++q) {
                int m = l4 * 4 + q;
                float rg = sigm_f(accr[q] + brz0[gg]);
                float zg = sigm_f(accz[q] + brz1[gg]);
                float nn = tanh_f(acci[q] + bin_[gg] + rg * (acch[q] + bhn_[gg]));
                float hnew = (1.0f - zg) * nn + zg * h_st[gg][q];
                float o = obs[m];
                float hs = o * hnew + (1.0f - o) * h_st[gg][q];
                h_st[gg][q] = hs;
                int off = m * 512 + ((hcol[gg] * 2) ^ ((m & 7) << 4));
                *(unsigned short*)((char*)h_bf + off) = f2bf(hs);
            }
        }
        __syncthreads();
    }

    bf16x8 ahf[8];
    #pragma unroll
    for (int ks = 0; ks < 8; ++ks)
        ahf[ks] = *(const bf16x8*)((const char*)h_bf + (arow * 512 + ((ks * 64 + l4 * 16) ^ asw)));
    #pragma unroll
    for (int gg = 0; gg < 2; ++gg) {
        int nt = 2 * w + gg;
        f32x4 acc = {0,0,0,0};
        #pragma unroll
        for (int ks = 0; ks < 8; ++ks) {
            bf16x8 b = *(const bf16x8*)(Bz0 + ((nt * 8 + ks) * 512 + lane * 8));
            acc = MFMA_BF16(ahf[ks], b, acc);
        }
        int n = nt * 16 + l15;
        float bb = z0_b[n];
        #pragma unroll
        for (int q = 0; q < 4; ++q) {
            int m = l4 * 4 + q;
            int row = blk * 16 + m;
            float v = acc[q] + bb;
            if (n < 128) out_mean[row * LL + n] = v;
            else         out_lv  [row * LL + (n - 128)] = v;
        }
    }
}

// ---------------- ODE dynamics eval via MFMA (round-11 verbatim, validated) ----------------

__device__ __forceinline__ void ode_f_mfma(
    const unsigned short* __restrict__ az, unsigned short* __restrict__ h1b,
    unsigned short* __restrict__ h2b, float* __restrict__ fo,
    const unsigned short* __restrict__ B1, const unsigned short* __restrict__ B2,
    const unsigned short* __restrict__ B3,
    const float* __restrict__ tW1,   // tembW1 + ti*256 (includes b1)
    float b2n0, float b2n1, float b3n, int lane, int w) {

    int l4 = lane >> 4, l15 = lane & 15;
    int arow = l15, asw = (arow & 7) << 4;

    // phase A: h1 = tanh(W1z·z + tembW1(t))   K=128 -> 4 ks
    bf16x8 a4[4];
    #pragma unroll
    for (int ks = 0; ks < 4; ++ks)
        a4[ks] = *(const bf16x8*)((const char*)az + (arow * 256 + ((ks * 64 + l4 * 16) ^ asw)));
    #pragma unroll
    for (int gg = 0; gg < 2; ++gg) {
        int nt = 2 * w + gg, n = nt * 16 + l15;
        f32x4 acc = {0,0,0,0};
        #pragma unroll
        for (int ks = 0; ks < 4; ++ks) {
            bf16x8 b = *(const bf16x8*)(B1 + ((nt * 4 + ks) * 512 + lane * 8));
            acc = MFMA_BF16(a4[ks], b, acc);
        }
        float tb = tW1[n];
        #pragma unroll
        for (int q = 0; q < 4; ++q) {
            int m = l4 * 4 + q;
            float v = tanh_f(acc[q] + tb);
            *(unsigned short*)((char*)h1b + (m * 512 + ((n * 2) ^ ((m & 7) << 4)))) = f2bf(v);
        }
    }
    __syncthreads();

    // phase B: h2 = tanh(W2·h1 + b2)   K=256 -> 8 ks
    bf16x8 a8[8];
    #pragma unroll
    for (int ks = 0; ks < 8; ++ks)
        a8[ks] = *(const bf16x8*)((const char*)h1b + (arow * 512 + ((ks * 64 + l4 * 16) ^ asw)));
    #pragma unroll
    for (int gg = 0; gg < 2; ++gg) {
        int nt = 2 * w + gg, n = nt * 16 + l15;
        f32x4 acc = {0,0,0,0};
        #pragma unroll
        for (int ks = 0; ks < 8; ++ks) {
            bf16x8 b = *(const bf16x8*)(B2 + ((nt * 8 + ks) * 512 + lane * 8));
            acc = MFMA_BF16(a8[ks], b, acc);
        }
        float bb = (gg == 0) ? b2n0 : b2n1;
        #pragma unroll
        for (int q = 0; q < 4; ++q) {
            int m = l4 * 4 + q;
            float v = tanh_f(acc[q] + bb);
            *(unsigned short*)((char*)h2b + (m * 512 + ((n * 2) ^ ((m & 7) << 4)))) = f2bf(v);
        }
    }
    __syncthreads();

    // phase C: fo = W3·h2 + b3   N=128, wave w -> tile w
    #pragma unroll
    for (int ks = 0; ks < 8; ++ks)
        a8[ks] = *(const bf16x8*)((const char*)h2b + (arow * 512 + ((ks * 64 + l4 * 16) ^ asw)));
    {
        f32x4 acc = {0,0,0,0};
        #pragma unroll
        for (int ks = 0; ks < 8; ++ks) {
            bf16x8 b = *(const bf16x8*)(B3 + ((w * 8 + ks) * 512 + lane * 8));
            acc = MFMA_BF16(a8[ks], b, acc);
        }
        int n = w * 16 + l15;
        #pragma unroll
        for (int q = 0; q < 4; ++q)
            fo[(l4 * 4 + q) * 128 + n] = acc[q] + b3n;
    }
    __syncthreads();
}

// ---------------- ODE (6-step RK4 + Hermite dense output) + head ----------------

__global__ __launch_bounds__(512, 2) void ode_head_mfma_k(
    const float* __restrict__ zinit,
    const unsigned short* __restrict__ B1, const unsigned short* __restrict__ B2,
    const unsigned short* __restrict__ B3,
    const float* __restrict__ tembW1, const float* __restrict__ b2, const float* __restrict__ b3,
    const float* __restrict__ shw1g, const float* __restrict__ shb1,
    const float* __restrict__ shw2, const float* __restrict__ shb2,
    float* __restrict__ out_haz, float* __restrict__ out_surv, float* __restrict__ out_pg) {

    __shared__ __align__(16) float bufA [2048];              // 8KB z knot s
    __shared__ __align__(16) float bufB [2048];              // 8KB z knot s+1
    __shared__ __align__(16) float bufFP[2048];              // 8KB f knot s
    __shared__ __align__(16) float bufFN[2048];              // 8KB f scratch
    __shared__ __align__(16) float ztl  [2048];              // 8KB stage/z-theta
    __shared__ __align__(16) unsigned short az [16 * 128];   // 4KB bf16 A of state
    __shared__ __align__(16) unsigned short h1b[16 * 256];   // 8KB
    __shared__ __align__(16) unsigned short h2b[16 * 256];   // 8KB
    __shared__ __align__(16) float w1h[32 * 128];            // 16KB head W1 packed

    int tid = threadIdx.x, blk = blockIdx.x;
    int lane = tid & 63, w = tid >> 6;
    int l15 = lane & 15;
    int s5 = tid & 31, rh = tid >> 5;

    float b2n0 = b2[(2 * w) * 16 + l15];
    float b2n1 = b2[(2 * w + 1) * 16 + l15];
    float b3n  = b3[w * 16 + l15];
    float w2s = shw2[s5], b1s = shb1[s5], b2s = shb2[0];
    float cum_r = 0.0f;
    const float4* w1hq = (const float4*)w1h;

    float* zA = bufA; float* zB = bufB;
    float* fP = bufFP; float* fN = bufFN;

    int crow = tid >> 5, ccol = (tid & 31) * 4;
    int azoff = crow * 256 + ((ccol * 2) ^ ((crow & 7) << 4));

    {
        float4 zv = ((const float4*)(zinit + (size_t)blk * 2048))[tid];
        ((float4*)zA)[tid] = zv;
        ushort4 pb; pb.x = f2bf(zv.x); pb.y = f2bf(zv.y); pb.z = f2bf(zv.z); pb.w = f2bf(zv.w);
        *(ushort4*)((char*)az + azoff) = pb;
    }
    for (int e = tid; e < 32 * 128; e += 512) {
        int u = e >> 7, k = e & 127;
        w1h[((k >> 2) * 32 + u) * 4 + (k & 3)] = shw1g[e];
    }
    __syncthreads();

    // f0 = f(z0, t=0)
    ode_f_mfma(az, h1b, h2b, fP, B1, B2, B3, tembW1, b2n0, b2n1, b3n, lane, w);

    const float Hh = 1.0f / (float)NS;

    for (int st = 0; st < NS; ++st) {
        float4 ka, zr0;
        {   // k1 = fP (FSAL)
            float4 f = ((const float4*)fP)[tid];
            zr0 = ((const float4*)zA)[tid];
            ka = f;
            float4 zv = axpy4(0.5f * Hh, f, zr0);
            ((float4*)ztl)[tid] = zv;
            ushort4 pb; pb.x=f2bf(zv.x); pb.y=f2bf(zv.y); pb.z=f2bf(zv.z); pb.w=f2bf(zv.w);
            *(ushort4*)((char*)az + azoff) = pb;
        }
        __syncthreads();
        ode_f_mfma(az, h1b, h2b, fN, B1, B2, B3, tembW1 + (2*st+1)*256, b2n0, b2n1, b3n, lane, w); // k2
        {
            float4 f = ((const float4*)fN)[tid];
            ka = axpy4(2.0f, f, ka);
            float4 zv = axpy4(0.5f * Hh, f, zr0);
            ((float4*)ztl)[tid] = zv;
            ushort4 pb; pb.x=f2bf(zv.x); pb.y=f2bf(zv.y); pb.z=f2bf(zv.z); pb.w=f2bf(zv.w);
            *(ushort4*)((char*)az + azoff) = pb;
        }
        __syncthreads();
        ode_f_mfma(az, h1b, h2b, fN, B1, B2, B3, tembW1 + (2*st+1)*256, b2n0, b2n1, b3n, lane, w); // k3
        {
            float4 f = ((const float4*)fN)[tid];
            ka = axpy4(2.0f, f, ka);
            float4 zv = axpy4(Hh, f, zr0);
            ((float4*)ztl)[tid] = zv;
            ushort4 pb; pb.x=f2bf(zv.x); pb.y=f2bf(zv.y); pb.z=f2bf(zv.z); pb.w=f2bf(zv.w);
            *(ushort4*)((char*)az + azoff) = pb;
        }
        __syncthreads();
        ode_f_mfma(az, h1b, h2b, fN, B1, B2, B3, tembW1 + (2*st+2)*256, b2n0, b2n1, b3n, lane, w); // k4
        {
            float4 f = ((const float4*)fN)[tid];
            float s6 = Hh / 6.0f;
            float4 kk = make_float4(ka.x + f.x, ka.y + f.y, ka.z + f.z, ka.w + f.w);
            float4 zv = axpy4(s6, kk, zr0);
            ((float4*)zB)[tid] = zv;
            ushort4 pb; pb.x=f2bf(zv.x); pb.y=f2bf(zv.y); pb.z=f2bf(zv.z); pb.w=f2bf(zv.w);
            *(ushort4*)((char*)az + azoff) = pb;
        }
        __syncthreads();
        // f_{s+1} (next step's k1, Hermite right-slope)
        ode_f_mfma(az, h1b, h2b, fN, B1, B2, B3, tembW1 + (2*st+2)*256, b2n0, b2n1, b3n, lane, w);

        // ---- emit head at output points inside [st/NS, (st+1)/NS] via Hermite ----
        int jlo = (47 * st + NS - 1) / NS;
        int jhi = (st == NS - 1) ? 47 : (47 * (st + 1) + NS - 1) / NS - 1;
        for (int jp = jlo; jp <= jhi; ++jp) {
            float th  = ((float)NS * (float)jp - 47.0f * (float)st) * (1.0f / 47.0f);
            float th2 = th * th, th3 = th2 * th;
            float c0 = 2.0f * th3 - 3.0f * th2 + 1.0f;
            float c1 = 3.0f * th2 - 2.0f * th3;
            float c2 = Hh * (th3 - 2.0f * th2 + th);
            float c3 = Hh * (th3 - th2);
            {
                float4 za = ((const float4*)zA)[tid];
                float4 zb = ((const float4*)zB)[tid];
                float4 fa = ((const float4*)fP)[tid];
                float4 fb = ((const float4*)fN)[tid];
                float4 zv;
                zv.x = c0*za.x + c1*zb.x + c2*fa.x + c3*fb.x;
                zv.y = c0*za.y + c1*zb.y + c2*fa.y + c3*fb.y;
                zv.z = c0*za.z + c1*zb.z + c2*fa.z + c3*fb.z;
                zv.w = c0*za.w + c1*zb.w + c2*fa.w + c3*fb.w;
                ((float4*)ztl)[tid] = zv;
            }
            __syncthreads();
            {
                float aa = b1s;
                const float4* zrow = (const float4*)(ztl + rh * LL);
                for (int k4 = 0; k4 < 32; ++k4) {
                    float4 wv = w1hq[k4 * 32 + s5];
                    float4 v = zrow[k4];
                    aa = fmaf(wv.x, v.x, aa); aa = fmaf(wv.y, v.y, aa);
                    aa = fmaf(wv.z, v.z, aa); aa = fmaf(wv.w, v.w, aa);
                }
                float p = fmaxf(aa, 0.0f) * w2s;
                p += __shfl_xor(p, 1);  p += __shfl_xor(p, 2);
                p += __shfl_xor(p, 4);  p += __shfl_xor(p, 8);
                p += __shfl_xor(p, 16);
                float hz = sigm_f(p + b2s);
                float sv = __expf(cum_r);
                cum_r += __logf(1.0f - hz + 1e-7f);
                if (s5 == 0) {
                    int row = blk * 16 + rh;
                    out_haz [row * NHZ + jp] = hz;
                    out_surv[row * NHZ + jp] = sv;
                    if (jp == NHZ - 1) out_pg[row] = 1.0f - sv;
                }
            }
            __syncthreads();
        }

        // roll buffers
        float* t0 = zA; zA = zB; zB = t0;
        t0 = fP; fP = fN; fN = t0;
    }
}

// ---------------- launch ----------------

extern "C" void kernel_launch(void* const* d_in, const int* in_sizes, int n_in,
                              void* d_out, int out_size, void* d_ws, size_t ws_size,
                              hipStream_t stream) {
    const float* X        = (const float*)d_in[0];
    const float* Mask     = (const float*)d_in[1];
    const float* gru_w_ih = (const float*)d_in[2];
    const float* gru_w_hh = (const float*)d_in[3];
    const float* gru_b_ih = (const float*)d_in[4];
    const float* gru_b_hh = (const float*)d_in[5];
    const float* z0_w     = (const float*)d_in[6];
    const float* z0_b     = (const float*)d_in[7];
    const float* tproj_w  = (const float*)d_in[8];
    const float* tproj_b  = (const float*)d_in[9];
    const float* ode_w1   = (const float*)d_in[10];
    const float* ode_b1   = (const float*)d_in[11];
    const float* ode_w2   = (const float*)d_in[12];
    const float* ode_b2   = (const float*)d_in[13];
    const float* ode_w3   = (const float*)d_in[14];
    const float* ode_b3   = (const float*)d_in[15];
    const float* sh_w1    = (const float*)d_in[16];
    const float* sh_b1    = (const float*)d_in[17];
    const float* sh_w2    = (const float*)d_in[18];
    const float* sh_b2    = (const float*)d_in[19];

    float* ws     = (float*)d_ws;
    float* tembs  = ws;                        // 104 floats
    float* tembW1 = ws + 256;                  // 13*256 = 3328 -> end 3584
    unsigned short* Brz = (unsigned short*)(ws + 4608);  // 163840
    unsigned short* Bnu = Brz + 163840;                  // 16384
    unsigned short* Bnh = Bnu + 16384;                   // 65536
    unsigned short* Bz0 = Bnh + 65536;                   // 65536
    unsigned short* B1  = Bz0 + 65536;                   // 16*4*512 = 32768
    unsigned short* B2  = B1  + 32768;                   // 16*8*512 = 65536
    unsigned short* B3  = B2  + 65536;                   //  8*8*512 = 32768

    float* out      = (float*)d_out;
    float* out_haz  = out;                              // 4096*48
    float* out_surv = out + 196608;                     // 4096*48
    float* out_mean = out + 393216;                     // 4096*128
    float* out_lv   = out + 917504;                     // 4096*128
    float* out_pg   = out + 1441792;                    // 4096

    temb_k<<<1, 64, 0, stream>>>(tproj_w, tproj_b, tembs);
    tembW1_k<<<(NTEMB * 256 + 255) / 256, 256, 0, stream>>>(ode_w1, ode_b1, tembs, tembW1);

    packBrz_k<<<(32*10*512) / 256, 256, 0, stream>>>(gru_w_ih, gru_w_hh, Brz);
    packB_k<<<(16*2*512) / 256, 256, 0, stream>>>(gru_w_ih + 512 * 64,  Bnu, 64,  16, 2);
    packB_k<<<(16*8*512) / 256, 256, 0, stream>>>(gru_w_hh + 512 * 256, Bnh, 256, 16, 8);
    packB_k<<<(16*8*512) / 256, 256, 0, stream>>>(z0_w,                 Bz0, 256, 16, 8);
    packB_k<<<(16*4*512) / 256, 256, 0, stream>>>(ode_w1, B1, 136, 16, 4);   // k<128 only
    packB_k<<<(16*8*512) / 256, 256, 0, stream>>>(ode_w2, B2, 256, 16, 8);
    packB_k<<<( 8*8*512) / 256, 256, 0, stream>>>(ode_w3, B3, 256,  8, 8);

    gru_mfma_k<<<BB / 16, 512, 0, stream>>>(X, Mask, Brz, Bnu, Bnh, Bz0,
                                            gru_b_ih, gru_b_hh, z0_b, out_mean, out_lv);

    ode_head_mfma_k<<<BB / 16, 512, 0, stream>>>(out_mean, B1, B2, B3,
                                                 tembW1, ode_b2, ode_b3,
                                                 sh_w1, sh_b1, sh_w2, sh_b2,
                                                 out_haz, out_surv, out_pg);
}

// Round 17
// 402.610 us; speedup vs baseline: 1.8822x; 1.0390x over previous
//
#include <hip/hip_runtime.h>
#include <math.h>

#define BB 4096
#define TT 48
#define DD 32
#define HH 256
#define LL 128
#define HID 256
#define EE 8
#define NHZ 48
#define NS 6              // RK4 macro steps (dense-output Hermite between knots)
#define NTEMB (2*NS+1)    // 13 precomputed time-embeddings

typedef __attribute__((ext_vector_type(8))) short bf16x8;   // 8 bf16 = 4 VGPRs
typedef __attribute__((ext_vector_type(4))) float f32x4;

#define MFMA_BF16(a,b,c) __builtin_amdgcn_mfma_f32_16x16x32_bf16((a),(b),(c),0,0,0)

__device__ __forceinline__ float sigm_f(float x) {
    return 1.0f / (1.0f + __expf(-x));
}
__device__ __forceinline__ float tanh_f(float x) {
    x = fminf(fmaxf(x, -15.0f), 15.0f);
    float e = __expf(2.0f * x);
    return (e - 1.0f) / (e + 1.0f);
}
__device__ __forceinline__ float4 axpy4(float s, float4 a, float4 z) {
    return make_float4(fmaf(s, a.x, z.x), fmaf(s, a.y, z.y),
                       fmaf(s, a.z, z.z), fmaf(s, a.w, z.w));
}
__device__ __forceinline__ unsigned short f2bf(float x) {   // RNE fp32->bf16
    union { float f; unsigned u; } a; a.f = x;
    unsigned r = a.u + 0x7FFFu + ((a.u >> 16) & 1u);
    return (unsigned short)(r >> 16);
}

// ---------------- prep kernels ----------------

__global__ void temb_k(const float* __restrict__ tproj_w, const float* __restrict__ tproj_b,
                       float* __restrict__ tembs) {
    int i = blockIdx.x * 64 + threadIdx.x;
    if (i >= NTEMB) return;
    float t = (float)i / (float)(2 * NS);
    const float PI = 3.14159265358979323846f;
    float emb[8];
    #pragma unroll
    for (int m = 0; m < 4; ++m) {
        float pos = t * (float)(m + 1) * PI;
        emb[m]     = sinf(pos);
        emb[4 + m] = cosf(pos);
    }
    #pragma unroll
    for (int o = 0; o < 8; ++o) {
        float a = tproj_b[o];
        #pragma unroll
        for (int k = 0; k < 8; ++k) a = fmaf(tproj_w[o * 8 + k], emb[k], a);
        tembs[i * 8 + o] = a;
    }
}

// tembW1[ti][n] = b1[n] + sum_k W1[n][128+k] * temb(ti)[k]
__global__ void tembW1_k(const float* __restrict__ w1, const float* __restrict__ b1,
                         const float* __restrict__ tembs, float* __restrict__ out) {
    int i = blockIdx.x * 256 + threadIdx.x;
    if (i >= NTEMB * 256) return;
    int ti = i >> 8, n = i & 255;
    float a = b1[n];
    #pragma unroll
    for (int k = 0; k < 8; ++k) a = fmaf(w1[n * 136 + 128 + k], tembs[ti * 8 + k], a);
    out[i] = a;
}

// B-fragment packers (bf16). Fragment = 512 bf16: element (lane*8+j) holds
// B[k][n] with k = ks*32 + (lane>>4)*8 + j, n = nt*16 + (lane&15).

__global__ void packBrz_k(const float* __restrict__ w_ih, const float* __restrict__ w_hh,
                          unsigned short* __restrict__ dst) {
    int i = blockIdx.x * 256 + threadIdx.x;      // 32 nt * 10 ks * 512
    if (i >= 32 * 10 * 512) return;
    int frag = i >> 9, e = i & 511;
    int lane = e >> 3, j = e & 7;
    int nt = frag / 10, ks = frag % 10;
    int k = ks * 32 + ((lane >> 4) << 3) + j;
    int n = nt * 16 + (lane & 15);
    float v = (k < 64) ? w_ih[n * 64 + k] : w_hh[n * 256 + (k - 64)];
    dst[i] = f2bf(v);
}

__global__ void packB_k(const float* __restrict__ src, unsigned short* __restrict__ dst,
                        int K, int NT, int NKS) {
    int i = blockIdx.x * 256 + threadIdx.x;
    if (i >= NT * NKS * 512) return;
    int frag = i >> 9, e = i & 511;
    int lane = e >> 3, j = e & 7;
    int nt = frag / NKS, ks = frag % NKS;
    int k = ks * 32 + ((lane >> 4) << 3) + j;
    int n = nt * 16 + (lane & 15);
    dst[i] = f2bf(src[n * K + k]);
}

// ---------------- GRU encoder via MFMA (+ fused z0 projection) ----------------
// Round-13 structure (287us). NEW: gate-group 0's r/z B-fragments (20) + both
// groups' Bnu (4) hoisted into registers before the t-loop (time-invariant,
// 48x reuse) -- streamed L2 weight traffic drops 352->164 KB/block/t.

__global__ __launch_bounds__(512, 1) void gru_mfma_k(
    const float* __restrict__ Xp, const float* __restrict__ Mp,
    const unsigned short* __restrict__ Brz,   // [32 nt][10 ks][512]
    const unsigned short* __restrict__ Bnu,   // [16 nt][ 2 ks][512]
    const unsigned short* __restrict__ Bnh,   // [16 nt][ 8 ks][512]  (-> LDS)
    const unsigned short* __restrict__ Bz0,   // [16 nt][ 8 ks][512]
    const float* __restrict__ b_ih, const float* __restrict__ b_hh,
    const float* __restrict__ z0_b,
    float* __restrict__ out_mean, float* __restrict__ out_lv) {

    __shared__ unsigned short h_bf[16 * 256];        // 8KB, swizzled
    __shared__ unsigned short u_bf[16 * 64];         // 2KB, swizzled
    __shared__ unsigned short bnh_lds[16 * 8 * 512]; // 131KB n-gate hh fragments
    __shared__ float obs[16];

    int tid = threadIdx.x, blk = blockIdx.x;
    int lane = tid & 63, w = tid >> 6;
    int l4 = lane >> 4, l15 = lane & 15;

    for (int e = tid; e < 16 * 256; e += 512) h_bf[e] = 0;
    for (int e = tid; e < 8192; e += 512)
        ((f32x4*)bnh_lds)[e] = ((const f32x4*)Bnh)[e];

    float brz0[2], brz1[2], bin_[2], bhn_[2];
    int hcol[2];
    #pragma unroll
    for (int gg = 0; gg < 2; ++gg) {
        int n = (2 * w + gg) * 16 + l15;
        hcol[gg] = n;
        brz0[gg] = b_ih[n]       + b_hh[n];
        brz1[gg] = b_ih[256 + n] + b_hh[256 + n];
        bin_[gg] = b_ih[512 + n];
        bhn_[gg] = b_hh[512 + n];
    }
    float h_st[2][4] = {{0,0,0,0},{0,0,0,0}};

    // ---- hoist time-invariant fragments: group 0's r/z (20) + both Bnu (4) ----
    bf16x8 hbr[10], hbz[10], hbu[2][2];
    {
        int g0 = 2 * w;
        #pragma unroll
        for (int ks = 0; ks < 10; ++ks) {
            hbr[ks] = *(const bf16x8*)(Brz + ((g0 * 10 + ks) * 512 + lane * 8));
            hbz[ks] = *(const bf16x8*)(Brz + (((16 + g0) * 10 + ks) * 512 + lane * 8));
        }
        #pragma unroll
        for (int gg = 0; gg < 2; ++gg)
            #pragma unroll
            for (int ks = 0; ks < 2; ++ks)
                hbu[gg][ks] = *(const bf16x8*)(Bnu + (((g0 + gg) * 2 + ks) * 512 + lane * 8));
    }

    __syncthreads();

    int arow = l15, asw = (arow & 7) << 4;

    for (int t = TT - 1; t >= 0; --t) {
        if (tid < 256) {
            int r = tid >> 4, c4 = tid & 15;
            const float* base = (c4 < 8 ? Xp : Mp) + (size_t)(blk * 16 + r) * (TT * DD) + t * DD;
            f32x4 v = __builtin_nontemporal_load(((const f32x4*)base) + (c4 & 7));
            ushort4 p;
            p.x = f2bf(v.x); p.y = f2bf(v.y); p.z = f2bf(v.z); p.w = f2bf(v.w);
            int k0 = (c4 < 8) ? c4 * 4 : 32 + (c4 - 8) * 4;
            int off = r * 128 + ((k0 * 2) ^ ((r & 7) << 4));
            *(ushort4*)((char*)u_bf + off) = p;
        }
        if (tid < 16) {
            const f32x4* mrow = (const f32x4*)(Mp + (size_t)(blk * 16 + tid) * (TT * DD) + t * DD);
            float s = 0.0f;
            #pragma unroll
            for (int i = 0; i < 8; ++i) {
                f32x4 v = __builtin_nontemporal_load(mrow + i);
                s += v.x + v.y + v.z + v.w;
            }
            obs[tid] = (s > 0.0f) ? 1.0f : 0.0f;
        }
        bf16x8 ah[8];
        #pragma unroll
        for (int ks = 0; ks < 8; ++ks)
            ah[ks] = *(const bf16x8*)((const char*)h_bf + (arow * 512 + ((ks * 64 + l4 * 16) ^ asw)));
        __syncthreads();

        bf16x8 au[2];
        #pragma unroll
        for (int ks = 0; ks < 2; ++ks)
            au[ks] = *(const bf16x8*)((const char*)u_bf + (arow * 128 + ((ks * 64 + l4 * 16) ^ asw)));

        #pragma unroll
        for (int gg = 0; gg < 2; ++gg) {
            int g = 2 * w + gg;
            f32x4 accr = {0,0,0,0}, accz = {0,0,0,0}, acci = {0,0,0,0}, acch = {0,0,0,0};
            #pragma unroll
            for (int ks = 0; ks < 10; ++ks) {
                bf16x8 a = (ks < 2) ? au[ks] : ah[ks - 2];
                bf16x8 br = (gg == 0) ? hbr[ks]
                          : *(const bf16x8*)(Brz + ((g * 10 + ks) * 512 + lane * 8));
                bf16x8 bz = (gg == 0) ? hbz[ks]
                          : *(const bf16x8*)(Brz + (((16 + g) * 10 + ks) * 512 + lane * 8));
                accr = MFMA_BF16(a, br, accr);
                accz = MFMA_BF16(a, bz, accz);
            }
            #pragma unroll
            for (int ks = 0; ks < 2; ++ks)
                acci = MFMA_BF16(au[ks], hbu[gg][ks], acci);
            #pragma unroll
            for (int ks = 0; ks < 8; ++ks) {
                bf16x8 b = *(const bf16x8*)(bnh_lds + ((g * 8 + ks) * 512 + lane * 8));
                acch = MFMA_BF16(ah[ks], b, acch);
            }
            #pragma unroll
            for (int q = 0; q < 4; ++q) {
                int m = l4 * 4 + q;
                float rg = sigm_f(accr[q] + brz0[gg]);
                float zg = sigm_f(accz[q] + brz1[gg]);
                float nn = tanh_f(acci[q] + bin_[gg] + rg * (acch[q] + bhn_[gg]));
                float hnew = (1.0f - zg) * nn + zg * h_st[gg][q];
                float o = obs[m];
                float hs = o * hnew + (1.0f - o) * h_st[gg][q];
                h_st[gg][q] = hs;
                int off = m * 512 + ((hcol[gg] * 2) ^ ((m & 7) << 4));
                *(unsigned short*)((char*)h_bf + off) = f2bf(hs);
            }
        }
        __syncthreads();
    }

    bf16x8 ahf[8];
    #pragma unroll
    for (int ks = 0; ks < 8; ++ks)
        ahf[ks] = *(const bf16x8*)((const char*)h_bf + (arow * 512 + ((ks * 64 + l4 * 16) ^ asw)));
    #pragma unroll
    for (int gg = 0; gg < 2; ++gg) {
        int nt = 2 * w + gg;
        f32x4 acc = {0,0,0,0};
        #pragma unroll
        for (int ks = 0; ks < 8; ++ks) {
            bf16x8 b = *(const bf16x8*)(Bz0 + ((nt * 8 + ks) * 512 + lane * 8));
            acc = MFMA_BF16(ahf[ks], b, acc);
        }
        int n = nt * 16 + l15;
        float bb = z0_b[n];
        #pragma unroll
        for (int q = 0; q < 4; ++q) {
            int m = l4 * 4 + q;
            int row = blk * 16 + m;
            float v = acc[q] + bb;
            if (n < 128) out_mean[row * LL + n] = v;
            else         out_lv  [row * LL + (n - 128)] = v;
        }
    }
}

// ---------------- ODE dynamics eval via MFMA (round-11 verbatim, validated) ----------------

__device__ __forceinline__ void ode_f_mfma(
    const unsigned short* __restrict__ az, unsigned short* __restrict__ h1b,
    unsigned short* __restrict__ h2b, float* __restrict__ fo,
    const unsigned short* __restrict__ B1, const unsigned short* __restrict__ B2,
    const unsigned short* __restrict__ B3,
    const float* __restrict__ tW1,   // tembW1 + ti*256 (includes b1)
    float b2n0, float b2n1, float b3n, int lane, int w) {

    int l4 = lane >> 4, l15 = lane & 15;
    int arow = l15, asw = (arow & 7) << 4;

    // phase A: h1 = tanh(W1z·z + tembW1(t))   K=128 -> 4 ks
    bf16x8 a4[4];
    #pragma unroll
    for (int ks = 0; ks < 4; ++ks)
        a4[ks] = *(const bf16x8*)((const char*)az + (arow * 256 + ((ks * 64 + l4 * 16) ^ asw)));
    #pragma unroll
    for (int gg = 0; gg < 2; ++gg) {
        int nt = 2 * w + gg, n = nt * 16 + l15;
        f32x4 acc = {0,0,0,0};
        #pragma unroll
        for (int ks = 0; ks < 4; ++ks) {
            bf16x8 b = *(const bf16x8*)(B1 + ((nt * 4 + ks) * 512 + lane * 8));
            acc = MFMA_BF16(a4[ks], b, acc);
        }
        float tb = tW1[n];
        #pragma unroll
        for (int q = 0; q < 4; ++q) {
            int m = l4 * 4 + q;
            float v = tanh_f(acc[q] + tb);
            *(unsigned short*)((char*)h1b + (m * 512 + ((n * 2) ^ ((m & 7) << 4)))) = f2bf(v);
        }
    }
    __syncthreads();

    // phase B: h2 = tanh(W2·h1 + b2)   K=256 -> 8 ks
    bf16x8 a8[8];
    #pragma unroll
    for (int ks = 0; ks < 8; ++ks)
        a8[ks] = *(const bf16x8*)((const char*)h1b + (arow * 512 + ((ks * 64 + l4 * 16) ^ asw)));
    #pragma unroll
    for (int gg = 0; gg < 2; ++gg) {
        int nt = 2 * w + gg, n = nt * 16 + l15;
        f32x4 acc = {0,0,0,0};
        #pragma unroll
        for (int ks = 0; ks < 8; ++ks) {
            bf16x8 b = *(const bf16x8*)(B2 + ((nt * 8 + ks) * 512 + lane * 8));
            acc = MFMA_BF16(a8[ks], b, acc);
        }
        float bb = (gg == 0) ? b2n0 : b2n1;
        #pragma unroll
        for (int q = 0; q < 4; ++q) {
            int m = l4 * 4 + q;
            float v = tanh_f(acc[q] + bb);
            *(unsigned short*)((char*)h2b + (m * 512 + ((n * 2) ^ ((m & 7) << 4)))) = f2bf(v);
        }
    }
    __syncthreads();

    // phase C: fo = W3·h2 + b3   N=128, wave w -> tile w
    #pragma unroll
    for (int ks = 0; ks < 8; ++ks)
        a8[ks] = *(const bf16x8*)((const char*)h2b + (arow * 512 + ((ks * 64 + l4 * 16) ^ asw)));
    {
        f32x4 acc = {0,0,0,0};
        #pragma unroll
        for (int ks = 0; ks < 8; ++ks) {
            bf16x8 b = *(const bf16x8*)(B3 + ((w * 8 + ks) * 512 + lane * 8));
            acc = MFMA_BF16(a8[ks], b, acc);
        }
        int n = w * 16 + l15;
        #pragma unroll
        for (int q = 0; q < 4; ++q)
            fo[(l4 * 4 + q) * 128 + n] = acc[q] + b3n;
    }
    __syncthreads();
}

// ---------------- ODE (6-step RK4 + Hermite dense output) + head ----------------

__global__ __launch_bounds__(512, 2) void ode_head_mfma_k(
    const float* __restrict__ zinit,
    const unsigned short* __restrict__ B1, const unsigned short* __restrict__ B2,
    const unsigned short* __restrict__ B3,
    const float* __restrict__ tembW1, const float* __restrict__ b2, const float* __restrict__ b3,
    const float* __restrict__ shw1g, const float* __restrict__ shb1,
    const float* __restrict__ shw2, const float* __restrict__ shb2,
    float* __restrict__ out_haz, float* __restrict__ out_surv, float* __restrict__ out_pg) {

    __shared__ __align__(16) float bufA [2048];              // 8KB z knot s
    __shared__ __align__(16) float bufB [2048];              // 8KB z knot s+1
    __shared__ __align__(16) float bufFP[2048];              // 8KB f knot s
    __shared__ __align__(16) float bufFN[2048];              // 8KB f scratch
    __shared__ __align__(16) float ztl  [2048];              // 8KB stage/z-theta
    __shared__ __align__(16) unsigned short az [16 * 128];   // 4KB bf16 A of state
    __shared__ __align__(16) unsigned short h1b[16 * 256];   // 8KB
    __shared__ __align__(16) unsigned short h2b[16 * 256];   // 8KB
    __shared__ __align__(16) float w1h[32 * 128];            // 16KB head W1 packed

    int tid = threadIdx.x, blk = blockIdx.x;
    int lane = tid & 63, w = tid >> 6;
    int l15 = lane & 15;
    int s5 = tid & 31, rh = tid >> 5;

    float b2n0 = b2[(2 * w) * 16 + l15];
    float b2n1 = b2[(2 * w + 1) * 16 + l15];
    float b3n  = b3[w * 16 + l15];
    float w2s = shw2[s5], b1s = shb1[s5], b2s = shb2[0];
    float cum_r = 0.0f;
    const float4* w1hq = (const float4*)w1h;

    float* zA = bufA; float* zB = bufB;
    float* fP = bufFP; float* fN = bufFN;

    int crow = tid >> 5, ccol = (tid & 31) * 4;
    int azoff = crow * 256 + ((ccol * 2) ^ ((crow & 7) << 4));

    {
        float4 zv = ((const float4*)(zinit + (size_t)blk * 2048))[tid];
        ((float4*)zA)[tid] = zv;
        ushort4 pb; pb.x = f2bf(zv.x); pb.y = f2bf(zv.y); pb.z = f2bf(zv.z); pb.w = f2bf(zv.w);
        *(ushort4*)((char*)az + azoff) = pb;
    }
    for (int e = tid; e < 32 * 128; e += 512) {
        int u = e >> 7, k = e & 127;
        w1h[((k >> 2) * 32 + u) * 4 + (k & 3)] = shw1g[e];
    }
    __syncthreads();

    // f0 = f(z0, t=0)
    ode_f_mfma(az, h1b, h2b, fP, B1, B2, B3, tembW1, b2n0, b2n1, b3n, lane, w);

    const float Hh = 1.0f / (float)NS;

    for (int st = 0; st < NS; ++st) {
        float4 ka, zr0;
        {   // k1 = fP (FSAL)
            float4 f = ((const float4*)fP)[tid];
            zr0 = ((const float4*)zA)[tid];
            ka = f;
            float4 zv = axpy4(0.5f * Hh, f, zr0);
            ((float4*)ztl)[tid] = zv;
            ushort4 pb; pb.x=f2bf(zv.x); pb.y=f2bf(zv.y); pb.z=f2bf(zv.z); pb.w=f2bf(zv.w);
            *(ushort4*)((char*)az + azoff) = pb;
        }
        __syncthreads();
        ode_f_mfma(az, h1b, h2b, fN, B1, B2, B3, tembW1 + (2*st+1)*256, b2n0, b2n1, b3n, lane, w); // k2
        {
            float4 f = ((const float4*)fN)[tid];
            ka = axpy4(2.0f, f, ka);
            float4 zv = axpy4(0.5f * Hh, f, zr0);
            ((float4*)ztl)[tid] = zv;
            ushort4 pb; pb.x=f2bf(zv.x); pb.y=f2bf(zv.y); pb.z=f2bf(zv.z); pb.w=f2bf(zv.w);
            *(ushort4*)((char*)az + azoff) = pb;
        }
        __syncthreads();
        ode_f_mfma(az, h1b, h2b, fN, B1, B2, B3, tembW1 + (2*st+1)*256, b2n0, b2n1, b3n, lane, w); // k3
        {
            float4 f = ((const float4*)fN)[tid];
            ka = axpy4(2.0f, f, ka);
            float4 zv = axpy4(Hh, f, zr0);
            ((float4*)ztl)[tid] = zv;
            ushort4 pb; pb.x=f2bf(zv.x); pb.y=f2bf(zv.y); pb.z=f2bf(zv.z); pb.w=f2bf(zv.w);
            *(ushort4*)((char*)az + azoff) = pb;
        }
        __syncthreads();
        ode_f_mfma(az, h1b, h2b, fN, B1, B2, B3, tembW1 + (2*st+2)*256, b2n0, b2n1, b3n, lane, w); // k4
        {
            float4 f = ((const float4*)fN)[tid];
            float s6 = Hh / 6.0f;
            float4 kk = make_float4(ka.x + f.x, ka.y + f.y, ka.z + f.z, ka.w + f.w);
            float4 zv = axpy4(s6, kk, zr0);
            ((float4*)zB)[tid] = zv;
            ushort4 pb; pb.x=f2bf(zv.x); pb.y=f2bf(zv.y); pb.z=f2bf(zv.z); pb.w=f2bf(zv.w);
            *(ushort4*)((char*)az + azoff) = pb;
        }
        __syncthreads();
        // f_{s+1} (next step's k1, Hermite right-slope)
        ode_f_mfma(az, h1b, h2b, fN, B1, B2, B3, tembW1 + (2*st+2)*256, b2n0, b2n1, b3n, lane, w);

        // ---- emit head at output points inside [st/NS, (st+1)/NS] via Hermite ----
        int jlo = (47 * st + NS - 1) / NS;
        int jhi = (st == NS - 1) ? 47 : (47 * (st + 1) + NS - 1) / NS - 1;
        for (int jp = jlo; jp <= jhi; ++jp) {
            float th  = ((float)NS * (float)jp - 47.0f * (float)st) * (1.0f / 47.0f);
            float th2 = th * th, th3 = th2 * th;
            float c0 = 2.0f * th3 - 3.0f * th2 + 1.0f;
            float c1 = 3.0f * th2 - 2.0f * th3;
            float c2 = Hh * (th3 - 2.0f * th2 + th);
            float c3 = Hh * (th3 - th2);
            {
                float4 za = ((const float4*)zA)[tid];
                float4 zb = ((const float4*)zB)[tid];
                float4 fa = ((const float4*)fP)[tid];
                float4 fb = ((const float4*)fN)[tid];
                float4 zv;
                zv.x = c0*za.x + c1*zb.x + c2*fa.x + c3*fb.x;
                zv.y = c0*za.y + c1*zb.y + c2*fa.y + c3*fb.y;
                zv.z = c0*za.z + c1*zb.z + c2*fa.z + c3*fb.z;
                zv.w = c0*za.w + c1*zb.w + c2*fa.w + c3*fb.w;
                ((float4*)ztl)[tid] = zv;
            }
            __syncthreads();
            {
                float aa = b1s;
                const float4* zrow = (const float4*)(ztl + rh * LL);
                for (int k4 = 0; k4 < 32; ++k4) {
                    float4 wv = w1hq[k4 * 32 + s5];
                    float4 v = zrow[k4];
                    aa = fmaf(wv.x, v.x, aa); aa = fmaf(wv.y, v.y, aa);
                    aa = fmaf(wv.z, v.z, aa); aa = fmaf(wv.w, v.w, aa);
                }
                float p = fmaxf(aa, 0.0f) * w2s;
                p += __shfl_xor(p, 1);  p += __shfl_xor(p, 2);
                p += __shfl_xor(p, 4);  p += __shfl_xor(p, 8);
                p += __shfl_xor(p, 16);
                float hz = sigm_f(p + b2s);
                float sv = __expf(cum_r);
                cum_r += __logf(1.0f - hz + 1e-7f);
                if (s5 == 0) {
                    int row = blk * 16 + rh;
                    out_haz [row * NHZ + jp] = hz;
                    out_surv[row * NHZ + jp] = sv;
                    if (jp == NHZ - 1) out_pg[row] = 1.0f - sv;
                }
            }
            __syncthreads();
        }

        // roll buffers
        float* t0 = zA; zA = zB; zB = t0;
        t0 = fP; fP = fN; fN = t0;
    }
}

// ---------------- launch ----------------

extern "C" void kernel_launch(void* const* d_in, const int* in_sizes, int n_in,
                              void* d_out, int out_size, void* d_ws, size_t ws_size,
                              hipStream_t stream) {
    const float* X        = (const float*)d_in[0];
    const float* Mask     = (const float*)d_in[1];
    const float* gru_w_ih = (const float*)d_in[2];
    const float* gru_w_hh = (const float*)d_in[3];
    const float* gru_b_ih = (const float*)d_in[4];
    const float* gru_b_hh = (const float*)d_in[5];
    const float* z0_w     = (const float*)d_in[6];
    const float* z0_b     = (const float*)d_in[7];
    const float* tproj_w  = (const float*)d_in[8];
    const float* tproj_b  = (const float*)d_in[9];
    const float* ode_w1   = (const float*)d_in[10];
    const float* ode_b1   = (const float*)d_in[11];
    const float* ode_w2   = (const float*)d_in[12];
    const float* ode_b2   = (const float*)d_in[13];
    const float* ode_w3   = (const float*)d_in[14];
    const float* ode_b3   = (const float*)d_in[15];
    const float* sh_w1    = (const float*)d_in[16];
    const float* sh_b1    = (const float*)d_in[17];
    const float* sh_w2    = (const float*)d_in[18];
    const float* sh_b2    = (const float*)d_in[19];

    float* ws     = (float*)d_ws;
    float* tembs  = ws;                        // 104 floats
    float* tembW1 = ws + 256;                  // 13*256 = 3328 -> end 3584
    unsigned short* Brz = (unsigned short*)(ws + 4608);  // 163840
    unsigned short* Bnu = Brz + 163840;                  // 16384
    unsigned short* Bnh = Bnu + 16384;                   // 65536
    unsigned short* Bz0 = Bnh + 65536;                   // 65536
    unsigned short* B1  = Bz0 + 65536;                   // 16*4*512 = 32768
    unsigned short* B2  = B1  + 32768;                   // 16*8*512 = 65536
    unsigned short* B3  = B2  + 65536;                   //  8*8*512 = 32768

    float* out      = (float*)d_out;
    float* out_haz  = out;                              // 4096*48
    float* out_surv = out + 196608;                     // 4096*48
    float* out_mean = out + 393216;                     // 4096*128
    float* out_lv   = out + 917504;                     // 4096*128
    float* out_pg   = out + 1441792;                    // 4096

    temb_k<<<1, 64, 0, stream>>>(tproj_w, tproj_b, tembs);
    tembW1_k<<<(NTEMB * 256 + 255) / 256, 256, 0, stream>>>(ode_w1, ode_b1, tembs, tembW1);

    packBrz_k<<<(32*10*512) / 256, 256, 0, stream>>>(gru_w_ih, gru_w_hh, Brz);
    packB_k<<<(16*2*512) / 256, 256, 0, stream>>>(gru_w_ih + 512 * 64,  Bnu, 64,  16, 2);
    packB_k<<<(16*8*512) / 256, 256, 0, stream>>>(gru_w_hh + 512 * 256, Bnh, 256, 16, 8);
    packB_k<<<(16*8*512) / 256, 256, 0, stream>>>(z0_w,                 Bz0, 256, 16, 8);
    packB_k<<<(16*4*512) / 256, 256, 0, stream>>>(ode_w1, B1, 136, 16, 4);   // k<128 only
    packB_k<<<(16*8*512) / 256, 256, 0, stream>>>(ode_w2, B2, 256, 16, 8);
    packB_k<<<( 8*8*512) / 256, 256, 0, stream>>>(ode_w3, B3, 256,  8, 8);

    gru_mfma_k<<<BB / 16, 512, 0, stream>>>(X, Mask, Brz, Bnu, Bnh, Bz0,
                                            gru_b_ih, gru_b_hh, z0_b, out_mean, out_lv);

    ode_head_mfma_k<<<BB / 16, 512, 0, stream>>>(out_mean, B1, B2, B3,
                                                 tembW1, ode_b2, ode_b3,
                                                 sh_w1, sh_b1, sh_w2, sh_b2,
                                                 out_haz, out_surv, out_pg);
}

// Round 18
// 387.718 us; speedup vs baseline: 1.9545x; 1.0384x over previous
//
#include <hip/hip_runtime.h>
#include <math.h>

#define BB 4096
#define TT 48
#define DD 32
#define HH 256
#define LL 128
#define HID 256
#define EE 8
#define NHZ 48
#define NS 6              // RK4 macro steps (dense-output Hermite between knots)
#define NTEMB (2*NS+1)    // 13 precomputed time-embeddings

typedef __attribute__((ext_vector_type(8))) short bf16x8;   // 8 bf16 = 4 VGPRs
typedef __attribute__((ext_vector_type(4))) float f32x4;

#define MFMA_BF16(a,b,c) __builtin_amdgcn_mfma_f32_16x16x32_bf16((a),(b),(c),0,0,0)

__device__ __forceinline__ float sigm_f(float x) {
    return 1.0f / (1.0f + __expf(-x));
}
__device__ __forceinline__ float tanh_f(float x) {
    x = fminf(fmaxf(x, -15.0f), 15.0f);
    float e = __expf(2.0f * x);
    return (e - 1.0f) / (e + 1.0f);
}
__device__ __forceinline__ float4 axpy4(float s, float4 a, float4 z) {
    return make_float4(fmaf(s, a.x, z.x), fmaf(s, a.y, z.y),
                       fmaf(s, a.z, z.z), fmaf(s, a.w, z.w));
}
__device__ __forceinline__ unsigned short f2bf(float x) {   // RNE fp32->bf16
    union { float f; unsigned u; } a; a.f = x;
    unsigned r = a.u + 0x7FFFu + ((a.u >> 16) & 1u);
    return (unsigned short)(r >> 16);
}

// ---------------- prep kernels ----------------

__global__ void temb_k(const float* __restrict__ tproj_w, const float* __restrict__ tproj_b,
                       float* __restrict__ tembs) {
    int i = blockIdx.x * 64 + threadIdx.x;
    if (i >= NTEMB) return;
    float t = (float)i / (float)(2 * NS);
    const float PI = 3.14159265358979323846f;
    float emb[8];
    #pragma unroll
    for (int m = 0; m < 4; ++m) {
        float pos = t * (float)(m + 1) * PI;
        emb[m]     = sinf(pos);
        emb[4 + m] = cosf(pos);
    }
    #pragma unroll
    for (int o = 0; o < 8; ++o) {
        float a = tproj_b[o];
        #pragma unroll
        for (int k = 0; k < 8; ++k) a = fmaf(tproj_w[o * 8 + k], emb[k], a);
        tembs[i * 8 + o] = a;
    }
}

// tembW1[ti][n] = b1[n] + sum_k W1[n][128+k] * temb(ti)[k]
__global__ void tembW1_k(const float* __restrict__ w1, const float* __restrict__ b1,
                         const float* __restrict__ tembs, float* __restrict__ out) {
    int i = blockIdx.x * 256 + threadIdx.x;
    if (i >= NTEMB * 256) return;
    int ti = i >> 8, n = i & 255;
    float a = b1[n];
    #pragma unroll
    for (int k = 0; k < 8; ++k) a = fmaf(w1[n * 136 + 128 + k], tembs[ti * 8 + k], a);
    out[i] = a;
}

// B-fragment packers (bf16). Fragment = 512 bf16: element (lane*8+j) holds
// B[k][n] with k = ks*32 + (lane>>4)*8 + j, n = nt*16 + (lane&15).

__global__ void packBrz_k(const float* __restrict__ w_ih, const float* __restrict__ w_hh,
                          unsigned short* __restrict__ dst) {
    int i = blockIdx.x * 256 + threadIdx.x;      // 32 nt * 10 ks * 512
    if (i >= 32 * 10 * 512) return;
    int frag = i >> 9, e = i & 511;
    int lane = e >> 3, j = e & 7;
    int nt = frag / 10, ks = frag % 10;
    int k = ks * 32 + ((lane >> 4) << 3) + j;
    int n = nt * 16 + (lane & 15);
    float v = (k < 64) ? w_ih[n * 64 + k] : w_hh[n * 256 + (k - 64)];
    dst[i] = f2bf(v);
}

__global__ void packB_k(const float* __restrict__ src, unsigned short* __restrict__ dst,
                        int K, int NT, int NKS) {
    int i = blockIdx.x * 256 + threadIdx.x;
    if (i >= NT * NKS * 512) return;
    int frag = i >> 9, e = i & 511;
    int lane = e >> 3, j = e & 7;
    int nt = frag / NKS, ks = frag % NKS;
    int k = ks * 32 + ((lane >> 4) << 3) + j;
    int n = nt * 16 + (lane & 15);
    dst[i] = f2bf(src[n * K + k]);
}

// ---------------- GRU encoder via MFMA (+ fused z0 projection) ----------------
// Round-17 structure. NEW: all gg=1 Brz fragments loaded into registers
// IMMEDIATELY after the barrier (early issue) so their L2 latency overlaps
// gg=0's MFMA chains. (512,1) + 1 block/CU => up to 256 VGPR at no occ cost.

__global__ __launch_bounds__(512, 1) void gru_mfma_k(
    const float* __restrict__ Xp, const float* __restrict__ Mp,
    const unsigned short* __restrict__ Brz,   // [32 nt][10 ks][512]
    const unsigned short* __restrict__ Bnu,   // [16 nt][ 2 ks][512]
    const unsigned short* __restrict__ Bnh,   // [16 nt][ 8 ks][512]  (-> LDS)
    const unsigned short* __restrict__ Bz0,   // [16 nt][ 8 ks][512]
    const float* __restrict__ b_ih, const float* __restrict__ b_hh,
    const float* __restrict__ z0_b,
    float* __restrict__ out_mean, float* __restrict__ out_lv) {

    __shared__ unsigned short h_bf[16 * 256];        // 8KB, swizzled
    __shared__ unsigned short u_bf[16 * 64];         // 2KB, swizzled
    __shared__ unsigned short bnh_lds[16 * 8 * 512]; // 131KB n-gate hh fragments
    __shared__ float obs[16];

    int tid = threadIdx.x, blk = blockIdx.x;
    int lane = tid & 63, w = tid >> 6;
    int l4 = lane >> 4, l15 = lane & 15;

    for (int e = tid; e < 16 * 256; e += 512) h_bf[e] = 0;
    for (int e = tid; e < 8192; e += 512)
        ((f32x4*)bnh_lds)[e] = ((const f32x4*)Bnh)[e];

    float brz0[2], brz1[2], bin_[2], bhn_[2];
    int hcol[2];
    #pragma unroll
    for (int gg = 0; gg < 2; ++gg) {
        int n = (2 * w + gg) * 16 + l15;
        hcol[gg] = n;
        brz0[gg] = b_ih[n]       + b_hh[n];
        brz1[gg] = b_ih[256 + n] + b_hh[256 + n];
        bin_[gg] = b_ih[512 + n];
        bhn_[gg] = b_hh[512 + n];
    }
    float h_st[2][4] = {{0,0,0,0},{0,0,0,0}};

    // hoist time-invariant fragments: group 0's r/z (20) + both Bnu (4)
    bf16x8 hbr[10], hbz[10], hbu[2][2];
    {
        int g0 = 2 * w;
        #pragma unroll
        for (int ks = 0; ks < 10; ++ks) {
            hbr[ks] = *(const bf16x8*)(Brz + ((g0 * 10 + ks) * 512 + lane * 8));
            hbz[ks] = *(const bf16x8*)(Brz + (((16 + g0) * 10 + ks) * 512 + lane * 8));
        }
        #pragma unroll
        for (int gg = 0; gg < 2; ++gg)
            #pragma unroll
            for (int ks = 0; ks < 2; ++ks)
                hbu[gg][ks] = *(const bf16x8*)(Bnu + (((g0 + gg) * 2 + ks) * 512 + lane * 8));
    }

    __syncthreads();

    int arow = l15, asw = (arow & 7) << 4;
    int g1 = 2 * w + 1;

    for (int t = TT - 1; t >= 0; --t) {
        if (tid < 256) {
            int r = tid >> 4, c4 = tid & 15;
            const float* base = (c4 < 8 ? Xp : Mp) + (size_t)(blk * 16 + r) * (TT * DD) + t * DD;
            f32x4 v = __builtin_nontemporal_load(((const f32x4*)base) + (c4 & 7));
            ushort4 p;
            p.x = f2bf(v.x); p.y = f2bf(v.y); p.z = f2bf(v.z); p.w = f2bf(v.w);
            int k0 = (c4 < 8) ? c4 * 4 : 32 + (c4 - 8) * 4;
            int off = r * 128 + ((k0 * 2) ^ ((r & 7) << 4));
            *(ushort4*)((char*)u_bf + off) = p;
        }
        if (tid < 16) {
            const f32x4* mrow = (const f32x4*)(Mp + (size_t)(blk * 16 + tid) * (TT * DD) + t * DD);
            float s = 0.0f;
            #pragma unroll
            for (int i = 0; i < 8; ++i) {
                f32x4 v = __builtin_nontemporal_load(mrow + i);
                s += v.x + v.y + v.z + v.w;
            }
            obs[tid] = (s > 0.0f) ? 1.0f : 0.0f;
        }
        bf16x8 ah[8];
        #pragma unroll
        for (int ks = 0; ks < 8; ++ks)
            ah[ks] = *(const bf16x8*)((const char*)h_bf + (arow * 512 + ((ks * 64 + l4 * 16) ^ asw)));

        // EARLY ISSUE: gg=1 streamed r/z fragments -> registers, in flight
        // while gg=0 computes below.
        bf16x8 br1[10], bz1[10];
        #pragma unroll
        for (int ks = 0; ks < 10; ++ks) {
            br1[ks] = *(const bf16x8*)(Brz + ((g1 * 10 + ks) * 512 + lane * 8));
            bz1[ks] = *(const bf16x8*)(Brz + (((16 + g1) * 10 + ks) * 512 + lane * 8));
        }
        __syncthreads();

        bf16x8 au[2];
        #pragma unroll
        for (int ks = 0; ks < 2; ++ks)
            au[ks] = *(const bf16x8*)((const char*)u_bf + (arow * 128 + ((ks * 64 + l4 * 16) ^ asw)));

        #pragma unroll
        for (int gg = 0; gg < 2; ++gg) {
            int g = 2 * w + gg;
            f32x4 accr = {0,0,0,0}, accz = {0,0,0,0}, acci = {0,0,0,0}, acch = {0,0,0,0};
            #pragma unroll
            for (int ks = 0; ks < 10; ++ks) {
                bf16x8 a = (ks < 2) ? au[ks] : ah[ks - 2];
                bf16x8 br = (gg == 0) ? hbr[ks] : br1[ks];
                bf16x8 bz = (gg == 0) ? hbz[ks] : bz1[ks];
                accr = MFMA_BF16(a, br, accr);
                accz = MFMA_BF16(a, bz, accz);
            }
            #pragma unroll
            for (int ks = 0; ks < 2; ++ks)
                acci = MFMA_BF16(au[ks], hbu[gg][ks], acci);
            #pragma unroll
            for (int ks = 0; ks < 8; ++ks) {
                bf16x8 b = *(const bf16x8*)(bnh_lds + ((g * 8 + ks) * 512 + lane * 8));
                acch = MFMA_BF16(ah[ks], b, acch);
            }
            #pragma unroll
            for (int q = 0; q < 4; ++q) {
                int m = l4 * 4 + q;
                float rg = sigm_f(accr[q] + brz0[gg]);
                float zg = sigm_f(accz[q] + brz1[gg]);
                float nn = tanh_f(acci[q] + bin_[gg] + rg * (acch[q] + bhn_[gg]));
                float hnew = (1.0f - zg) * nn + zg * h_st[gg][q];
                float o = obs[m];
                float hs = o * hnew + (1.0f - o) * h_st[gg][q];
                h_st[gg][q] = hs;
                int off = m * 512 + ((hcol[gg] * 2) ^ ((m & 7) << 4));
                *(unsigned short*)((char*)h_bf + off) = f2bf(hs);
            }
        }
        __syncthreads();
    }

    bf16x8 ahf[8];
    #pragma unroll
    for (int ks = 0; ks < 8; ++ks)
        ahf[ks] = *(const bf16x8*)((const char*)h_bf + (arow * 512 + ((ks * 64 + l4 * 16) ^ asw)));
    #pragma unroll
    for (int gg = 0; gg < 2; ++gg) {
        int nt = 2 * w + gg;
        f32x4 acc = {0,0,0,0};
        #pragma unroll
        for (int ks = 0; ks < 8; ++ks) {
            bf16x8 b = *(const bf16x8*)(Bz0 + ((nt * 8 + ks) * 512 + lane * 8));
            acc = MFMA_BF16(ahf[ks], b, acc);
        }
        int n = nt * 16 + l15;
        float bb = z0_b[n];
        #pragma unroll
        for (int q = 0; q < 4; ++q) {
            int m = l4 * 4 + q;
            int row = blk * 16 + m;
            float v = acc[q] + bb;
            if (n < 128) out_mean[row * LL + n] = v;
            else         out_lv  [row * LL + (n - 128)] = v;
        }
    }
}

// ---------------- ODE dynamics eval via MFMA (round-11 verbatim, validated) ----------------

__device__ __forceinline__ void ode_f_mfma(
    const unsigned short* __restrict__ az, unsigned short* __restrict__ h1b,
    unsigned short* __restrict__ h2b, float* __restrict__ fo,
    const unsigned short* __restrict__ B1, const unsigned short* __restrict__ B2,
    const unsigned short* __restrict__ B3,
    const float* __restrict__ tW1,   // tembW1 + ti*256 (includes b1)
    float b2n0, float b2n1, float b3n, int lane, int w) {

    int l4 = lane >> 4, l15 = lane & 15;
    int arow = l15, asw = (arow & 7) << 4;

    // phase A: h1 = tanh(W1z·z + tembW1(t))   K=128 -> 4 ks
    bf16x8 a4[4];
    #pragma unroll
    for (int ks = 0; ks < 4; ++ks)
        a4[ks] = *(const bf16x8*)((const char*)az + (arow * 256 + ((ks * 64 + l4 * 16) ^ asw)));
    #pragma unroll
    for (int gg = 0; gg < 2; ++gg) {
        int nt = 2 * w + gg, n = nt * 16 + l15;
        f32x4 acc = {0,0,0,0};
        #pragma unroll
        for (int ks = 0; ks < 4; ++ks) {
            bf16x8 b = *(const bf16x8*)(B1 + ((nt * 4 + ks) * 512 + lane * 8));
            acc = MFMA_BF16(a4[ks], b, acc);
        }
        float tb = tW1[n];
        #pragma unroll
        for (int q = 0; q < 4; ++q) {
            int m = l4 * 4 + q;
            float v = tanh_f(acc[q] + tb);
            *(unsigned short*)((char*)h1b + (m * 512 + ((n * 2) ^ ((m & 7) << 4)))) = f2bf(v);
        }
    }
    __syncthreads();

    // phase B: h2 = tanh(W2·h1 + b2)   K=256 -> 8 ks
    bf16x8 a8[8];
    #pragma unroll
    for (int ks = 0; ks < 8; ++ks)
        a8[ks] = *(const bf16x8*)((const char*)h1b + (arow * 512 + ((ks * 64 + l4 * 16) ^ asw)));
    #pragma unroll
    for (int gg = 0; gg < 2; ++gg) {
        int nt = 2 * w + gg, n = nt * 16 + l15;
        f32x4 acc = {0,0,0,0};
        #pragma unroll
        for (int ks = 0; ks < 8; ++ks) {
            bf16x8 b = *(const bf16x8*)(B2 + ((nt * 8 + ks) * 512 + lane * 8));
            acc = MFMA_BF16(a8[ks], b, acc);
        }
        float bb = (gg == 0) ? b2n0 : b2n1;
        #pragma unroll
        for (int q = 0; q < 4; ++q) {
            int m = l4 * 4 + q;
            float v = tanh_f(acc[q] + bb);
            *(unsigned short*)((char*)h2b + (m * 512 + ((n * 2) ^ ((m & 7) << 4)))) = f2bf(v);
        }
    }
    __syncthreads();

    // phase C: fo = W3·h2 + b3   N=128, wave w -> tile w
    #pragma unroll
    for (int ks = 0; ks < 8; ++ks)
        a8[ks] = *(const bf16x8*)((const char*)h2b + (arow * 512 + ((ks * 64 + l4 * 16) ^ asw)));
    {
        f32x4 acc = {0,0,0,0};
        #pragma unroll
        for (int ks = 0; ks < 8; ++ks) {
            bf16x8 b = *(const bf16x8*)(B3 + ((w * 8 + ks) * 512 + lane * 8));
            acc = MFMA_BF16(a8[ks], b, acc);
        }
        int n = w * 16 + l15;
        #pragma unroll
        for (int q = 0; q < 4; ++q)
            fo[(l4 * 4 + q) * 128 + n] = acc[q] + b3n;
    }
    __syncthreads();
}

// ---------------- ODE (6-step RK4 + Hermite dense output) + head ----------------

__global__ __launch_bounds__(512, 2) void ode_head_mfma_k(
    const float* __restrict__ zinit,
    const unsigned short* __restrict__ B1, const unsigned short* __restrict__ B2,
    const unsigned short* __restrict__ B3,
    const float* __restrict__ tembW1, const float* __restrict__ b2, const float* __restrict__ b3,
    const float* __restrict__ shw1g, const float* __restrict__ shb1,
    const float* __restrict__ shw2, const float* __restrict__ shb2,
    float* __restrict__ out_haz, float* __restrict__ out_surv, float* __restrict__ out_pg) {

    __shared__ __align__(16) float bufA [2048];              // 8KB z knot s
    __shared__ __align__(16) float bufB [2048];              // 8KB z knot s+1
    __shared__ __align__(16) float bufFP[2048];              // 8KB f knot s
    __shared__ __align__(16) float bufFN[2048];              // 8KB f scratch
    __shared__ __align__(16) float ztl  [2048];              // 8KB stage/z-theta
    __shared__ __align__(16) unsigned short az [16 * 128];   // 4KB bf16 A of state
    __shared__ __align__(16) unsigned short h1b[16 * 256];   // 8KB
    __shared__ __align__(16) unsigned short h2b[16 * 256];   // 8KB
    __shared__ __align__(16) float w1h[32 * 128];            // 16KB head W1 packed

    int tid = threadIdx.x, blk = blockIdx.x;
    int lane = tid & 63, w = tid >> 6;
    int l15 = lane & 15;
    int s5 = tid & 31, rh = tid >> 5;

    float b2n0 = b2[(2 * w) * 16 + l15];
    float b2n1 = b2[(2 * w + 1) * 16 + l15];
    float b3n  = b3[w * 16 + l15];
    float w2s = shw2[s5], b1s = shb1[s5], b2s = shb2[0];
    float cum_r = 0.0f;
    const float4* w1hq = (const float4*)w1h;

    float* zA = bufA; float* zB = bufB;
    float* fP = bufFP; float* fN = bufFN;

    int crow = tid >> 5, ccol = (tid & 31) * 4;
    int azoff = crow * 256 + ((ccol * 2) ^ ((crow & 7) << 4));

    {
        float4 zv = ((const float4*)(zinit + (size_t)blk * 2048))[tid];
        ((float4*)zA)[tid] = zv;
        ushort4 pb; pb.x = f2bf(zv.x); pb.y = f2bf(zv.y); pb.z = f2bf(zv.z); pb.w = f2bf(zv.w);
        *(ushort4*)((char*)az + azoff) = pb;
    }
    for (int e = tid; e < 32 * 128; e += 512) {
        int u = e >> 7, k = e & 127;
        w1h[((k >> 2) * 32 + u) * 4 + (k & 3)] = shw1g[e];
    }
    __syncthreads();

    // f0 = f(z0, t=0)
    ode_f_mfma(az, h1b, h2b, fP, B1, B2, B3, tembW1, b2n0, b2n1, b3n, lane, w);

    const float Hh = 1.0f / (float)NS;

    for (int st = 0; st < NS; ++st) {
        float4 ka, zr0;
        {   // k1 = fP (FSAL)
            float4 f = ((const float4*)fP)[tid];
            zr0 = ((const float4*)zA)[tid];
            ka = f;
            float4 zv = axpy4(0.5f * Hh, f, zr0);
            ((float4*)ztl)[tid] = zv;
            ushort4 pb; pb.x=f2bf(zv.x); pb.y=f2bf(zv.y); pb.z=f2bf(zv.z); pb.w=f2bf(zv.w);
            *(ushort4*)((char*)az + azoff) = pb;
        }
        __syncthreads();
        ode_f_mfma(az, h1b, h2b, fN, B1, B2, B3, tembW1 + (2*st+1)*256, b2n0, b2n1, b3n, lane, w); // k2
        {
            float4 f = ((const float4*)fN)[tid];
            ka = axpy4(2.0f, f, ka);
            float4 zv = axpy4(0.5f * Hh, f, zr0);
            ((float4*)ztl)[tid] = zv;
            ushort4 pb; pb.x=f2bf(zv.x); pb.y=f2bf(zv.y); pb.z=f2bf(zv.z); pb.w=f2bf(zv.w);
            *(ushort4*)((char*)az + azoff) = pb;
        }
        __syncthreads();
        ode_f_mfma(az, h1b, h2b, fN, B1, B2, B3, tembW1 + (2*st+1)*256, b2n0, b2n1, b3n, lane, w); // k3
        {
            float4 f = ((const float4*)fN)[tid];
            ka = axpy4(2.0f, f, ka);
            float4 zv = axpy4(Hh, f, zr0);
            ((float4*)ztl)[tid] = zv;
            ushort4 pb; pb.x=f2bf(zv.x); pb.y=f2bf(zv.y); pb.z=f2bf(zv.z); pb.w=f2bf(zv.w);
            *(ushort4*)((char*)az + azoff) = pb;
        }
        __syncthreads();
        ode_f_mfma(az, h1b, h2b, fN, B1, B2, B3, tembW1 + (2*st+2)*256, b2n0, b2n1, b3n, lane, w); // k4
        {
            float4 f = ((const float4*)fN)[tid];
            float s6 = Hh / 6.0f;
            float4 kk = make_float4(ka.x + f.x, ka.y + f.y, ka.z + f.z, ka.w + f.w);
            float4 zv = axpy4(s6, kk, zr0);
            ((float4*)zB)[tid] = zv;
            ushort4 pb; pb.x=f2bf(zv.x); pb.y=f2bf(zv.y); pb.z=f2bf(zv.z); pb.w=f2bf(zv.w);
            *(ushort4*)((char*)az + azoff) = pb;
        }
        __syncthreads();
        // f_{s+1} (next step's k1, Hermite right-slope)
        ode_f_mfma(az, h1b, h2b, fN, B1, B2, B3, tembW1 + (2*st+2)*256, b2n0, b2n1, b3n, lane, w);

        // ---- emit head at output points inside [st/NS, (st+1)/NS] via Hermite ----
        int jlo = (47 * st + NS - 1) / NS;
        int jhi = (st == NS - 1) ? 47 : (47 * (st + 1) + NS - 1) / NS - 1;
        for (int jp = jlo; jp <= jhi; ++jp) {
            float th  = ((float)NS * (float)jp - 47.0f * (float)st) * (1.0f / 47.0f);
            float th2 = th * th, th3 = th2 * th;
            float c0 = 2.0f * th3 - 3.0f * th2 + 1.0f;
            float c1 = 3.0f * th2 - 2.0f * th3;
            float c2 = Hh * (th3 - 2.0f * th2 + th);
            float c3 = Hh * (th3 - th2);
            {
                float4 za = ((const float4*)zA)[tid];
                float4 zb = ((const float4*)zB)[tid];
                float4 fa = ((const float4*)fP)[tid];
                float4 fb = ((const float4*)fN)[tid];
                float4 zv;
                zv.x = c0*za.x + c1*zb.x + c2*fa.x + c3*fb.x;
                zv.y = c0*za.y + c1*zb.y + c2*fa.y + c3*fb.y;
                zv.z = c0*za.z + c1*zb.z + c2*fa.z + c3*fb.z;
                zv.w = c0*za.w + c1*zb.w + c2*fa.w + c3*fb.w;
                ((float4*)ztl)[tid] = zv;
            }
            __syncthreads();
            {
                float aa = b1s;
                const float4* zrow = (const float4*)(ztl + rh * LL);
                for (int k4 = 0; k4 < 32; ++k4) {
                    float4 wv = w1hq[k4 * 32 + s5];
                    float4 v = zrow[k4];
                    aa = fmaf(wv.x, v.x, aa); aa = fmaf(wv.y, v.y, aa);
                    aa = fmaf(wv.z, v.z, aa); aa = fmaf(wv.w, v.w, aa);
                }
                float p = fmaxf(aa, 0.0f) * w2s;
                p += __shfl_xor(p, 1);  p += __shfl_xor(p, 2);
                p += __shfl_xor(p, 4);  p += __shfl_xor(p, 8);
                p += __shfl_xor(p, 16);
                float hz = sigm_f(p + b2s);
                float sv = __expf(cum_r);
                cum_r += __logf(1.0f - hz + 1e-7f);
                if (s5 == 0) {
                    int row = blk * 16 + rh;
                    out_haz [row * NHZ + jp] = hz;
                    out_surv[row * NHZ + jp] = sv;
                    if (jp == NHZ - 1) out_pg[row] = 1.0f - sv;
                }
            }
            __syncthreads();
        }

        // roll buffers
        float* t0 = zA; zA = zB; zB = t0;
        t0 = fP; fP = fN; fN = t0;
    }
}

// ---------------- launch ----------------

extern "C" void kernel_launch(void* const* d_in, const int* in_sizes, int n_in,
                              void* d_out, int out_size, void* d_ws, size_t ws_size,
                              hipStream_t stream) {
    const float* X        = (const float*)d_in[0];
    const float* Mask     = (const float*)d_in[1];
    const float* gru_w_ih = (const float*)d_in[2];
    const float* gru_w_hh = (const float*)d_in[3];
    const float* gru_b_ih = (const float*)d_in[4];
    const float* gru_b_hh = (const float*)d_in[5];
    const float* z0_w     = (const float*)d_in[6];
    const float* z0_b     = (const float*)d_in[7];
    const float* tproj_w  = (const float*)d_in[8];
    const float* tproj_b  = (const float*)d_in[9];
    const float* ode_w1   = (const float*)d_in[10];
    const float* ode_b1   = (const float*)d_in[11];
    const float* ode_w2   = (const float*)d_in[12];
    const float* ode_b2   = (const float*)d_in[13];
    const float* ode_w3   = (const float*)d_in[14];
    const float* ode_b3   = (const float*)d_in[15];
    const float* sh_w1    = (const float*)d_in[16];
    const float* sh_b1    = (const float*)d_in[17];
    const float* sh_w2    = (const float*)d_in[18];
    const float* sh_b2    = (const float*)d_in[19];

    float* ws     = (float*)d_ws;
    float* tembs  = ws;                        // 104 floats
    float* tembW1 = ws + 256;                  // 13*256 = 3328 -> end 3584
    unsigned short* Brz = (unsigned short*)(ws + 4608);  // 163840
    unsigned short* Bnu = Brz + 163840;                  // 16384
    unsigned short* Bnh = Bnu + 16384;                   // 65536
    unsigned short* Bz0 = Bnh + 65536;                   // 65536
    unsigned short* B1  = Bz0 + 65536;                   // 16*4*512 = 32768
    unsigned short* B2  = B1  + 32768;                   // 16*8*512 = 65536
    unsigned short* B3  = B2  + 65536;                   //  8*8*512 = 32768

    float* out      = (float*)d_out;
    float* out_haz  = out;                              // 4096*48
    float* out_surv = out + 196608;                     // 4096*48
    float* out_mean = out + 393216;                     // 4096*128
    float* out_lv   = out + 917504;                     // 4096*128
    float* out_pg   = out + 1441792;                    // 4096

    temb_k<<<1, 64, 0, stream>>>(tproj_w, tproj_b, tembs);
    tembW1_k<<<(NTEMB * 256 + 255) / 256, 256, 0, stream>>>(ode_w1, ode_b1, tembs, tembW1);

    packBrz_k<<<(32*10*512) / 256, 256, 0, stream>>>(gru_w_ih, gru_w_hh, Brz);
    packB_k<<<(16*2*512) / 256, 256, 0, stream>>>(gru_w_ih + 512 * 64,  Bnu, 64,  16, 2);
    packB_k<<<(16*8*512) / 256, 256, 0, stream>>>(gru_w_hh + 512 * 256, Bnh, 256, 16, 8);
    packB_k<<<(16*8*512) / 256, 256, 0, stream>>>(z0_w,                 Bz0, 256, 16, 8);
    packB_k<<<(16*4*512) / 256, 256, 0, stream>>>(ode_w1, B1, 136, 16, 4);   // k<128 only
    packB_k<<<(16*8*512) / 256, 256, 0, stream>>>(ode_w2, B2, 256, 16, 8);
    packB_k<<<( 8*8*512) / 256, 256, 0, stream>>>(ode_w3, B3, 256,  8, 8);

    gru_mfma_k<<<BB / 16, 512, 0, stream>>>(X, Mask, Brz, Bnu, Bnh, Bz0,
                                            gru_b_ih, gru_b_hh, z0_b, out_mean, out_lv);

    ode_head_mfma_k<<<BB / 16, 512, 0, stream>>>(out_mean, B1, B2, B3,
                                                 tembW1, ode_b2, ode_b3,
                                                 sh_w1, sh_b1, sh_w2, sh_b2,
                                                 out_haz, out_surv, out_pg);
}

// Round 19
// 375.697 us; speedup vs baseline: 2.0170x; 1.0320x over previous
//
#include <hip/hip_runtime.h>
#include <math.h>

#define BB 4096
#define TT 48
#define DD 32
#define HH 256
#define LL 128
#define HID 256
#define EE 8
#define NHZ 48
#define NS 4              // RK4 macro steps (dense-output Hermite between knots)
#define NTEMB (2*NS+1)    // 9 precomputed time-embeddings

typedef __attribute__((ext_vector_type(8))) short bf16x8;   // 8 bf16 = 4 VGPRs
typedef __attribute__((ext_vector_type(4))) float f32x4;

#define MFMA_BF16(a,b,c) __builtin_amdgcn_mfma_f32_16x16x32_bf16((a),(b),(c),0,0,0)

__device__ __forceinline__ float sigm_f(float x) {
    return 1.0f / (1.0f + __expf(-x));
}
__device__ __forceinline__ float tanh_f(float x) {
    x = fminf(fmaxf(x, -15.0f), 15.0f);
    float e = __expf(2.0f * x);
    return (e - 1.0f) / (e + 1.0f);
}
__device__ __forceinline__ float4 axpy4(float s, float4 a, float4 z) {
    return make_float4(fmaf(s, a.x, z.x), fmaf(s, a.y, z.y),
                       fmaf(s, a.z, z.z), fmaf(s, a.w, z.w));
}
__device__ __forceinline__ unsigned short f2bf(float x) {   // RNE fp32->bf16
    union { float f; unsigned u; } a; a.f = x;
    unsigned r = a.u + 0x7FFFu + ((a.u >> 16) & 1u);
    return (unsigned short)(r >> 16);
}

// ---------------- prep kernels ----------------

__global__ void temb_k(const float* __restrict__ tproj_w, const float* __restrict__ tproj_b,
                       float* __restrict__ tembs) {
    int i = blockIdx.x * 64 + threadIdx.x;
    if (i >= NTEMB) return;
    float t = (float)i / (float)(2 * NS);
    const float PI = 3.14159265358979323846f;
    float emb[8];
    #pragma unroll
    for (int m = 0; m < 4; ++m) {
        float pos = t * (float)(m + 1) * PI;
        emb[m]     = sinf(pos);
        emb[4 + m] = cosf(pos);
    }
    #pragma unroll
    for (int o = 0; o < 8; ++o) {
        float a = tproj_b[o];
        #pragma unroll
        for (int k = 0; k < 8; ++k) a = fmaf(tproj_w[o * 8 + k], emb[k], a);
        tembs[i * 8 + o] = a;
    }
}

// tembW1[ti][n] = b1[n] + sum_k W1[n][128+k] * temb(ti)[k]
__global__ void tembW1_k(const float* __restrict__ w1, const float* __restrict__ b1,
                         const float* __restrict__ tembs, float* __restrict__ out) {
    int i = blockIdx.x * 256 + threadIdx.x;
    if (i >= NTEMB * 256) return;
    int ti = i >> 8, n = i & 255;
    float a = b1[n];
    #pragma unroll
    for (int k = 0; k < 8; ++k) a = fmaf(w1[n * 136 + 128 + k], tembs[ti * 8 + k], a);
    out[i] = a;
}

// B-fragment packers (bf16). Fragment = 512 bf16: element (lane*8+j) holds
// B[k][n] with k = ks*32 + (lane>>4)*8 + j, n = nt*16 + (lane&15).

__global__ void packBrz_k(const float* __restrict__ w_ih, const float* __restrict__ w_hh,
                          unsigned short* __restrict__ dst) {
    int i = blockIdx.x * 256 + threadIdx.x;      // 32 nt * 10 ks * 512
    if (i >= 32 * 10 * 512) return;
    int frag = i >> 9, e = i & 511;
    int lane = e >> 3, j = e & 7;
    int nt = frag / 10, ks = frag % 10;
    int k = ks * 32 + ((lane >> 4) << 3) + j;
    int n = nt * 16 + (lane & 15);
    float v = (k < 64) ? w_ih[n * 64 + k] : w_hh[n * 256 + (k - 64)];
    dst[i] = f2bf(v);
}

__global__ void packB_k(const float* __restrict__ src, unsigned short* __restrict__ dst,
                        int K, int NT, int NKS) {
    int i = blockIdx.x * 256 + threadIdx.x;
    if (i >= NT * NKS * 512) return;
    int frag = i >> 9, e = i & 511;
    int lane = e >> 3, j = e & 7;
    int nt = frag / NKS, ks = frag % NKS;
    int k = ks * 32 + ((lane >> 4) << 3) + j;
    int n = nt * 16 + (lane & 15);
    dst[i] = f2bf(src[n * K + k]);
}

// ---------------- GRU encoder via MFMA (+ fused z0 projection) ----------------
// Round-18 structure + NEW: double-buffered h/u/obs -> ONE barrier per
// timestep (reads from buf p, h-writes and next-t u-staging to buf p^1),
// and next-t X/Mask loads overlap this t's MFMA compute.

__global__ __launch_bounds__(512, 1) void gru_mfma_k(
    const float* __restrict__ Xp, const float* __restrict__ Mp,
    const unsigned short* __restrict__ Brz,   // [32 nt][10 ks][512]
    const unsigned short* __restrict__ Bnu,   // [16 nt][ 2 ks][512]
    const unsigned short* __restrict__ Bnh,   // [16 nt][ 8 ks][512]  (-> LDS)
    const unsigned short* __restrict__ Bz0,   // [16 nt][ 8 ks][512]
    const float* __restrict__ b_ih, const float* __restrict__ b_hh,
    const float* __restrict__ z0_b,
    float* __restrict__ out_mean, float* __restrict__ out_lv) {

    __shared__ unsigned short h_bf[2][16 * 256];     // 16KB, swizzled
    __shared__ unsigned short u_bf[2][16 * 64];      // 4KB, swizzled
    __shared__ unsigned short bnh_lds[16 * 8 * 512]; // 131KB
    __shared__ float obs[2][16];

    int tid = threadIdx.x, blk = blockIdx.x;
    int lane = tid & 63, w = tid >> 6;
    int l4 = lane >> 4, l15 = lane & 15;

    for (int e = tid; e < 16 * 256; e += 512) h_bf[0][e] = 0;
    for (int e = tid; e < 8192; e += 512)
        ((f32x4*)bnh_lds)[e] = ((const f32x4*)Bnh)[e];

    float brz0[2], brz1[2], bin_[2], bhn_[2];
    int hcol[2];
    #pragma unroll
    for (int gg = 0; gg < 2; ++gg) {
        int n = (2 * w + gg) * 16 + l15;
        hcol[gg] = n;
        brz0[gg] = b_ih[n]       + b_hh[n];
        brz1[gg] = b_ih[256 + n] + b_hh[256 + n];
        bin_[gg] = b_ih[512 + n];
        bhn_[gg] = b_hh[512 + n];
    }
    float h_st[2][4] = {{0,0,0,0},{0,0,0,0}};

    // hoist time-invariant fragments: group 0's r/z (20) + both Bnu (4)
    bf16x8 hbr[10], hbz[10], hbu[2][2];
    {
        int g0 = 2 * w;
        #pragma unroll
        for (int ks = 0; ks < 10; ++ks) {
            hbr[ks] = *(const bf16x8*)(Brz + ((g0 * 10 + ks) * 512 + lane * 8));
            hbz[ks] = *(const bf16x8*)(Brz + (((16 + g0) * 10 + ks) * 512 + lane * 8));
        }
        #pragma unroll
        for (int gg = 0; gg < 2; ++gg)
            #pragma unroll
            for (int ks = 0; ks < 2; ++ks)
                hbu[gg][ks] = *(const bf16x8*)(Bnu + (((g0 + gg) * 2 + ks) * 512 + lane * 8));
    }

    // prologue: stage u/obs for t = TT-1 into buffer 0
    if (tid < 256) {
        int r = tid >> 4, c4 = tid & 15;
        const float* base = (c4 < 8 ? Xp : Mp) + (size_t)(blk * 16 + r) * (TT * DD) + (TT - 1) * DD;
        f32x4 v = __builtin_nontemporal_load(((const f32x4*)base) + (c4 & 7));
        ushort4 pk;
        pk.x = f2bf(v.x); pk.y = f2bf(v.y); pk.z = f2bf(v.z); pk.w = f2bf(v.w);
        int k0 = (c4 < 8) ? c4 * 4 : 32 + (c4 - 8) * 4;
        int off = r * 128 + ((k0 * 2) ^ ((r & 7) << 4));
        *(ushort4*)((char*)u_bf[0] + off) = pk;
    }
    if (tid < 16) {
        const f32x4* mrow = (const f32x4*)(Mp + (size_t)(blk * 16 + tid) * (TT * DD) + (TT - 1) * DD);
        float s = 0.0f;
        #pragma unroll
        for (int i = 0; i < 8; ++i) {
            f32x4 v = __builtin_nontemporal_load(mrow + i);
            s += v.x + v.y + v.z + v.w;
        }
        obs[0][tid] = (s > 0.0f) ? 1.0f : 0.0f;
    }
    __syncthreads();

    int arow = l15, asw = (arow & 7) << 4;
    int g1 = 2 * w + 1;
    int p = 0;

    for (int t = TT - 1; t >= 0; --t) {
        // reads from buffer p (protected by previous barrier)
        bf16x8 ah[8];
        #pragma unroll
        for (int ks = 0; ks < 8; ++ks)
            ah[ks] = *(const bf16x8*)((const char*)h_bf[p] + (arow * 512 + ((ks * 64 + l4 * 16) ^ asw)));
        bf16x8 au[2];
        #pragma unroll
        for (int ks = 0; ks < 2; ++ks)
            au[ks] = *(const bf16x8*)((const char*)u_bf[p] + (arow * 128 + ((ks * 64 + l4 * 16) ^ asw)));

        // early-issue: gg=1 streamed r/z fragments
        bf16x8 br1[10], bz1[10];
        #pragma unroll
        for (int ks = 0; ks < 10; ++ks) {
            br1[ks] = *(const bf16x8*)(Brz + ((g1 * 10 + ks) * 512 + lane * 8));
            bz1[ks] = *(const bf16x8*)(Brz + (((16 + g1) * 10 + ks) * 512 + lane * 8));
        }

        // stage NEXT timestep's u/obs into buffer p^1 (overlaps compute)
        if (t > 0) {
            if (tid < 256) {
                int r = tid >> 4, c4 = tid & 15;
                const float* base = (c4 < 8 ? Xp : Mp) + (size_t)(blk * 16 + r) * (TT * DD) + (t - 1) * DD;
                f32x4 v = __builtin_nontemporal_load(((const f32x4*)base) + (c4 & 7));
                ushort4 pk;
                pk.x = f2bf(v.x); pk.y = f2bf(v.y); pk.z = f2bf(v.z); pk.w = f2bf(v.w);
                int k0 = (c4 < 8) ? c4 * 4 : 32 + (c4 - 8) * 4;
                int off = r * 128 + ((k0 * 2) ^ ((r & 7) << 4));
                *(ushort4*)((char*)u_bf[p ^ 1] + off) = pk;
            }
            if (tid < 16) {
                const f32x4* mrow = (const f32x4*)(Mp + (size_t)(blk * 16 + tid) * (TT * DD) + (t - 1) * DD);
                float s = 0.0f;
                #pragma unroll
                for (int i = 0; i < 8; ++i) {
                    f32x4 v = __builtin_nontemporal_load(mrow + i);
                    s += v.x + v.y + v.z + v.w;
                }
                obs[p ^ 1][tid] = (s > 0.0f) ? 1.0f : 0.0f;
            }
        }

        #pragma unroll
        for (int gg = 0; gg < 2; ++gg) {
            int g = 2 * w + gg;
            f32x4 accr = {0,0,0,0}, accz = {0,0,0,0}, acci = {0,0,0,0}, acch = {0,0,0,0};
            #pragma unroll
            for (int ks = 0; ks < 10; ++ks) {
                bf16x8 a = (ks < 2) ? au[ks] : ah[ks - 2];
                bf16x8 br = (gg == 0) ? hbr[ks] : br1[ks];
                bf16x8 bz = (gg == 0) ? hbz[ks] : bz1[ks];
                accr = MFMA_BF16(a, br, accr);
                accz = MFMA_BF16(a, bz, accz);
            }
            #pragma unroll
            for (int ks = 0; ks < 2; ++ks)
                acci = MFMA_BF16(au[ks], hbu[gg][ks], acci);
            #pragma unroll
            for (int ks = 0; ks < 8; ++ks) {
                bf16x8 b = *(const bf16x8*)(bnh_lds + ((g * 8 + ks) * 512 + lane * 8));
                acch = MFMA_BF16(ah[ks], b, acch);
            }
            #pragma unroll
            for (int q = 0; q < 4; ++q) {
                int m = l4 * 4 + q;
                float rg = sigm_f(accr[q] + brz0[gg]);
                float zg = sigm_f(accz[q] + brz1[gg]);
                float nn = tanh_f(acci[q] + bin_[gg] + rg * (acch[q] + bhn_[gg]));
                float hnew = (1.0f - zg) * nn + zg * h_st[gg][q];
                float o = obs[p][m];
                float hs = o * hnew + (1.0f - o) * h_st[gg][q];
                h_st[gg][q] = hs;
                int off = m * 512 + ((hcol[gg] * 2) ^ ((m & 7) << 4));
                *(unsigned short*)((char*)h_bf[p ^ 1] + off) = f2bf(hs);
            }
        }
        __syncthreads();   // single barrier: p^1 writes ready, p free for reuse
        p ^= 1;
    }

    // final h lives in h_bf[p] (p toggled TT=48 times -> p=0; last write went there)
    bf16x8 ahf[8];
    #pragma unroll
    for (int ks = 0; ks < 8; ++ks)
        ahf[ks] = *(const bf16x8*)((const char*)h_bf[p] + (arow * 512 + ((ks * 64 + l4 * 16) ^ asw)));
    #pragma unroll
    for (int gg = 0; gg < 2; ++gg) {
        int nt = 2 * w + gg;
        f32x4 acc = {0,0,0,0};
        #pragma unroll
        for (int ks = 0; ks < 8; ++ks) {
            bf16x8 b = *(const bf16x8*)(Bz0 + ((nt * 8 + ks) * 512 + lane * 8));
            acc = MFMA_BF16(ahf[ks], b, acc);
        }
        int n = nt * 16 + l15;
        float bb = z0_b[n];
        #pragma unroll
        for (int q = 0; q < 4; ++q) {
            int m = l4 * 4 + q;
            int row = blk * 16 + m;
            float v = acc[q] + bb;
            if (n < 128) out_mean[row * LL + n] = v;
            else         out_lv  [row * LL + (n - 128)] = v;
        }
    }
}

// ---------------- ODE dynamics eval via MFMA (round-11 verbatim, validated) ----------------

__device__ __forceinline__ void ode_f_mfma(
    const unsigned short* __restrict__ az, unsigned short* __restrict__ h1b,
    unsigned short* __restrict__ h2b, float* __restrict__ fo,
    const unsigned short* __restrict__ B1, const unsigned short* __restrict__ B2,
    const unsigned short* __restrict__ B3,
    const float* __restrict__ tW1,   // tembW1 + ti*256 (includes b1)
    float b2n0, float b2n1, float b3n, int lane, int w) {

    int l4 = lane >> 4, l15 = lane & 15;
    int arow = l15, asw = (arow & 7) << 4;

    // phase A: h1 = tanh(W1z·z + tembW1(t))   K=128 -> 4 ks
    bf16x8 a4[4];
    #pragma unroll
    for (int ks = 0; ks < 4; ++ks)
        a4[ks] = *(const bf16x8*)((const char*)az + (arow * 256 + ((ks * 64 + l4 * 16) ^ asw)));
    #pragma unroll
    for (int gg = 0; gg < 2; ++gg) {
        int nt = 2 * w + gg, n = nt * 16 + l15;
        f32x4 acc = {0,0,0,0};
        #pragma unroll
        for (int ks = 0; ks < 4; ++ks) {
            bf16x8 b = *(const bf16x8*)(B1 + ((nt * 4 + ks) * 512 + lane * 8));
            acc = MFMA_BF16(a4[ks], b, acc);
        }
        float tb = tW1[n];
        #pragma unroll
        for (int q = 0; q < 4; ++q) {
            int m = l4 * 4 + q;
            float v = tanh_f(acc[q] + tb);
            *(unsigned short*)((char*)h1b + (m * 512 + ((n * 2) ^ ((m & 7) << 4)))) = f2bf(v);
        }
    }
    __syncthreads();

    // phase B: h2 = tanh(W2·h1 + b2)   K=256 -> 8 ks
    bf16x8 a8[8];
    #pragma unroll
    for (int ks = 0; ks < 8; ++ks)
        a8[ks] = *(const bf16x8*)((const char*)h1b + (arow * 512 + ((ks * 64 + l4 * 16) ^ asw)));
    #pragma unroll
    for (int gg = 0; gg < 2; ++gg) {
        int nt = 2 * w + gg, n = nt * 16 + l15;
        f32x4 acc = {0,0,0,0};
        #pragma unroll
        for (int ks = 0; ks < 8; ++ks) {
            bf16x8 b = *(const bf16x8*)(B2 + ((nt * 8 + ks) * 512 + lane * 8));
            acc = MFMA_BF16(a8[ks], b, acc);
        }
        float bb = (gg == 0) ? b2n0 : b2n1;
        #pragma unroll
        for (int q = 0; q < 4; ++q) {
            int m = l4 * 4 + q;
            float v = tanh_f(acc[q] + bb);
            *(unsigned short*)((char*)h2b + (m * 512 + ((n * 2) ^ ((m & 7) << 4)))) = f2bf(v);
        }
    }
    __syncthreads();

    // phase C: fo = W3·h2 + b3   N=128, wave w -> tile w
    #pragma unroll
    for (int ks = 0; ks < 8; ++ks)
        a8[ks] = *(const bf16x8*)((const char*)h2b + (arow * 512 + ((ks * 64 + l4 * 16) ^ asw)));
    {
        f32x4 acc = {0,0,0,0};
        #pragma unroll
        for (int ks = 0; ks < 8; ++ks) {
            bf16x8 b = *(const bf16x8*)(B3 + ((w * 8 + ks) * 512 + lane * 8));
            acc = MFMA_BF16(a8[ks], b, acc);
        }
        int n = w * 16 + l15;
        #pragma unroll
        for (int q = 0; q < 4; ++q)
            fo[(l4 * 4 + q) * 128 + n] = acc[q] + b3n;
    }
    __syncthreads();
}

// ---------------- ODE (4-step RK4 + Hermite dense output) + head ----------------

__global__ __launch_bounds__(512, 2) void ode_head_mfma_k(
    const float* __restrict__ zinit,
    const unsigned short* __restrict__ B1, const unsigned short* __restrict__ B2,
    const unsigned short* __restrict__ B3,
    const float* __restrict__ tembW1, const float* __restrict__ b2, const float* __restrict__ b3,
    const float* __restrict__ shw1g, const float* __restrict__ shb1,
    const float* __restrict__ shw2, const float* __restrict__ shb2,
    float* __restrict__ out_haz, float* __restrict__ out_surv, float* __restrict__ out_pg) {

    __shared__ __align__(16) float bufA [2048];              // 8KB z knot s
    __shared__ __align__(16) float bufB [2048];              // 8KB z knot s+1
    __shared__ __align__(16) float bufFP[2048];              // 8KB f knot s
    __shared__ __align__(16) float bufFN[2048];              // 8KB f scratch
    __shared__ __align__(16) float ztl  [2048];              // 8KB stage/z-theta
    __shared__ __align__(16) unsigned short az [16 * 128];   // 4KB bf16 A of state
    __shared__ __align__(16) unsigned short h1b[16 * 256];   // 8KB
    __shared__ __align__(16) unsigned short h2b[16 * 256];   // 8KB
    __shared__ __align__(16) float w1h[32 * 128];            // 16KB head W1 packed

    int tid = threadIdx.x, blk = blockIdx.x;
    int lane = tid & 63, w = tid >> 6;
    int l15 = lane & 15;
    int s5 = tid & 31, rh = tid >> 5;

    float b2n0 = b2[(2 * w) * 16 + l15];
    float b2n1 = b2[(2 * w + 1) * 16 + l15];
    float b3n  = b3[w * 16 + l15];
    float w2s = shw2[s5], b1s = shb1[s5], b2s = shb2[0];
    float cum_r = 0.0f;
    const float4* w1hq = (const float4*)w1h;

    float* zA = bufA; float* zB = bufB;
    float* fP = bufFP; float* fN = bufFN;

    int crow = tid >> 5, ccol = (tid & 31) * 4;
    int azoff = crow * 256 + ((ccol * 2) ^ ((crow & 7) << 4));

    {
        float4 zv = ((const float4*)(zinit + (size_t)blk * 2048))[tid];
        ((float4*)zA)[tid] = zv;
        ushort4 pb; pb.x = f2bf(zv.x); pb.y = f2bf(zv.y); pb.z = f2bf(zv.z); pb.w = f2bf(zv.w);
        *(ushort4*)((char*)az + azoff) = pb;
    }
    for (int e = tid; e < 32 * 128; e += 512) {
        int u = e >> 7, k = e & 127;
        w1h[((k >> 2) * 32 + u) * 4 + (k & 3)] = shw1g[e];
    }
    __syncthreads();

    // f0 = f(z0, t=0)
    ode_f_mfma(az, h1b, h2b, fP, B1, B2, B3, tembW1, b2n0, b2n1, b3n, lane, w);

    const float Hh = 1.0f / (float)NS;

    for (int st = 0; st < NS; ++st) {
        float4 ka, zr0;
        {   // k1 = fP (FSAL)
            float4 f = ((const float4*)fP)[tid];
            zr0 = ((const float4*)zA)[tid];
            ka = f;
            float4 zv = axpy4(0.5f * Hh, f, zr0);
            ((float4*)ztl)[tid] = zv;
            ushort4 pb; pb.x=f2bf(zv.x); pb.y=f2bf(zv.y); pb.z=f2bf(zv.z); pb.w=f2bf(zv.w);
            *(ushort4*)((char*)az + azoff) = pb;
        }
        __syncthreads();
        ode_f_mfma(az, h1b, h2b, fN, B1, B2, B3, tembW1 + (2*st+1)*256, b2n0, b2n1, b3n, lane, w); // k2
        {
            float4 f = ((const float4*)fN)[tid];
            ka = axpy4(2.0f, f, ka);
            float4 zv = axpy4(0.5f * Hh, f, zr0);
            ((float4*)ztl)[tid] = zv;
            ushort4 pb; pb.x=f2bf(zv.x); pb.y=f2bf(zv.y); pb.z=f2bf(zv.z); pb.w=f2bf(zv.w);
            *(ushort4*)((char*)az + azoff) = pb;
        }
        __syncthreads();
        ode_f_mfma(az, h1b, h2b, fN, B1, B2, B3, tembW1 + (2*st+1)*256, b2n0, b2n1, b3n, lane, w); // k3
        {
            float4 f = ((const float4*)fN)[tid];
            ka = axpy4(2.0f, f, ka);
            float4 zv = axpy4(Hh, f, zr0);
            ((float4*)ztl)[tid] = zv;
            ushort4 pb; pb.x=f2bf(zv.x); pb.y=f2bf(zv.y); pb.z=f2bf(zv.z); pb.w=f2bf(zv.w);
            *(ushort4*)((char*)az + azoff) = pb;
        }
        __syncthreads();
        ode_f_mfma(az, h1b, h2b, fN, B1, B2, B3, tembW1 + (2*st+2)*256, b2n0, b2n1, b3n, lane, w); // k4
        {
            float4 f = ((const float4*)fN)[tid];
            float s6 = Hh / 6.0f;
            float4 kk = make_float4(ka.x + f.x, ka.y + f.y, ka.z + f.z, ka.w + f.w);
            float4 zv = axpy4(s6, kk, zr0);
            ((float4*)zB)[tid] = zv;
            ushort4 pb; pb.x=f2bf(zv.x); pb.y=f2bf(zv.y); pb.z=f2bf(zv.z); pb.w=f2bf(zv.w);
            *(ushort4*)((char*)az + azoff) = pb;
        }
        __syncthreads();
        // f_{s+1} (next step's k1, Hermite right-slope)
        ode_f_mfma(az, h1b, h2b, fN, B1, B2, B3, tembW1 + (2*st+2)*256, b2n0, b2n1, b3n, lane, w);

        // ---- emit head at output points inside [st/NS, (st+1)/NS] via Hermite ----
        int jlo = (47 * st + NS - 1) / NS;
        int jhi = (st == NS - 1) ? 47 : (47 * (st + 1) + NS - 1) / NS - 1;
        for (int jp = jlo; jp <= jhi; ++jp) {
            float th  = ((float)NS * (float)jp - 47.0f * (float)st) * (1.0f / 47.0f);
            float th2 = th * th, th3 = th2 * th;
            float c0 = 2.0f * th3 - 3.0f * th2 + 1.0f;
            float c1 = 3.0f * th2 - 2.0f * th3;
            float c2 = Hh * (th3 - 2.0f * th2 + th);
            float c3 = Hh * (th3 - th2);
            {
                float4 za = ((const float4*)zA)[tid];
                float4 zb = ((const float4*)zB)[tid];
                float4 fa = ((const float4*)fP)[tid];
                float4 fb = ((const float4*)fN)[tid];
                float4 zv;
                zv.x = c0*za.x + c1*zb.x + c2*fa.x + c3*fb.x;
                zv.y = c0*za.y + c1*zb.y + c2*fa.y + c3*fb.y;
                zv.z = c0*za.z + c1*zb.z + c2*fa.z + c3*fb.z;
                zv.w = c0*za.w + c1*zb.w + c2*fa.w + c3*fb.w;
                ((float4*)ztl)[tid] = zv;
            }
            __syncthreads();
            {
                float aa = b1s;
                const float4* zrow = (const float4*)(ztl + rh * LL);
                for (int k4 = 0; k4 < 32; ++k4) {
                    float4 wv = w1hq[k4 * 32 + s5];
                    float4 v = zrow[k4];
                    aa = fmaf(wv.x, v.x, aa); aa = fmaf(wv.y, v.y, aa);
                    aa = fmaf(wv.z, v.z, aa); aa = fmaf(wv.w, v.w, aa);
                }
                float p = fmaxf(aa, 0.0f) * w2s;
                p += __shfl_xor(p, 1);  p += __shfl_xor(p, 2);
                p += __shfl_xor(p, 4);  p += __shfl_xor(p, 8);
                p += __shfl_xor(p, 16);
                float hz = sigm_f(p + b2s);
                float sv = __expf(cum_r);
                cum_r += __logf(1.0f - hz + 1e-7f);
                if (s5 == 0) {
                    int row = blk * 16 + rh;
                    out_haz [row * NHZ + jp] = hz;
                    out_surv[row * NHZ + jp] = sv;
                    if (jp == NHZ - 1) out_pg[row] = 1.0f - sv;
                }
            }
            __syncthreads();
        }

        // roll buffers
        float* t0 = zA; zA = zB; zB = t0;
        t0 = fP; fP = fN; fN = t0;
    }
}

// ---------------- launch ----------------

extern "C" void kernel_launch(void* const* d_in, const int* in_sizes, int n_in,
                              void* d_out, int out_size, void* d_ws, size_t ws_size,
                              hipStream_t stream) {
    const float* X        = (const float*)d_in[0];
    const float* Mask     = (const float*)d_in[1];
    const float* gru_w_ih = (const float*)d_in[2];
    const float* gru_w_hh = (const float*)d_in[3];
    const float* gru_b_ih = (const float*)d_in[4];
    const float* gru_b_hh = (const float*)d_in[5];
    const float* z0_w     = (const float*)d_in[6];
    const float* z0_b     = (const float*)d_in[7];
    const float* tproj_w  = (const float*)d_in[8];
    const float* tproj_b  = (const float*)d_in[9];
    const float* ode_w1   = (const float*)d_in[10];
    const float* ode_b1   = (const float*)d_in[11];
    const float* ode_w2   = (const float*)d_in[12];
    const float* ode_b2   = (const float*)d_in[13];
    const float* ode_w3   = (const float*)d_in[14];
    const float* ode_b3   = (const float*)d_in[15];
    const float* sh_w1    = (const float*)d_in[16];
    const float* sh_b1    = (const float*)d_in[17];
    const float* sh_w2    = (const float*)d_in[18];
    const float* sh_b2    = (const float*)d_in[19];

    float* ws     = (float*)d_ws;
    float* tembs  = ws;                        // 72 floats
    float* tembW1 = ws + 256;                  // 9*256 = 2304 -> end 2560
    unsigned short* Brz = (unsigned short*)(ws + 4608);  // 163840
    unsigned short* Bnu = Brz + 163840;                  // 16384
    unsigned short* Bnh = Bnu + 16384;                   // 65536
    unsigned short* Bz0 = Bnh + 65536;                   // 65536
    unsigned short* B1  = Bz0 + 65536;                   // 16*4*512 = 32768
    unsigned short* B2  = B1  + 32768;                   // 16*8*512 = 65536
    unsigned short* B3  = B2  + 65536;                   //  8*8*512 = 32768

    float* out      = (float*)d_out;
    float* out_haz  = out;                              // 4096*48
    float* out_surv = out + 196608;                     // 4096*48
    float* out_mean = out + 393216;                     // 4096*128
    float* out_lv   = out + 917504;                     // 4096*128
    float* out_pg   = out + 1441792;                    // 4096

    temb_k<<<1, 64, 0, stream>>>(tproj_w, tproj_b, tembs);
    tembW1_k<<<(NTEMB * 256 + 255) / 256, 256, 0, stream>>>(ode_w1, ode_b1, tembs, tembW1);

    packBrz_k<<<(32*10*512) / 256, 256, 0, stream>>>(gru_w_ih, gru_w_hh, Brz);
    packB_k<<<(16*2*512) / 256, 256, 0, stream>>>(gru_w_ih + 512 * 64,  Bnu, 64,  16, 2);
    packB_k<<<(16*8*512) / 256, 256, 0, stream>>>(gru_w_hh + 512 * 256, Bnh, 256, 16, 8);
    packB_k<<<(16*8*512) / 256, 256, 0, stream>>>(z0_w,                 Bz0, 256, 16, 8);
    packB_k<<<(16*4*512) / 256, 256, 0, stream>>>(ode_w1, B1, 136, 16, 4);   // k<128 only
    packB_k<<<(16*8*512) / 256, 256, 0, stream>>>(ode_w2, B2, 256, 16, 8);
    packB_k<<<( 8*8*512) / 256, 256, 0, stream>>>(ode_w3, B3, 256,  8, 8);

    gru_mfma_k<<<BB / 16, 512, 0, stream>>>(X, Mask, Brz, Bnu, Bnh, Bz0,
                                            gru_b_ih, gru_b_hh, z0_b, out_mean, out_lv);

    ode_head_mfma_k<<<BB / 16, 512, 0, stream>>>(out_mean, B1, B2, B3,
                                                 tembW1, ode_b2, ode_b3,
                                                 sh_w1, sh_b1, sh_w2, sh_b2,
                                                 out_haz, out_surv, out_pg);
}

// Round 20
// 361.483 us; speedup vs baseline: 2.0963x; 1.0393x over previous
//
#include <hip/hip_runtime.h>
#include <math.h>

#define BB 4096
#define TT 48
#define DD 32
#define HH 256
#define LL 128
#define HID 256
#define EE 8
#define NHZ 48
#define NS 4              // RK4 macro steps (dense-output Hermite between knots)
#define NTEMB (2*NS+1)    // 9 precomputed time-embeddings

typedef __attribute__((ext_vector_type(8))) short bf16x8;   // 8 bf16 = 4 VGPRs
typedef __attribute__((ext_vector_type(4))) float f32x4;

#define MFMA_BF16(a,b,c) __builtin_amdgcn_mfma_f32_16x16x32_bf16((a),(b),(c),0,0,0)

__device__ __forceinline__ float sigm_f(float x) {
    return 1.0f / (1.0f + __expf(-x));
}
__device__ __forceinline__ float tanh_f(float x) {
    x = fminf(fmaxf(x, -15.0f), 15.0f);
    float e = __expf(2.0f * x);
    return (e - 1.0f) / (e + 1.0f);
}
__device__ __forceinline__ float4 axpy4(float s, float4 a, float4 z) {
    return make_float4(fmaf(s, a.x, z.x), fmaf(s, a.y, z.y),
                       fmaf(s, a.z, z.z), fmaf(s, a.w, z.w));
}
__device__ __forceinline__ unsigned short f2bf(float x) {   // RNE fp32->bf16
    union { float f; unsigned u; } a; a.f = x;
    unsigned r = a.u + 0x7FFFu + ((a.u >> 16) & 1u);
    return (unsigned short)(r >> 16);
}

// ---------------- prep: fused time-embedding + tembW1 (one block) ----------------
// tembW1[ti][n] = b1[n] + sum_k W1[n][128+k] * temb(ti)[k]; tembs lives in LDS.

__global__ void prep_tw_k(const float* __restrict__ tproj_w, const float* __restrict__ tproj_b,
                          const float* __restrict__ w1, const float* __restrict__ b1,
                          float* __restrict__ tembW1) {
    __shared__ float ts[NTEMB * 8];
    int tid = threadIdx.x;
    if (tid < NTEMB) {
        float t = (float)tid / (float)(2 * NS);
        const float PI = 3.14159265358979323846f;
        float emb[8];
        #pragma unroll
        for (int m = 0; m < 4; ++m) {
            float pos = t * (float)(m + 1) * PI;
            emb[m]     = sinf(pos);
            emb[4 + m] = cosf(pos);
        }
        #pragma unroll
        for (int o = 0; o < 8; ++o) {
            float a = tproj_b[o];
            #pragma unroll
            for (int k = 0; k < 8; ++k) a = fmaf(tproj_w[o * 8 + k], emb[k], a);
            ts[tid * 8 + o] = a;
        }
    }
    __syncthreads();
    // 256 threads: thread n computes tembW1[ti][n] for all ti
    float wt[8];
    #pragma unroll
    for (int k = 0; k < 8; ++k) wt[k] = w1[tid * 136 + 128 + k];
    float bb = b1[tid];
    for (int ti = 0; ti < NTEMB; ++ti) {
        float a = bb;
        #pragma unroll
        for (int k = 0; k < 8; ++k) a = fmaf(wt[k], ts[ti * 8 + k], a);
        tembW1[ti * 256 + tid] = a;
    }
}

// ---------------- prep: single segmented mega-pack ----------------
// B-fragment layout (validated): element (frag*512 + lane*8 + j) holds
// B[k][n], k = ks*32 + (lane>>4)*8 + j, n = nt*16 + (lane&15).

__device__ __forceinline__ void packone(const float* __restrict__ src,
                                        unsigned short* __restrict__ dst,
                                        int i, int K, int NKS) {
    int frag = i >> 9, e = i & 511;
    int lane = e >> 3, j = e & 7;
    int nt = frag / NKS, ks = frag % NKS;
    int k = ks * 32 + ((lane >> 4) << 3) + j;
    int n = nt * 16 + (lane & 15);
    dst[i] = f2bf(src[n * K + k]);
}

#define SZ_BRZ (32*10*512)   // 163840
#define SZ_BNU (16*2*512)    // 16384
#define SZ_BNH (16*8*512)    // 65536
#define SZ_BZ0 (16*8*512)    // 65536
#define SZ_B1  (16*4*512)    // 32768
#define SZ_B2  (16*8*512)    // 65536
#define SZ_B3  ( 8*8*512)    // 32768
#define SZ_ALL (SZ_BRZ+SZ_BNU+SZ_BNH+SZ_BZ0+SZ_B1+SZ_B2+SZ_B3)  // 442368

__global__ void megapack_k(const float* __restrict__ w_ih, const float* __restrict__ w_hh,
                           const float* __restrict__ z0_w,
                           const float* __restrict__ ode_w1, const float* __restrict__ ode_w2,
                           const float* __restrict__ ode_w3,
                           unsigned short* __restrict__ Brz, unsigned short* __restrict__ Bnu,
                           unsigned short* __restrict__ Bnh, unsigned short* __restrict__ Bz0,
                           unsigned short* __restrict__ B1, unsigned short* __restrict__ B2,
                           unsigned short* __restrict__ B3) {
    int i = blockIdx.x * 256 + threadIdx.x;
    if (i < SZ_BRZ) {   // Brz: [u|h] concat, K=320
        int frag = i >> 9, e = i & 511;
        int lane = e >> 3, j = e & 7;
        int nt = frag / 10, ks = frag % 10;
        int k = ks * 32 + ((lane >> 4) << 3) + j;
        int n = nt * 16 + (lane & 15);
        float v = (k < 64) ? w_ih[n * 64 + k] : w_hh[n * 256 + (k - 64)];
        Brz[i] = f2bf(v);
        return;
    }
    i -= SZ_BRZ;
    if (i < SZ_BNU) { packone(w_ih + 512 * 64,  Bnu, i, 64,  2); return; }
    i -= SZ_BNU;
    if (i < SZ_BNH) { packone(w_hh + 512 * 256, Bnh, i, 256, 8); return; }
    i -= SZ_BNH;
    if (i < SZ_BZ0) { packone(z0_w,   Bz0, i, 256, 8); return; }
    i -= SZ_BZ0;
    if (i < SZ_B1)  { packone(ode_w1, B1,  i, 136, 4); return; }   // k<128 only
    i -= SZ_B1;
    if (i < SZ_B2)  { packone(ode_w2, B2,  i, 256, 8); return; }
    i -= SZ_B2;
    packone(ode_w3, B3, i, 256, 8);
}

// ---------------- GRU encoder via MFMA (round-19 verbatim) ----------------

__global__ __launch_bounds__(512, 1) void gru_mfma_k(
    const float* __restrict__ Xp, const float* __restrict__ Mp,
    const unsigned short* __restrict__ Brz,   // [32 nt][10 ks][512]
    const unsigned short* __restrict__ Bnu,   // [16 nt][ 2 ks][512]
    const unsigned short* __restrict__ Bnh,   // [16 nt][ 8 ks][512]  (-> LDS)
    const unsigned short* __restrict__ Bz0,   // [16 nt][ 8 ks][512]
    const float* __restrict__ b_ih, const float* __restrict__ b_hh,
    const float* __restrict__ z0_b,
    float* __restrict__ out_mean, float* __restrict__ out_lv) {

    __shared__ unsigned short h_bf[2][16 * 256];     // 16KB, swizzled
    __shared__ unsigned short u_bf[2][16 * 64];      // 4KB, swizzled
    __shared__ unsigned short bnh_lds[16 * 8 * 512]; // 131KB
    __shared__ float obs[2][16];

    int tid = threadIdx.x, blk = blockIdx.x;
    int lane = tid & 63, w = tid >> 6;
    int l4 = lane >> 4, l15 = lane & 15;

    for (int e = tid; e < 16 * 256; e += 512) h_bf[0][e] = 0;
    for (int e = tid; e < 8192; e += 512)
        ((f32x4*)bnh_lds)[e] = ((const f32x4*)Bnh)[e];

    float brz0[2], brz1[2], bin_[2], bhn_[2];
    int hcol[2];
    #pragma unroll
    for (int gg = 0; gg < 2; ++gg) {
        int n = (2 * w + gg) * 16 + l15;
        hcol[gg] = n;
        brz0[gg] = b_ih[n]       + b_hh[n];
        brz1[gg] = b_ih[256 + n] + b_hh[256 + n];
        bin_[gg] = b_ih[512 + n];
        bhn_[gg] = b_hh[512 + n];
    }
    float h_st[2][4] = {{0,0,0,0},{0,0,0,0}};

    // hoist time-invariant fragments: group 0's r/z (20) + both Bnu (4)
    bf16x8 hbr[10], hbz[10], hbu[2][2];
    {
        int g0 = 2 * w;
        #pragma unroll
        for (int ks = 0; ks < 10; ++ks) {
            hbr[ks] = *(const bf16x8*)(Brz + ((g0 * 10 + ks) * 512 + lane * 8));
            hbz[ks] = *(const bf16x8*)(Brz + (((16 + g0) * 10 + ks) * 512 + lane * 8));
        }
        #pragma unroll
        for (int gg = 0; gg < 2; ++gg)
            #pragma unroll
            for (int ks = 0; ks < 2; ++ks)
                hbu[gg][ks] = *(const bf16x8*)(Bnu + (((g0 + gg) * 2 + ks) * 512 + lane * 8));
    }

    // prologue: stage u/obs for t = TT-1 into buffer 0
    if (tid < 256) {
        int r = tid >> 4, c4 = tid & 15;
        const float* base = (c4 < 8 ? Xp : Mp) + (size_t)(blk * 16 + r) * (TT * DD) + (TT - 1) * DD;
        f32x4 v = __builtin_nontemporal_load(((const f32x4*)base) + (c4 & 7));
        ushort4 pk;
        pk.x = f2bf(v.x); pk.y = f2bf(v.y); pk.z = f2bf(v.z); pk.w = f2bf(v.w);
        int k0 = (c4 < 8) ? c4 * 4 : 32 + (c4 - 8) * 4;
        int off = r * 128 + ((k0 * 2) ^ ((r & 7) << 4));
        *(ushort4*)((char*)u_bf[0] + off) = pk;
    }
    if (tid < 16) {
        const f32x4* mrow = (const f32x4*)(Mp + (size_t)(blk * 16 + tid) * (TT * DD) + (TT - 1) * DD);
        float s = 0.0f;
        #pragma unroll
        for (int i = 0; i < 8; ++i) {
            f32x4 v = __builtin_nontemporal_load(mrow + i);
            s += v.x + v.y + v.z + v.w;
        }
        obs[0][tid] = (s > 0.0f) ? 1.0f : 0.0f;
    }
    __syncthreads();

    int arow = l15, asw = (arow & 7) << 4;
    int g1 = 2 * w + 1;
    int p = 0;

    for (int t = TT - 1; t >= 0; --t) {
        bf16x8 ah[8];
        #pragma unroll
        for (int ks = 0; ks < 8; ++ks)
            ah[ks] = *(const bf16x8*)((const char*)h_bf[p] + (arow * 512 + ((ks * 64 + l4 * 16) ^ asw)));
        bf16x8 au[2];
        #pragma unroll
        for (int ks = 0; ks < 2; ++ks)
            au[ks] = *(const bf16x8*)((const char*)u_bf[p] + (arow * 128 + ((ks * 64 + l4 * 16) ^ asw)));

        // early-issue: gg=1 streamed r/z fragments
        bf16x8 br1[10], bz1[10];
        #pragma unroll
        for (int ks = 0; ks < 10; ++ks) {
            br1[ks] = *(const bf16x8*)(Brz + ((g1 * 10 + ks) * 512 + lane * 8));
            bz1[ks] = *(const bf16x8*)(Brz + (((16 + g1) * 10 + ks) * 512 + lane * 8));
        }

        // stage NEXT timestep's u/obs into buffer p^1 (overlaps compute)
        if (t > 0) {
            if (tid < 256) {
                int r = tid >> 4, c4 = tid & 15;
                const float* base = (c4 < 8 ? Xp : Mp) + (size_t)(blk * 16 + r) * (TT * DD) + (t - 1) * DD;
                f32x4 v = __builtin_nontemporal_load(((const f32x4*)base) + (c4 & 7));
                ushort4 pk;
                pk.x = f2bf(v.x); pk.y = f2bf(v.y); pk.z = f2bf(v.z); pk.w = f2bf(v.w);
                int k0 = (c4 < 8) ? c4 * 4 : 32 + (c4 - 8) * 4;
                int off = r * 128 + ((k0 * 2) ^ ((r & 7) << 4));
                *(ushort4*)((char*)u_bf[p ^ 1] + off) = pk;
            }
            if (tid < 16) {
                const f32x4* mrow = (const f32x4*)(Mp + (size_t)(blk * 16 + tid) * (TT * DD) + (t - 1) * DD);
                float s = 0.0f;
                #pragma unroll
                for (int i = 0; i < 8; ++i) {
                    f32x4 v = __builtin_nontemporal_load(mrow + i);
                    s += v.x + v.y + v.z + v.w;
                }
                obs[p ^ 1][tid] = (s > 0.0f) ? 1.0f : 0.0f;
            }
        }

        #pragma unroll
        for (int gg = 0; gg < 2; ++gg) {
            int g = 2 * w + gg;
            f32x4 accr = {0,0,0,0}, accz = {0,0,0,0}, acci = {0,0,0,0}, acch = {0,0,0,0};
            #pragma unroll
            for (int ks = 0; ks < 10; ++ks) {
                bf16x8 a = (ks < 2) ? au[ks] : ah[ks - 2];
                bf16x8 br = (gg == 0) ? hbr[ks] : br1[ks];
                bf16x8 bz = (gg == 0) ? hbz[ks] : bz1[ks];
                accr = MFMA_BF16(a, br, accr);
                accz = MFMA_BF16(a, bz, accz);
            }
            #pragma unroll
            for (int ks = 0; ks < 2; ++ks)
                acci = MFMA_BF16(au[ks], hbu[gg][ks], acci);
            #pragma unroll
            for (int ks = 0; ks < 8; ++ks) {
                bf16x8 b = *(const bf16x8*)(bnh_lds + ((g * 8 + ks) * 512 + lane * 8));
                acch = MFMA_BF16(ah[ks], b, acch);
            }
            #pragma unroll
            for (int q = 0; q < 4; ++q) {
                int m = l4 * 4 + q;
                float rg = sigm_f(accr[q] + brz0[gg]);
                float zg = sigm_f(accz[q] + brz1[gg]);
                float nn = tanh_f(acci[q] + bin_[gg] + rg * (acch[q] + bhn_[gg]));
                float hnew = (1.0f - zg) * nn + zg * h_st[gg][q];
                float o = obs[p][m];
                float hs = o * hnew + (1.0f - o) * h_st[gg][q];
                h_st[gg][q] = hs;
                int off = m * 512 + ((hcol[gg] * 2) ^ ((m & 7) << 4));
                *(unsigned short*)((char*)h_bf[p ^ 1] + off) = f2bf(hs);
            }
        }
        __syncthreads();   // single barrier per timestep
        p ^= 1;
    }

    bf16x8 ahf[8];
    #pragma unroll
    for (int ks = 0; ks < 8; ++ks)
        ahf[ks] = *(const bf16x8*)((const char*)h_bf[p] + (arow * 512 + ((ks * 64 + l4 * 16) ^ asw)));
    #pragma unroll
    for (int gg = 0; gg < 2; ++gg) {
        int nt = 2 * w + gg;
        f32x4 acc = {0,0,0,0};
        #pragma unroll
        for (int ks = 0; ks < 8; ++ks) {
            bf16x8 b = *(const bf16x8*)(Bz0 + ((nt * 8 + ks) * 512 + lane * 8));
            acc = MFMA_BF16(ahf[ks], b, acc);
        }
        int n = nt * 16 + l15;
        float bb = z0_b[n];
        #pragma unroll
        for (int q = 0; q < 4; ++q) {
            int m = l4 * 4 + q;
            int row = blk * 16 + m;
            float v = acc[q] + bb;
            if (n < 128) out_mean[row * LL + n] = v;
            else         out_lv  [row * LL + (n - 128)] = v;
        }
    }
}

// ---------------- ODE dynamics eval via MFMA (validated) ----------------

__device__ __forceinline__ void ode_f_mfma(
    const unsigned short* __restrict__ az, unsigned short* __restrict__ h1b,
    unsigned short* __restrict__ h2b, float* __restrict__ fo,
    const unsigned short* __restrict__ B1, const unsigned short* __restrict__ B2,
    const unsigned short* __restrict__ B3,
    const float* __restrict__ tW1,   // tembW1 + ti*256 (includes b1)
    float b2n0, float b2n1, float b3n, int lane, int w) {

    int l4 = lane >> 4, l15 = lane & 15;
    int arow = l15, asw = (arow & 7) << 4;

    // phase A: h1 = tanh(W1z·z + tembW1(t))   K=128 -> 4 ks
    bf16x8 a4[4];
    #pragma unroll
    for (int ks = 0; ks < 4; ++ks)
        a4[ks] = *(const bf16x8*)((const char*)az + (arow * 256 + ((ks * 64 + l4 * 16) ^ asw)));
    #pragma unroll
    for (int gg = 0; gg < 2; ++gg) {
        int nt = 2 * w + gg, n = nt * 16 + l15;
        f32x4 acc = {0,0,0,0};
        #pragma unroll
        for (int ks = 0; ks < 4; ++ks) {
            bf16x8 b = *(const bf16x8*)(B1 + ((nt * 4 + ks) * 512 + lane * 8));
            acc = MFMA_BF16(a4[ks], b, acc);
        }
        float tb = tW1[n];
        #pragma unroll
        for (int q = 0; q < 4; ++q) {
            int m = l4 * 4 + q;
            float v = tanh_f(acc[q] + tb);
            *(unsigned short*)((char*)h1b + (m * 512 + ((n * 2) ^ ((m & 7) << 4)))) = f2bf(v);
        }
    }
    __syncthreads();

    // phase B: h2 = tanh(W2·h1 + b2)   K=256 -> 8 ks
    bf16x8 a8[8];
    #pragma unroll
    for (int ks = 0; ks < 8; ++ks)
        a8[ks] = *(const bf16x8*)((const char*)h1b + (arow * 512 + ((ks * 64 + l4 * 16) ^ asw)));
    #pragma unroll
    for (int gg = 0; gg < 2; ++gg) {
        int nt = 2 * w + gg, n = nt * 16 + l15;
        f32x4 acc = {0,0,0,0};
        #pragma unroll
        for (int ks = 0; ks < 8; ++ks) {
            bf16x8 b = *(const bf16x8*)(B2 + ((nt * 8 + ks) * 512 + lane * 8));
            acc = MFMA_BF16(a8[ks], b, acc);
        }
        float bb = (gg == 0) ? b2n0 : b2n1;
        #pragma unroll
        for (int q = 0; q < 4; ++q) {
            int m = l4 * 4 + q;
            float v = tanh_f(acc[q] + bb);
            *(unsigned short*)((char*)h2b + (m * 512 + ((n * 2) ^ ((m & 7) << 4)))) = f2bf(v);
        }
    }
    __syncthreads();

    // phase C: fo = W3·h2 + b3   N=128, wave w -> tile w
    #pragma unroll
    for (int ks = 0; ks < 8; ++ks)
        a8[ks] = *(const bf16x8*)((const char*)h2b + (arow * 512 + ((ks * 64 + l4 * 16) ^ asw)));
    {
        f32x4 acc = {0,0,0,0};
        #pragma unroll
        for (int ks = 0; ks < 8; ++ks) {
            bf16x8 b = *(const bf16x8*)(B3 + ((w * 8 + ks) * 512 + lane * 8));
            acc = MFMA_BF16(a8[ks], b, acc);
        }
        int n = w * 16 + l15;
        #pragma unroll
        for (int q = 0; q < 4; ++q)
            fo[(l4 * 4 + q) * 128 + n] = acc[q] + b3n;
    }
    __syncthreads();
}

// ---------------- ODE (4-step RK4 + Hermite dense output) + head ----------------

__global__ __launch_bounds__(512, 2) void ode_head_mfma_k(
    const float* __restrict__ zinit,
    const unsigned short* __restrict__ B1, const unsigned short* __restrict__ B2,
    const unsigned short* __restrict__ B3,
    const float* __restrict__ tembW1, const float* __restrict__ b2, const float* __restrict__ b3,
    const float* __restrict__ shw1g, const float* __restrict__ shb1,
    const float* __restrict__ shw2, const float* __restrict__ shb2,
    float* __restrict__ out_haz, float* __restrict__ out_surv, float* __restrict__ out_pg) {

    __shared__ __align__(16) float bufA [2048];
    __shared__ __align__(16) float bufB [2048];
    __shared__ __align__(16) float bufFP[2048];
    __shared__ __align__(16) float bufFN[2048];
    __shared__ __align__(16) float ztl  [2048];
    __shared__ __align__(16) unsigned short az [16 * 128];
    __shared__ __align__(16) unsigned short h1b[16 * 256];
    __shared__ __align__(16) unsigned short h2b[16 * 256];
    __shared__ __align__(16) float w1h[32 * 128];

    int tid = threadIdx.x, blk = blockIdx.x;
    int lane = tid & 63, w = tid >> 6;
    int l15 = lane & 15;
    int s5 = tid & 31, rh = tid >> 5;

    float b2n0 = b2[(2 * w) * 16 + l15];
    float b2n1 = b2[(2 * w + 1) * 16 + l15];
    float b3n  = b3[w * 16 + l15];
    float w2s = shw2[s5], b1s = shb1[s5], b2s = shb2[0];
    float cum_r = 0.0f;
    const float4* w1hq = (const float4*)w1h;

    float* zA = bufA; float* zB = bufB;
    float* fP = bufFP; float* fN = bufFN;

    int crow = tid >> 5, ccol = (tid & 31) * 4;
    int azoff = crow * 256 + ((ccol * 2) ^ ((crow & 7) << 4));

    {
        float4 zv = ((const float4*)(zinit + (size_t)blk * 2048))[tid];
        ((float4*)zA)[tid] = zv;
        ushort4 pb; pb.x = f2bf(zv.x); pb.y = f2bf(zv.y); pb.z = f2bf(zv.z); pb.w = f2bf(zv.w);
        *(ushort4*)((char*)az + azoff) = pb;
    }
    for (int e = tid; e < 32 * 128; e += 512) {
        int u = e >> 7, k = e & 127;
        w1h[((k >> 2) * 32 + u) * 4 + (k & 3)] = shw1g[e];
    }
    __syncthreads();

    // f0 = f(z0, t=0)
    ode_f_mfma(az, h1b, h2b, fP, B1, B2, B3, tembW1, b2n0, b2n1, b3n, lane, w);

    const float Hh = 1.0f / (float)NS;

    for (int st = 0; st < NS; ++st) {
        float4 ka, zr0;
        {   // k1 = fP (FSAL)
            float4 f = ((const float4*)fP)[tid];
            zr0 = ((const float4*)zA)[tid];
            ka = f;
            float4 zv = axpy4(0.5f * Hh, f, zr0);
            ((float4*)ztl)[tid] = zv;
            ushort4 pb; pb.x=f2bf(zv.x); pb.y=f2bf(zv.y); pb.z=f2bf(zv.z); pb.w=f2bf(zv.w);
            *(ushort4*)((char*)az + azoff) = pb;
        }
        __syncthreads();
        ode_f_mfma(az, h1b, h2b, fN, B1, B2, B3, tembW1 + (2*st+1)*256, b2n0, b2n1, b3n, lane, w); // k2
        {
            float4 f = ((const float4*)fN)[tid];
            ka = axpy4(2.0f, f, ka);
            float4 zv = axpy4(0.5f * Hh, f, zr0);
            ((float4*)ztl)[tid] = zv;
            ushort4 pb; pb.x=f2bf(zv.x); pb.y=f2bf(zv.y); pb.z=f2bf(zv.z); pb.w=f2bf(zv.w);
            *(ushort4*)((char*)az + azoff) = pb;
        }
        __syncthreads();
        ode_f_mfma(az, h1b, h2b, fN, B1, B2, B3, tembW1 + (2*st+1)*256, b2n0, b2n1, b3n, lane, w); // k3
        {
            float4 f = ((const float4*)fN)[tid];
            ka = axpy4(2.0f, f, ka);
            float4 zv = axpy4(Hh, f, zr0);
            ((float4*)ztl)[tid] = zv;
            ushort4 pb; pb.x=f2bf(zv.x); pb.y=f2bf(zv.y); pb.z=f2bf(zv.z); pb.w=f2bf(zv.w);
            *(ushort4*)((char*)az + azoff) = pb;
        }
        __syncthreads();
        ode_f_mfma(az, h1b, h2b, fN, B1, B2, B3, tembW1 + (2*st+2)*256, b2n0, b2n1, b3n, lane, w); // k4
        {
            float4 f = ((const float4*)fN)[tid];
            float s6 = Hh / 6.0f;
            float4 kk = make_float4(ka.x + f.x, ka.y + f.y, ka.z + f.z, ka.w + f.w);
            float4 zv = axpy4(s6, kk, zr0);
            ((float4*)zB)[tid] = zv;
            ushort4 pb; pb.x=f2bf(zv.x); pb.y=f2bf(zv.y); pb.z=f2bf(zv.z); pb.w=f2bf(zv.w);
            *(ushort4*)((char*)az + azoff) = pb;
        }
        __syncthreads();
        // f_{s+1} (next step's k1, Hermite right-slope)
        ode_f_mfma(az, h1b, h2b, fN, B1, B2, B3, tembW1 + (2*st+2)*256, b2n0, b2n1, b3n, lane, w);

        // ---- emit head at output points inside [st/NS, (st+1)/NS] via Hermite ----
        int jlo = (47 * st + NS - 1) / NS;
        int jhi = (st == NS - 1) ? 47 : (47 * (st + 1) + NS - 1) / NS - 1;
        for (int jp = jlo; jp <= jhi; ++jp) {
            float th  = ((float)NS * (float)jp - 47.0f * (float)st) * (1.0f / 47.0f);
            float th2 = th * th, th3 = th2 * th;
            float c0 = 2.0f * th3 - 3.0f * th2 + 1.0f;
            float c1 = 3.0f * th2 - 2.0f * th3;
            float c2 = Hh * (th3 - 2.0f * th2 + th);
            float c3 = Hh * (th3 - th2);
            {
                float4 za = ((const float4*)zA)[tid];
                float4 zb = ((const float4*)zB)[tid];
                float4 fa = ((const float4*)fP)[tid];
                float4 fb = ((const float4*)fN)[tid];
                float4 zv;
                zv.x = c0*za.x + c1*zb.x + c2*fa.x + c3*fb.x;
                zv.y = c0*za.y + c1*zb.y + c2*fa.y + c3*fb.y;
                zv.z = c0*za.z + c1*zb.z + c2*fa.z + c3*fb.z;
                zv.w = c0*za.w + c1*zb.w + c2*fa.w + c3*fb.w;
                ((float4*)ztl)[tid] = zv;
            }
            __syncthreads();
            {
                float aa = b1s;
                const float4* zrow = (const float4*)(ztl + rh * LL);
                for (int k4 = 0; k4 < 32; ++k4) {
                    float4 wv = w1hq[k4 * 32 + s5];
                    float4 v = zrow[k4];
                    aa = fmaf(wv.x, v.x, aa); aa = fmaf(wv.y, v.y, aa);
                    aa = fmaf(wv.z, v.z, aa); aa = fmaf(wv.w, v.w, aa);
                }
                float p = fmaxf(aa, 0.0f) * w2s;
                p += __shfl_xor(p, 1);  p += __shfl_xor(p, 2);
                p += __shfl_xor(p, 4);  p += __shfl_xor(p, 8);
                p += __shfl_xor(p, 16);
                float hz = sigm_f(p + b2s);
                float sv = __expf(cum_r);
                cum_r += __logf(1.0f - hz + 1e-7f);
                if (s5 == 0) {
                    int row = blk * 16 + rh;
                    out_haz [row * NHZ + jp] = hz;
                    out_surv[row * NHZ + jp] = sv;
                    if (jp == NHZ - 1) out_pg[row] = 1.0f - sv;
                }
            }
            __syncthreads();
        }

        // roll buffers
        float* t0 = zA; zA = zB; zB = t0;
        t0 = fP; fP = fN; fN = t0;
    }
}

// ---------------- launch ----------------

extern "C" void kernel_launch(void* const* d_in, const int* in_sizes, int n_in,
                              void* d_out, int out_size, void* d_ws, size_t ws_size,
                              hipStream_t stream) {
    const float* X        = (const float*)d_in[0];
    const float* Mask     = (const float*)d_in[1];
    const float* gru_w_ih = (const float*)d_in[2];
    const float* gru_w_hh = (const float*)d_in[3];
    const float* gru_b_ih = (const float*)d_in[4];
    const float* gru_b_hh = (const float*)d_in[5];
    const float* z0_w     = (const float*)d_in[6];
    const float* z0_b     = (const float*)d_in[7];
    const float* tproj_w  = (const float*)d_in[8];
    const float* tproj_b  = (const float*)d_in[9];
    const float* ode_w1   = (const float*)d_in[10];
    const float* ode_b1   = (const float*)d_in[11];
    const float* ode_w2   = (const float*)d_in[12];
    const float* ode_b2   = (const float*)d_in[13];
    const float* ode_w3   = (const float*)d_in[14];
    const float* ode_b3   = (const float*)d_in[15];
    const float* sh_w1    = (const float*)d_in[16];
    const float* sh_b1    = (const float*)d_in[17];
    const float* sh_w2    = (const float*)d_in[18];
    const float* sh_b2    = (const float*)d_in[19];

    float* ws     = (float*)d_ws;
    float* tembW1 = ws + 256;                  // 9*256 = 2304 -> end 2560
    unsigned short* Brz = (unsigned short*)(ws + 4608);  // 163840
    unsigned short* Bnu = Brz + 163840;                  // 16384
    unsigned short* Bnh = Bnu + 16384;                   // 65536
    unsigned short* Bz0 = Bnh + 65536;                   // 65536
    unsigned short* B1  = Bz0 + 65536;                   // 32768
    unsigned short* B2  = B1  + 32768;                   // 65536
    unsigned short* B3  = B2  + 65536;                   // 32768

    float* out      = (float*)d_out;
    float* out_haz  = out;                              // 4096*48
    float* out_surv = out + 196608;                     // 4096*48
    float* out_mean = out + 393216;                     // 4096*128
    float* out_lv   = out + 917504;                     // 4096*128
    float* out_pg   = out + 1441792;                    // 4096

    prep_tw_k<<<1, 256, 0, stream>>>(tproj_w, tproj_b, ode_w1, ode_b1, tembW1);

    megapack_k<<<SZ_ALL / 256, 256, 0, stream>>>(gru_w_ih, gru_w_hh, z0_w,
                                                 ode_w1, ode_w2, ode_w3,
                                                 Brz, Bnu, Bnh, Bz0, B1, B2, B3);

    gru_mfma_k<<<BB / 16, 512, 0, stream>>>(X, Mask, Brz, Bnu, Bnh, Bz0,
                                            gru_b_ih, gru_b_hh, z0_b, out_mean, out_lv);

    ode_head_mfma_k<<<BB / 16, 512, 0, stream>>>(out_mean, B1, B2, B3,
                                                 tembW1, ode_b2, ode_b3,
                                                 sh_w1, sh_b1, sh_w2, sh_b2,
                                                 out_haz, out_surv, out_pg);
}